// Round 1
// baseline (3718.420 us; speedup 1.0000x reference)
//
#include <hip/hip_runtime.h>
#include <math.h>
#include <limits.h>

#define FDIM 512
#define HIDN 256
#define NBAGS 8
#define NINST 16384
#define NNODE 8200
#define NEDGE 32800

__device__ __forceinline__ float lrelu(float v, float s){ return v >= 0.f ? v : v*s; }

// ---------------------------------------------------------------------------
// Fused scores GEMM: for each of 131072 rows, score = sum_j relu(x@aW1 + ab1)_j * aW2_j
// tile 128x128, thread-tile 8x8, col-split partials written to scoresP[split][row]
// ---------------------------------------------------------------------------
__global__ __launch_bounds__(256) void k_scores(const float* __restrict__ X,
        const float* __restrict__ W, const float* __restrict__ b1,
        const float* __restrict__ v2, float* __restrict__ scoresP)
{
    __shared__ float As[32][128];
    __shared__ float Ws[32][128];
    __shared__ float red[128][16];
    int t = threadIdx.x; int tx = t & 15, ty = t >> 4;
    size_t mb = (size_t)blockIdx.y * 128; int nb = blockIdx.x * 128;
    float acc[8][8];
#pragma unroll
    for (int i=0;i<8;i++)
#pragma unroll
        for (int j=0;j<8;j++) acc[i][j]=0.f;

    int kq=(t&7)*4, m0=t>>3;
    int n4=(t&31)*4, k0=t>>5;
    for (int kc=0;kc<512;kc+=32){
#pragma unroll
        for (int mm=0;mm<4;mm++){
            int m = m0 + mm*32;
            float4 v = *(const float4*)(X + (mb+m)*512 + kc + kq);
            As[kq+0][m]=v.x; As[kq+1][m]=v.y; As[kq+2][m]=v.z; As[kq+3][m]=v.w;
        }
#pragma unroll
        for (int kk=0;kk<4;kk++){
            float4 v = *(const float4*)(W + (size_t)(kc+k0+kk*8)*512 + nb + n4);
            *(float4*)&Ws[k0+kk*8][n4] = v;
        }
        __syncthreads();
#pragma unroll 4
        for (int k=0;k<32;k++){
            float4 a0 = *(const float4*)&As[k][ty*8];
            float4 a1 = *(const float4*)&As[k][ty*8+4];
            float4 b0 = *(const float4*)&Ws[k][tx*8];
            float4 b1 = *(const float4*)&Ws[k][tx*8+4];
            float av[8]={a0.x,a0.y,a0.z,a0.w,a1.x,a1.y,a1.z,a1.w};
            float bv[8]={b0.x,b0.y,b0.z,b0.w,b1.x,b1.y,b1.z,b1.w};
#pragma unroll
            for (int i=0;i<8;i++)
#pragma unroll
                for (int j=0;j<8;j++)
                    acc[i][j] = fmaf(av[i], bv[j], acc[i][j]);
        }
        __syncthreads();
    }
    // epilogue: relu(h)·v2 partial per row
#pragma unroll
    for (int i=0;i<8;i++){
        float s=0.f;
#pragma unroll
        for (int j=0;j<8;j++){
            int gc = nb + tx*8 + j;
            float h = acc[i][j] + b1[gc];
            h = h > 0.f ? h : 0.f;
            s = fmaf(h, v2[gc], s);
        }
        red[ty*8+i][tx] = s;
    }
    __syncthreads();
    if (t < 128){
        float s=0.f;
#pragma unroll
        for (int q=0;q<16;q++) s += red[t][q];
        scoresP[(size_t)blockIdx.x*(NBAGS*NINST) + mb + t] = s;
    }
}

__global__ void k_scred(const float* __restrict__ sp, float* __restrict__ s){
    int r = blockIdx.x*256+threadIdx.x;
    if (r < NBAGS*NINST)
        s[r] = sp[r] + sp[NBAGS*NINST + r] + sp[2*NBAGS*NINST + r] + sp[3*NBAGS*NINST + r];
}

// softmax over 16384 per bag, in place
__global__ __launch_bounds__(256) void k_softmax(float* __restrict__ s0){
    int b = blockIdx.x; float* s = s0 + (size_t)b*NINST;
    __shared__ float red[256];
    int t = threadIdx.x;
    float m = -INFINITY;
    for (int i=t;i<NINST;i+=256) m = fmaxf(m, s[i]);
    red[t]=m; __syncthreads();
    for (int st=128; st>0; st>>=1){ if(t<st) red[t]=fmaxf(red[t],red[t+st]); __syncthreads(); }
    m = red[0]; __syncthreads();
    float sum=0.f;
    for (int i=t;i<NINST;i+=256) sum += __expf(s[i]-m);
    red[t]=sum; __syncthreads();
    for (int st=128; st>0; st>>=1){ if(t<st) red[t]+=red[t+st]; __syncthreads(); }
    float inv = 1.f/red[0];
    for (int i=t;i<NINST;i+=256) s[i] = __expf(s[i]-m)*inv;
}

// M partials: MP[(chunk*8+b)*512+d]
__global__ __launch_bounds__(256) void k_M(const float* __restrict__ x,
        const float* __restrict__ A, float* __restrict__ MP){
    int b = blockIdx.y; int chunk = blockIdx.x;
    int n0 = chunk*512;
    __shared__ float As[512];
    int t=threadIdx.x;
    As[t]       = A[(size_t)b*NINST+n0+t];
    As[t+256]   = A[(size_t)b*NINST+n0+t+256];
    __syncthreads();
    float a0=0.f, a1=0.f;
    const float* xb = x + ((size_t)b*NINST + n0)*FDIM;
    for (int n=0;n<512;n++){
        float w = As[n];
        a0 = fmaf(w, xb[(size_t)n*FDIM + t],       a0);
        a1 = fmaf(w, xb[(size_t)n*FDIM + t + 256], a1);
    }
    MP[((size_t)chunk*NBAGS + b)*FDIM + t]       = a0;
    MP[((size_t)chunk*NBAGS + b)*FDIM + t + 256] = a1;
}

__global__ void k_Mred(const float* __restrict__ mp, float* __restrict__ M_){
    int b = blockIdx.x; int d = threadIdx.x; // 512 threads
    float s=0.f;
    for (int c=0;c<32;c++) s += mp[((size_t)c*NBAGS+b)*FDIM + d];
    M_[b*FDIM+d]=s;
}

__global__ void k_logits_mlp(const float* __restrict__ M_, const float* __restrict__ cW,
        const float* __restrict__ cb, float* __restrict__ outp){
    int t = threadIdx.x;
    if (t < 16){
        int r=t>>1, c=t&1;
        float s=cb[c];
        for (int k=0;k<FDIM;k++) s = fmaf(M_[r*FDIM+k], cW[k*2+c], s);
        outp[r*2+c] = s;
    }
}

__global__ void k_xc(const float* __restrict__ M_, const float* __restrict__ reh, float* __restrict__ xc){
    size_t i = (size_t)blockIdx.x*256 + threadIdx.x;
    if (i >= (size_t)NNODE*FDIM) return;
    xc[i] = (i < (size_t)NBAGS*FDIM) ? M_[i] : reh[i - (size_t)NBAGS*FDIM];
}

// ---------------------------------------------------------------------------
// generic GEMM: C[M][N] = lrelu(X@W + bias, slope). tile 64x128, thread 4x8.
// N multiple of 128, K multiple of 32.
// ---------------------------------------------------------------------------
__global__ __launch_bounds__(256) void k_gemm(const float* __restrict__ X,
        const float* __restrict__ W, const float* __restrict__ bias,
        float* __restrict__ C, int M, int N, int K, float slope)
{
    __shared__ float As[32][64];
    __shared__ float Ws[32][128];
    int t = threadIdx.x; int tx = t & 15, ty = t >> 4;
    int mb = blockIdx.y * 64, nb = blockIdx.x * 128;
    float acc[4][8];
#pragma unroll
    for (int i=0;i<4;i++)
#pragma unroll
        for (int j=0;j<8;j++) acc[i][j]=0.f;

    int kq=(t&7)*4, m0=t>>3;
    int n4=(t&31)*4, k0=t>>5;
    for (int kc=0;kc<K;kc+=32){
#pragma unroll
        for (int mm=0;mm<2;mm++){
            int m = m0 + mm*32;
            int gr = mb + m; if (gr >= M) gr = M-1;
            float4 v = *(const float4*)(X + (size_t)gr*K + kc + kq);
            As[kq+0][m]=v.x; As[kq+1][m]=v.y; As[kq+2][m]=v.z; As[kq+3][m]=v.w;
        }
#pragma unroll
        for (int kk=0;kk<4;kk++){
            float4 v = *(const float4*)(W + (size_t)(kc+k0+kk*8)*N + nb + n4);
            *(float4*)&Ws[k0+kk*8][n4] = v;
        }
        __syncthreads();
#pragma unroll 4
        for (int k=0;k<32;k++){
            float4 a = *(const float4*)&As[k][ty*4];
            float4 b0 = *(const float4*)&Ws[k][tx*8];
            float4 b1 = *(const float4*)&Ws[k][tx*8+4];
            float av[4]={a.x,a.y,a.z,a.w};
            float bv[8]={b0.x,b0.y,b0.z,b0.w,b1.x,b1.y,b1.z,b1.w};
#pragma unroll
            for (int i=0;i<4;i++)
#pragma unroll
                for (int j=0;j<8;j++)
                    acc[i][j] = fmaf(av[i], bv[j], acc[i][j]);
        }
        __syncthreads();
    }
#pragma unroll
    for (int i=0;i<4;i++){
        int gr = mb + ty*4 + i;
        if (gr >= M) continue;
        float o[8];
#pragma unroll
        for (int j=0;j<8;j++){
            int gc = nb + tx*8 + j;
            float v = acc[i][j] + (bias ? bias[gc] : 0.f);
            o[j] = lrelu(v, slope);
        }
        float4 o0 = make_float4(o[0],o[1],o[2],o[3]);
        float4 o1 = make_float4(o[4],o[5],o[6],o[7]);
        *(float4*)(C + (size_t)gr*N + nb + tx*8)     = o0;
        *(float4*)(C + (size_t)gr*N + nb + tx*8 + 4) = o1;
    }
}

// row dot: mode 0: out[r] = X[r]·v ; mode 1: out[r] = 1/(sqrt(X[r]·X[r])+1e-12)
__global__ void k_rowdot(const float* __restrict__ X, const float* __restrict__ v,
        float* __restrict__ out, int K, int mode){
    int r = blockIdx.x; int t = threadIdx.x;
    const float* xr = X + (size_t)r*K;
    float s = 0.f;
    if (mode==1){ for (int k=t;k<K;k+=64){ float x_=xr[k]; s=fmaf(x_,x_,s);} }
    else        { for (int k=t;k<K;k+=64) s=fmaf(xr[k],v[k],s); }
    for (int off=32;off;off>>=1) s += __shfl_down(s, off);
    if (t==0) out[r] = (mode==1)? 1.f/(sqrtf(s)+1e-12f) : s;
}

// w2[k] = sum_j W[k][j]*att2[j]
__global__ void k_watt(const float* __restrict__ W, const float* __restrict__ att2, float* __restrict__ w2){
    int k = blockIdx.x; int t=threadIdx.x;
    float s=0.f;
    for (int j=t;j<FDIM;j+=64) s=fmaf(W[(size_t)k*FDIM+j], att2[j], s);
    for (int off=32;off;off>>=1) s += __shfl_down(s, off);
    if (t==0) w2[k]=s;
}

// ---------------------------------------------------------------------------
// sim + fused top-4.  grid (8 col-splits, 65 row-blocks). tile 128x128.
// candV/candI: [row][split][4]
// ---------------------------------------------------------------------------
__global__ __launch_bounds__(256) void k_simtopk(const float* __restrict__ xg,
        const float* __restrict__ rn, float* __restrict__ candV, int* __restrict__ candI)
{
    __shared__ __align__(16) char smem_[65536];
    float (*As)[128]   = (float(*)[128])smem_;
    float (*Bs)[128]   = (float(*)[128])(smem_ + 16384);
    float (*cand)[128] = (float(*)[128])smem_;
    int t = threadIdx.x; int tx = t & 15, ty = t >> 4;
    int split = blockIdx.x; int mb = blockIdx.y * 128;
    int c0 = split * 1025, cend = c0 + 1025;  // 8*1025 == 8200
    int grow = mb + t;
    float rnr = (t < 128 && grow < NNODE) ? rn[grow] : 0.f;
    float tv[4] = {-INFINITY,-INFINITY,-INFINITY,-INFINITY};
    int   ti[4] = {INT_MAX,INT_MAX,INT_MAX,INT_MAX};

    int kq=(t&7)*4, m0=t>>3;
    for (int cc = c0; cc < cend; cc += 128){
        float acc[8][8];
#pragma unroll
        for (int i=0;i<8;i++)
#pragma unroll
            for (int j=0;j<8;j++) acc[i][j]=0.f;
        for (int kc=0;kc<512;kc+=32){
#pragma unroll
            for (int mm=0;mm<4;mm++){
                int m = m0 + mm*32;
                int gr = mb+m; if (gr >= NNODE) gr = NNODE-1;
                float4 v = *(const float4*)(xg + (size_t)gr*512 + kc + kq);
                As[kq+0][m]=v.x; As[kq+1][m]=v.y; As[kq+2][m]=v.z; As[kq+3][m]=v.w;
            }
#pragma unroll
            for (int cci=0;cci<4;cci++){
                int col = m0 + cci*32;
                int gc = cc + col; if (gc >= NNODE) gc = NNODE-1;
                float4 v = *(const float4*)(xg + (size_t)gc*512 + kc + kq);
                Bs[kq+0][col]=v.x; Bs[kq+1][col]=v.y; Bs[kq+2][col]=v.z; Bs[kq+3][col]=v.w;
            }
            __syncthreads();
#pragma unroll 4
            for (int k=0;k<32;k++){
                float4 a0 = *(const float4*)&As[k][ty*8];
                float4 a1 = *(const float4*)&As[k][ty*8+4];
                float4 b0 = *(const float4*)&Bs[k][tx*8];
                float4 b1 = *(const float4*)&Bs[k][tx*8+4];
                float av[8]={a0.x,a0.y,a0.z,a0.w,a1.x,a1.y,a1.z,a1.w};
                float bv[8]={b0.x,b0.y,b0.z,b0.w,b1.x,b1.y,b1.z,b1.w};
#pragma unroll
                for (int i=0;i<8;i++)
#pragma unroll
                    for (int j=0;j<8;j++)
                        acc[i][j] = fmaf(av[i], bv[j], acc[i][j]);
            }
            __syncthreads();
        }
        // dump acc tile into LDS (overlays As/Bs; K loop is done)
#pragma unroll
        for (int i=0;i<8;i++){
            int r = ty*8+i;
            float4 o0 = make_float4(acc[i][0],acc[i][1],acc[i][2],acc[i][3]);
            float4 o1 = make_float4(acc[i][4],acc[i][5],acc[i][6],acc[i][7]);
            *(float4*)&cand[r][tx*8]   = o0;
            *(float4*)&cand[r][tx*8+4] = o1;
        }
        __syncthreads();
        if (t < 128 && grow < NNODE){
            int cmax = cend - cc; if (cmax > 128) cmax = 128;
            for (int c=0;c<cmax;c++){
                int gcol = cc + c;
                float v = cand[t][c] * rnr * rn[gcol];
                if (v > tv[3] || (v == tv[3] && gcol < ti[3])){
                    tv[3]=v; ti[3]=gcol;
#pragma unroll
                    for (int q=3;q>0;--q){
                        bool sw = (tv[q] > tv[q-1]) || (tv[q]==tv[q-1] && ti[q]<ti[q-1]);
                        if (sw){
                            float tv_=tv[q]; tv[q]=tv[q-1]; tv[q-1]=tv_;
                            int ti_=ti[q]; ti[q]=ti[q-1]; ti[q-1]=ti_;
                        }
                    }
                }
            }
        }
        __syncthreads();
    }
    if (t < 128 && grow < NNODE){
#pragma unroll
        for (int s=0;s<4;s++){
            candV[((size_t)grow*8+split)*4+s]=tv[s];
            candI[((size_t)grow*8+split)*4+s]=ti[s];
        }
    }
}

__global__ void k_topk_merge(const float* __restrict__ candV, const int* __restrict__ candI,
        int* __restrict__ nbr){
    int r = blockIdx.x*256+threadIdx.x; if (r>=NNODE) return;
    const float* cv = candV + (size_t)r*32;
    const int*   ci = candI + (size_t)r*32;
    int chosen[4];
    for (int s=0;s<4;s++){
        float bv=-INFINITY; int bi=INT_MAX; int bslot=-1;
        for (int i=0;i<32;i++){
            bool used=false;
            for (int q=0;q<s;q++) used = used || (chosen[q]==i);
            if (used) continue;
            float v = cv[i]; int id = ci[i];
            if (v > bv || (v==bv && id < bi)){ bv=v; bi=id; bslot=i; }
        }
        chosen[s]=bslot;
        nbr[r*4+s]=bi;
    }
}

__global__ void k_eattr(const float* __restrict__ xg, const int* __restrict__ nbr, float* __restrict__ ea){
    int j = blockIdx.x; int t = threadIdx.x;
    int n0=nbr[j*4], n1=nbr[j*4+1], n2=nbr[j*4+2], n3=nbr[j*4+3];
    for (int d=t; d<FDIM; d+=256){
        float s = xg[(size_t)n0*FDIM+d]+xg[(size_t)n1*FDIM+d]+xg[(size_t)n2*FDIM+d]+xg[(size_t)n3*FDIM+d];
        ea[(size_t)j*FDIM+d] = 0.25f*s;
    }
}

__global__ void k_count(const int* __restrict__ nbr, int* __restrict__ counts){
    int e = blockIdx.x*256+threadIdx.x; if(e<NEDGE) atomicAdd(&counts[nbr[e]],1);
}

__global__ void k_scan(const int* __restrict__ counts, int* __restrict__ csrOff){
    __shared__ int part[257];
    int t=threadIdx.x;
    int start = t*33; int s=0;
    for (int i=0;i<33;i++){ int idx=start+i; if(idx<NNODE) s += counts[idx]; }
    part[t+1]=s; if(t==0) part[0]=0;
    __syncthreads();
    if (t==0){ for (int i=1;i<=256;i++) part[i]+=part[i-1]; }
    __syncthreads();
    int run = part[t];
    for (int i=0;i<33;i++){ int idx=start+i; if(idx<NNODE){ csrOff[idx]=run; run+=counts[idx]; } }
    if (t==255) csrOff[NNODE]=run;
}

__global__ void k_fill(const int* __restrict__ nbr, const int* __restrict__ csrOff,
        int* __restrict__ fillPos, int* __restrict__ csrE){
    int e = blockIdx.x*256+threadIdx.x; if(e>=NEDGE) return;
    int i = nbr[e];
    int p = atomicAdd(&fillPos[i],1);
    csrE[csrOff[i]+p] = e;
}

__global__ void k_alpha(const int* __restrict__ nbr, const float* __restrict__ ps,
        const float* __restrict__ pe, float* __restrict__ alphan){
    int e = blockIdx.x*256+threadIdx.x; if(e>=NEDGE) return;
    float a = ps[nbr[e]] + pe[e>>2];
    alphan[e] = a>=0.f? a : 0.2f*a;
}

__global__ void k_esm(const int* __restrict__ csrOff, const int* __restrict__ csrE,
        float* __restrict__ alphan){
    int i = blockIdx.x*256+threadIdx.x; if(i>=NNODE) return;
    int s0=csrOff[i], s1=csrOff[i+1];
    if (s1==s0) return;
    float m=-INFINITY;
    for (int s=s0;s<s1;s++) m = fmaxf(m, alphan[csrE[s]]);
    float Z=0.f;
    for (int s=s0;s<s1;s++) Z += __expf(alphan[csrE[s]]-m);
    float inv = 1.f/Z;
    for (int s=s0;s<s1;s++){ int e=csrE[s]; alphan[e] = __expf(alphan[e]-m)*inv; }
}

__global__ void k_oute(const float* __restrict__ xs, const float* __restrict__ alphan,
        const int* __restrict__ nbr, float* __restrict__ out_e){
    int j = blockIdx.x; int t=threadIdx.x;
    __shared__ float a[4]; __shared__ int sidx[4];
    if (t<4){ a[t]=alphan[j*4+t]; sidx[t]=nbr[j*4+t]; }
    __syncthreads();
    for (int d=t; d<FDIM; d+=256){
        float v = a[0]*xs[(size_t)sidx[0]*FDIM+d] + a[1]*xs[(size_t)sidx[1]*FDIM+d]
                + a[2]*xs[(size_t)sidx[2]*FDIM+d] + a[3]*xs[(size_t)sidx[3]*FDIM+d];
        out_e[(size_t)j*FDIM+d] = 0.25f*v;
    }
}

__global__ void k_outn(const float* __restrict__ out_e, const float* __restrict__ alphan,
        const int* __restrict__ csrOff, const int* __restrict__ csrE,
        const float* __restrict__ bias, float* __restrict__ out_n){
    int i = blockIdx.x; int t=threadIdx.x;
    int s0=csrOff[i], s1=csrOff[i+1];
    float Dinv = (s1>s0)? 1.f/(float)(s1-s0) : 0.f;
    for (int d=t; d<FDIM; d+=256){
        float accv=0.f;
        for (int s=s0;s<s1;s++){
            int e=csrE[s];
            accv = fmaf(alphan[e], out_e[(size_t)(e>>2)*FDIM+d], accv);
        }
        out_n[(size_t)i*FDIM+d] = bias[d] + Dinv*accv;
    }
}

__global__ void k_colstat1(const float* __restrict__ Xn, float* __restrict__ p1, float* __restrict__ p2){
    int b = blockIdx.x; int t=threadIdx.x;
    float s0=0,q0=0,s1=0,q1=0;
    for (int r=b; r<NNODE; r+=64){
        float v0 = Xn[(size_t)r*FDIM + t];
        float v1 = Xn[(size_t)r*FDIM + t + 256];
        s0+=v0; q0=fmaf(v0,v0,q0); s1+=v1; q1=fmaf(v1,v1,q1);
    }
    p1[b*FDIM+t]=s0; p1[b*FDIM+t+256]=s1;
    p2[b*FDIM+t]=q0; p2[b*FDIM+t+256]=q1;
}

__global__ void k_colstat2(const float* __restrict__ p1, const float* __restrict__ p2,
        const float* __restrict__ w, const float* __restrict__ sc,
        float* __restrict__ mu, float* __restrict__ g){
    int d = threadIdx.x + blockIdx.x*256; if(d>=FDIM) return;
    float s=0,q=0;
    for (int bb=0;bb<64;bb++){ s+=p1[bb*FDIM+d]; q+=p2[bb*FDIM+d]; }
    float m = s/(float)NNODE;
    float ms = m*sc[d];
    float var = q/(float)NNODE - 2.f*ms*m + ms*ms;
    mu[d]=m;
    g[d] = w[d]*rsqrtf(var+1e-5f);
}

__global__ void k_gnapply(const float* __restrict__ Xin, const float* __restrict__ mu,
        const float* __restrict__ g, const float* __restrict__ sc,
        const float* __restrict__ bb, float* __restrict__ Xout){
    size_t i = (size_t)blockIdx.x*256+threadIdx.x;
    if (i >= (size_t)NNODE*FDIM) return;
    int d = (int)(i & 511);
    float o = Xin[i] - mu[d]*sc[d];
    Xout[i] = lrelu(g[d]*o + bb[d], 0.01f);
}

__global__ void k_final(const float* __restrict__ x1, const float* __restrict__ x2,
        const float* __restrict__ f1W, const float* __restrict__ f1b,
        const float* __restrict__ f2W, const float* __restrict__ f2b,
        const float* __restrict__ clW, const float* __restrict__ clb,
        float* __restrict__ outp){
    int r = blockIdx.x;
    int h = threadIdx.x;
    __shared__ float o8[HIDN];
    float s1=f1b[h], s2=f2b[h];
    for (int k=0;k<FDIM;k++){
        s1 = fmaf(x1[(size_t)r*FDIM+k], f1W[(size_t)k*HIDN+h], s1);
        s2 = fmaf(x2[(size_t)r*FDIM+k], f2W[(size_t)k*HIDN+h], s2);
    }
    o8[h] = lrelu(s1,0.01f)+lrelu(s2,0.01f);
    __syncthreads();
    if (h < 2){
        float s = clb[h];
        for (int k=0;k<HIDN;k++) s = fmaf(o8[k], clW[k*2+h], s);
        outp[16 + r*2 + h] = s;
    }
}

// ---------------------------------------------------------------------------
extern "C" void kernel_launch(void* const* d_in, const int* in_sizes, int n_in,
                              void* d_out, int out_size, void* d_ws, size_t ws_size,
                              hipStream_t stream) {
    (void)in_sizes; (void)n_in; (void)out_size; (void)ws_size;
    const float* x    = (const float*)d_in[0];
    const float* reh  = (const float*)d_in[1];
    const float* aW1  = (const float*)d_in[2];
    const float* ab1  = (const float*)d_in[3];
    const float* aW2  = (const float*)d_in[4];
    const float* cW   = (const float*)d_in[6];
    const float* cb   = (const float*)d_in[7];
    const float* dW1  = (const float*)d_in[8];
    const float* db1  = (const float*)d_in[9];
    const float* dW2  = (const float*)d_in[10];
    const float* db2  = (const float*)d_in[11];
    const float* g1W  = (const float*)d_in[12];
    const float* g1att= (const float*)d_in[13];
    const float* g1b  = (const float*)d_in[14];
    const float* n1w  = (const float*)d_in[15];
    const float* n1b  = (const float*)d_in[16];
    const float* n1s  = (const float*)d_in[17];
    const float* f1W  = (const float*)d_in[18];
    const float* f1b  = (const float*)d_in[19];
    const float* g2W  = (const float*)d_in[20];
    const float* g2att= (const float*)d_in[21];
    const float* g2b  = (const float*)d_in[22];
    const float* n2w  = (const float*)d_in[23];
    const float* n2b  = (const float*)d_in[24];
    const float* n2s  = (const float*)d_in[25];
    const float* f2W  = (const float*)d_in[26];
    const float* f2b  = (const float*)d_in[27];
    const float* clW  = (const float*)d_in[28];
    const float* clb  = (const float*)d_in[29];
    float* out = (float*)d_out;
    char* ws = (char*)d_ws;

    // workspace layout (bytes)
    float* scores = (float*)(ws + 0);              // 524288
    float* Mbuf   = (float*)(ws + 524288);         // 16384
    float* xc     = (float*)(ws + 540672);         // 16793600  (later reused as xs)
    float* xg1    = (float*)(ws + 17334272);       // 8396800
    float* xg     = (float*)(ws + 25731072);       // 16793600  (later reused as x2)
    float* rn     = (float*)(ws + 42524672);       // 32800
    float* candV  = (float*)(ws + 42557696);       // 1049600
    int*   candI  = (int*)  (ws + 43607296);       // 1049600
    int*   nbrp   = (int*)  (ws + 44656896);       // 131200
    float* eattr  = (float*)(ws + 44788224);       // 16793600
    int*   counts = (int*)  (ws + 61581824);       // 32800
    int*   csrOff = (int*)  (ws + 61614848);       // 32804
    int*   fillPos= (int*)  (ws + 61647872);       // 32800
    int*   csrE   = (int*)  (ws + 61680896);       // 131200
    float* w2     = (float*)(ws + 61812096);       // 2048
    float* ps     = (float*)(ws + 61814144);       // 32800
    float* pe     = (float*)(ws + 61847040);       // 32800
    float* alphan = (float*)(ws + 61880064);       // 131200
    float* out_e  = (float*)(ws + 62011264);       // 16793600
    float* out_n  = (float*)(ws + 78804864);       // 16793600
    float* part1  = (float*)(ws + 95598464);       // 131072
    float* part2  = (float*)(ws + 95729536);       // 131072
    float* mu     = (float*)(ws + 95860608);       // 2048
    float* gsc    = (float*)(ws + 95862656);       // 2048
    float* x1buf  = (float*)(ws + 95864704);       // 16793600
    float* scoresP= (float*)(ws + 112658304);      // 2097152
    float* MP     = (float*)(ws + 114755456);      // 524288  -> total ~115.3 MB
    float* xs     = xc;      // alias (xc dead after xg1 GEMM)
    float* x2buf  = xg;      // alias (xg dead after layer-1 xs GEMM)

    hipMemsetAsync(counts, 0, NNODE*sizeof(int), stream);
    hipMemsetAsync(fillPos, 0, NNODE*sizeof(int), stream);

    // ---- attention MIL pooling ----
    k_scores<<<dim3(4,1024),256,0,stream>>>(x, aW1, ab1, aW2, scoresP);
    k_scred<<<512,256,0,stream>>>(scoresP, scores);
    k_softmax<<<NBAGS,256,0,stream>>>(scores);
    k_M<<<dim3(32,NBAGS),256,0,stream>>>(x, scores, MP);
    k_Mred<<<NBAGS,512,0,stream>>>(MP, Mbuf);
    k_logits_mlp<<<1,64,0,stream>>>(Mbuf, cW, cb, out);

    // ---- projector ----
    k_xc<<<(NNODE*FDIM+255)/256,256,0,stream>>>(Mbuf, reh, xc);
    k_gemm<<<dim3(2,(NNODE+63)/64),256,0,stream>>>(xc, dW1, db1, xg1, NNODE, HIDN, FDIM, 0.01f);
    k_gemm<<<dim3(4,(NNODE+63)/64),256,0,stream>>>(xg1, dW2, db2, xg, NNODE, FDIM, HIDN, 0.01f);

    // ---- kNN graph ----
    k_rowdot<<<NNODE,64,0,stream>>>(xg, nullptr, rn, FDIM, 1);
    k_simtopk<<<dim3(8,(NNODE+127)/128),256,0,stream>>>(xg, rn, candV, candI);
    k_topk_merge<<<(NNODE+255)/256,256,0,stream>>>(candV, candI, nbrp);
    k_eattr<<<NNODE,256,0,stream>>>(xg, nbrp, eattr);
    k_count<<<(NEDGE+255)/256,256,0,stream>>>(nbrp, counts);
    k_scan<<<1,256,0,stream>>>(counts, csrOff);
    k_fill<<<(NEDGE+255)/256,256,0,stream>>>(nbrp, csrOff, fillPos, csrE);

    // ---- two hypergraph conv layers ----
    for (int layer=0; layer<2; ++layer){
        const float* Xin  = layer==0 ? xg   : x1buf;
        const float* W    = layer==0 ? g1W  : g2W;
        const float* att  = layer==0 ? g1att: g2att;
        const float* gb   = layer==0 ? g1b  : g2b;
        const float* nw   = layer==0 ? n1w  : n2w;
        const float* nb_  = layer==0 ? n1b  : n2b;
        const float* ns   = layer==0 ? n1s  : n2s;
        float* Xout       = layer==0 ? x1buf: x2buf;

        k_gemm<<<dim3(4,(NNODE+63)/64),256,0,stream>>>(Xin, W, nullptr, xs, NNODE, FDIM, FDIM, 1.0f);
        k_watt<<<FDIM,64,0,stream>>>(W, att+FDIM, w2);
        k_rowdot<<<NNODE,64,0,stream>>>(xs, att, ps, FDIM, 0);
        k_rowdot<<<NNODE,64,0,stream>>>(eattr, w2, pe, FDIM, 0);
        k_alpha<<<(NEDGE+255)/256,256,0,stream>>>(nbrp, ps, pe, alphan);
        k_esm<<<(NNODE+255)/256,256,0,stream>>>(csrOff, csrE, alphan);
        k_oute<<<NNODE,256,0,stream>>>(xs, alphan, nbrp, out_e);
        k_outn<<<NNODE,256,0,stream>>>(out_e, alphan, csrOff, csrE, gb, out_n);
        k_colstat1<<<64,256,0,stream>>>(out_n, part1, part2);
        k_colstat2<<<2,256,0,stream>>>(part1, part2, nw, ns, mu, gsc);
        k_gnapply<<<(NNODE*FDIM+255)/256,256,0,stream>>>(out_n, mu, gsc, ns, nb_, Xout);
    }

    // ---- final heads (only rows 0..7 matter) ----
    k_final<<<NBAGS,HIDN,0,stream>>>(x1buf, x2buf, f1W, f1b, f2W, f2b, clW, clb, out);
}

// Round 4
// 3456.696 us; speedup vs baseline: 1.0757x; 1.0757x over previous
//
#include <hip/hip_runtime.h>
#include <math.h>
#include <limits.h>

#define FDIM 512
#define HIDN 256
#define NBAGS 8
#define NINST 16384
#define NNODE 8200
#define NEDGE 32800

__device__ __forceinline__ float lrelu(float v, float s){ return v >= 0.f ? v : v*s; }

// sorted-4 insert with jax.lax.top_k tie semantics (lower index wins ties)
__device__ __forceinline__ void ins4(float v, int id, float* tv, int* ti){
    if ((v > tv[3]) || (v == tv[3] && id < ti[3])){
        tv[3]=v; ti[3]=id;
#pragma unroll
        for (int q=3;q>0;--q){
            bool sw = (tv[q] > tv[q-1]) || (tv[q]==tv[q-1] && ti[q]<ti[q-1]);
            if (sw){ float f=tv[q]; tv[q]=tv[q-1]; tv[q-1]=f; int d=ti[q]; ti[q]=ti[q-1]; ti[q-1]=d; }
        }
    }
}

// ---------------------------------------------------------------------------
// Fused scores GEMM (round-1 verbatim: bit-exact scores feeding the discrete
// top-k downstream). tile 128x128, thread-tile 8x8, col-split partials.
// ---------------------------------------------------------------------------
__global__ __launch_bounds__(256) void k_scores(const float* __restrict__ X,
        const float* __restrict__ W, const float* __restrict__ b1,
        const float* __restrict__ v2, float* __restrict__ scoresP)
{
    __shared__ float As[32][128];
    __shared__ float Ws[32][128];
    __shared__ float red[128][16];
    int t = threadIdx.x; int tx = t & 15, ty = t >> 4;
    size_t mb = (size_t)blockIdx.y * 128; int nb = blockIdx.x * 128;
    float acc[8][8];
#pragma unroll
    for (int i=0;i<8;i++)
#pragma unroll
        for (int j=0;j<8;j++) acc[i][j]=0.f;

    int kq=(t&7)*4, m0=t>>3;
    int n4=(t&31)*4, k0=t>>5;
    for (int kc=0;kc<512;kc+=32){
#pragma unroll
        for (int mm=0;mm<4;mm++){
            int m = m0 + mm*32;
            float4 v = *(const float4*)(X + (mb+m)*512 + kc + kq);
            As[kq+0][m]=v.x; As[kq+1][m]=v.y; As[kq+2][m]=v.z; As[kq+3][m]=v.w;
        }
#pragma unroll
        for (int kk=0;kk<4;kk++){
            float4 v = *(const float4*)(W + (size_t)(kc+k0+kk*8)*512 + nb + n4);
            *(float4*)&Ws[k0+kk*8][n4] = v;
        }
        __syncthreads();
#pragma unroll 4
        for (int k=0;k<32;k++){
            float4 a0 = *(const float4*)&As[k][ty*8];
            float4 a1 = *(const float4*)&As[k][ty*8+4];
            float4 b0 = *(const float4*)&Ws[k][tx*8];
            float4 b1 = *(const float4*)&Ws[k][tx*8+4];
            float av[8]={a0.x,a0.y,a0.z,a0.w,a1.x,a1.y,a1.z,a1.w};
            float bv[8]={b0.x,b0.y,b0.z,b0.w,b1.x,b1.y,b1.z,b1.w};
#pragma unroll
            for (int i=0;i<8;i++)
#pragma unroll
                for (int j=0;j<8;j++)
                    acc[i][j] = fmaf(av[i], bv[j], acc[i][j]);
        }
        __syncthreads();
    }
    // epilogue: relu(h)·v2 partial per row
#pragma unroll
    for (int i=0;i<8;i++){
        float s=0.f;
#pragma unroll
        for (int j=0;j<8;j++){
            int gc = nb + tx*8 + j;
            float h = acc[i][j] + b1[gc];
            h = h > 0.f ? h : 0.f;
            s = fmaf(h, v2[gc], s);
        }
        red[ty*8+i][tx] = s;
    }
    __syncthreads();
    if (t < 128){
        float s=0.f;
#pragma unroll
        for (int q=0;q<16;q++) s += red[t][q];
        scoresP[(size_t)blockIdx.x*(NBAGS*NINST) + mb + t] = s;
    }
}

__global__ void k_scred(const float* __restrict__ sp, float* __restrict__ s){
    int r = blockIdx.x*256+threadIdx.x;
    if (r < NBAGS*NINST)
        s[r] = sp[r] + sp[NBAGS*NINST + r] + sp[2*NBAGS*NINST + r] + sp[3*NBAGS*NINST + r];
}

// softmax over 16384 per bag, in place
__global__ __launch_bounds__(256) void k_softmax(float* __restrict__ s0){
    int b = blockIdx.x; float* s = s0 + (size_t)b*NINST;
    __shared__ float red[256];
    int t = threadIdx.x;
    float m = -INFINITY;
    for (int i=t;i<NINST;i+=256) m = fmaxf(m, s[i]);
    red[t]=m; __syncthreads();
    for (int st=128; st>0; st>>=1){ if(t<st) red[t]=fmaxf(red[t],red[t+st]); __syncthreads(); }
    m = red[0]; __syncthreads();
    float sum=0.f;
    for (int i=t;i<NINST;i+=256) sum += __expf(s[i]-m);
    red[t]=sum; __syncthreads();
    for (int st=128; st>0; st>>=1){ if(t<st) red[t]+=red[t+st]; __syncthreads(); }
    float inv = 1.f/red[0];
    for (int i=t;i<NINST;i+=256) s[i] = __expf(s[i]-m)*inv;
}

// M partials: MP[(chunk*8+b)*512+d]
__global__ __launch_bounds__(256) void k_M(const float* __restrict__ x,
        const float* __restrict__ A, float* __restrict__ MP){
    int b = blockIdx.y; int chunk = blockIdx.x;
    int n0 = chunk*512;
    __shared__ float As[512];
    int t=threadIdx.x;
    As[t]       = A[(size_t)b*NINST+n0+t];
    As[t+256]   = A[(size_t)b*NINST+n0+t+256];
    __syncthreads();
    float a0=0.f, a1=0.f;
    const float* xb = x + ((size_t)b*NINST + n0)*FDIM;
    for (int n=0;n<512;n++){
        float w = As[n];
        a0 = fmaf(w, xb[(size_t)n*FDIM + t],       a0);
        a1 = fmaf(w, xb[(size_t)n*FDIM + t + 256], a1);
    }
    MP[((size_t)chunk*NBAGS + b)*FDIM + t]       = a0;
    MP[((size_t)chunk*NBAGS + b)*FDIM + t + 256] = a1;
}

__global__ void k_Mred(const float* __restrict__ mp, float* __restrict__ M_){
    int b = blockIdx.x; int d = threadIdx.x; // 512 threads
    float s=0.f;
    for (int c=0;c<32;c++) s += mp[((size_t)c*NBAGS+b)*FDIM + d];
    M_[b*FDIM+d]=s;
}

__global__ void k_logits_mlp(const float* __restrict__ M_, const float* __restrict__ cW,
        const float* __restrict__ cb, float* __restrict__ outp){
    int t = threadIdx.x;
    if (t < 16){
        int r=t>>1, c=t&1;
        float s=cb[c];
        for (int k=0;k<FDIM;k++) s = fmaf(M_[r*FDIM+k], cW[k*2+c], s);
        outp[r*2+c] = s;
    }
}

__global__ void k_xc(const float* __restrict__ M_, const float* __restrict__ reh, float* __restrict__ xc){
    size_t i = (size_t)blockIdx.x*256 + threadIdx.x;
    if (i >= (size_t)NNODE*FDIM) return;
    xc[i] = (i < (size_t)NBAGS*FDIM) ? M_[i] : reh[i - (size_t)NBAGS*FDIM];
}

// ---------------------------------------------------------------------------
// generic GEMM: C[M][N] = lrelu(X@W + bias, slope). tile 64x128, thread 4x8.
// ---------------------------------------------------------------------------
__global__ __launch_bounds__(256) void k_gemm(const float* __restrict__ X,
        const float* __restrict__ W, const float* __restrict__ bias,
        float* __restrict__ C, int M, int N, int K, float slope)
{
    __shared__ float As[32][68];
    __shared__ float Ws[32][128];
    int t = threadIdx.x; int tx = t & 15, ty = t >> 4;
    int mb = blockIdx.y * 64, nb = blockIdx.x * 128;
    float acc[4][8];
#pragma unroll
    for (int i=0;i<4;i++)
#pragma unroll
        for (int j=0;j<8;j++) acc[i][j]=0.f;

    int kq=(t&7)*4, m0=t>>3;
    int n4=(t&31)*4, k0=t>>5;
    for (int kc=0;kc<K;kc+=32){
#pragma unroll
        for (int mm=0;mm<2;mm++){
            int m = m0 + mm*32;
            int gr = mb + m; if (gr >= M) gr = M-1;
            float4 v = *(const float4*)(X + (size_t)gr*K + kc + kq);
            As[kq+0][m]=v.x; As[kq+1][m]=v.y; As[kq+2][m]=v.z; As[kq+3][m]=v.w;
        }
#pragma unroll
        for (int kk=0;kk<4;kk++){
            float4 v = *(const float4*)(W + (size_t)(kc+k0+kk*8)*N + nb + n4);
            *(float4*)&Ws[k0+kk*8][n4] = v;
        }
        __syncthreads();
#pragma unroll 4
        for (int k=0;k<32;k++){
            float4 a = *(const float4*)&As[k][ty*4];
            float4 b0 = *(const float4*)&Ws[k][tx*4];
            float4 b1 = *(const float4*)&Ws[k][64+tx*4];
            float av[4]={a.x,a.y,a.z,a.w};
            float bv[8]={b0.x,b0.y,b0.z,b0.w,b1.x,b1.y,b1.z,b1.w};
#pragma unroll
            for (int i=0;i<4;i++)
#pragma unroll
                for (int j=0;j<8;j++)
                    acc[i][j] = fmaf(av[i], bv[j], acc[i][j]);
        }
        __syncthreads();
    }
#pragma unroll
    for (int i=0;i<4;i++){
        int gr = mb + ty*4 + i;
        if (gr >= M) continue;
        float o[8];
#pragma unroll
        for (int j=0;j<8;j++){
            int gc = (j<4) ? (nb + tx*4 + j) : (nb + 64 + tx*4 + (j-4));
            float v = acc[i][j] + (bias ? bias[gc] : 0.f);
            o[j] = lrelu(v, slope);
        }
        float4 o0 = make_float4(o[0],o[1],o[2],o[3]);
        float4 o1 = make_float4(o[4],o[5],o[6],o[7]);
        *(float4*)(C + (size_t)gr*N + nb + tx*4)      = o0;
        *(float4*)(C + (size_t)gr*N + nb + 64 + tx*4) = o1;
    }
}

// row dot: mode 0: out[r] = X[r]·v ; mode 1: out[r] = 1/(sqrt(X[r]·X[r])+1e-12)
__global__ void k_rowdot(const float* __restrict__ X, const float* __restrict__ v,
        float* __restrict__ out, int K, int mode){
    int r = blockIdx.x; int t = threadIdx.x;
    const float* xr = X + (size_t)r*K;
    float s = 0.f;
    if (mode==1){ for (int k=t;k<K;k+=64){ float x_=xr[k]; s=fmaf(x_,x_,s);} }
    else        { for (int k=t;k<K;k+=64) s=fmaf(xr[k],v[k],s); }
    for (int off=32;off;off>>=1) s += __shfl_down(s, off);
    if (t==0) out[r] = (mode==1)? 1.f/(sqrtf(s)+1e-12f) : s;
}

// w2[k] = sum_j W[k][j]*att2[j]
__global__ void k_watt(const float* __restrict__ W, const float* __restrict__ att2, float* __restrict__ w2){
    int k = blockIdx.x; int t=threadIdx.x;
    float s=0.f;
    for (int j=t;j<FDIM;j+=64) s=fmaf(W[(size_t)k*FDIM+j], att2[j], s);
    for (int off=32;off;off>>=1) s += __shfl_down(s, off);
    if (t==0) w2[k]=s;
}

// ---------------------------------------------------------------------------
// sim + fused top-4, all-register selection.
// grid (8 col-splits, 65 row-blocks). tile 128x128, thread tile 4x16.
// Selection value acc*rnr*rnc — exact round-1 association. Butterfly merge
// SNAPSHOTS the partner's full 4-slot list before any ins4 mutation (the
// rounds-2/3 bug: interleaved shfl/insert exchanged partially-merged slots,
// creating duplicate neighbor ids).
// ---------------------------------------------------------------------------
__global__ __launch_bounds__(256) void k_simtopk(const float* __restrict__ xg,
        const float* __restrict__ rn, float* __restrict__ candV, int* __restrict__ candI)
{
    __shared__ float As[32][132];
    __shared__ float Bs[32][132];
    int t = threadIdx.x;
    int cg = t & 7, rg = t >> 3;
    int split = blockIdx.x; int mb = blockIdx.y * 128;
    int c0 = split * 1024;
    int cend = (split == 7) ? NNODE : (c0 + 1024);

    float rnri[4];
#pragma unroll
    for (int i=0;i<4;i++){
        int grow = mb + rg*4 + i;
        rnri[i] = (grow < NNODE) ? rn[grow] : 0.f;
    }

    float tv[4][4]; int ti[4][4];
#pragma unroll
    for (int i=0;i<4;i++)
#pragma unroll
        for (int s=0;s<4;s++){ tv[i][s]=-INFINITY; ti[i][s]=INT_MAX; }

    int kq=(t&7)*4, m0=t>>3;
    for (int cc = c0; cc < cend; cc += 128){
        float acc[4][16];
#pragma unroll
        for (int i=0;i<4;i++)
#pragma unroll
            for (int c=0;c<16;c++) acc[i][c]=0.f;

        for (int kc=0;kc<512;kc+=32){
#pragma unroll
            for (int mm=0;mm<4;mm++){
                int m = m0 + mm*32;
                int gr = mb+m; if (gr >= NNODE) gr = NNODE-1;
                float4 v = *(const float4*)(xg + (size_t)gr*512 + kc + kq);
                As[kq+0][m]=v.x; As[kq+1][m]=v.y; As[kq+2][m]=v.z; As[kq+3][m]=v.w;
            }
#pragma unroll
            for (int cci=0;cci<4;cci++){
                int col = m0 + cci*32;
                int gc = cc + col; if (gc >= NNODE) gc = NNODE-1;
                float4 v = *(const float4*)(xg + (size_t)gc*512 + kc + kq);
                Bs[kq+0][col]=v.x; Bs[kq+1][col]=v.y; Bs[kq+2][col]=v.z; Bs[kq+3][col]=v.w;
            }
            __syncthreads();
#pragma unroll 4
            for (int k=0;k<32;k++){
                float4 a  = *(const float4*)&As[k][rg*4];
                float4 b0 = *(const float4*)&Bs[k][cg*4];
                float4 b1 = *(const float4*)&Bs[k][cg*4+32];
                float4 b2 = *(const float4*)&Bs[k][cg*4+64];
                float4 b3 = *(const float4*)&Bs[k][cg*4+96];
                float av[4]={a.x,a.y,a.z,a.w};
                float bv[16]={b0.x,b0.y,b0.z,b0.w,b1.x,b1.y,b1.z,b1.w,
                              b2.x,b2.y,b2.z,b2.w,b3.x,b3.y,b3.z,b3.w};
#pragma unroll
                for (int i=0;i<4;i++)
#pragma unroll
                    for (int c=0;c<16;c++)
                        acc[i][c] = fmaf(av[i], bv[c], acc[i][c]);
            }
            __syncthreads();
        }
        // fold this tile's 16 columns into per-row running top-4 (registers)
#pragma unroll
        for (int c=0;c<16;c++){
            int gcol = cc + cg*4 + ((c>>2)<<5) + (c&3);
            bool valid = gcol < cend;
            float rnc = valid ? rn[gcol] : 0.f;
#pragma unroll
            for (int i=0;i<4;i++){
                float v = valid ? acc[i][c]*rnri[i]*rnc : -INFINITY;
                ins4(v, gcol, tv[i], ti[i]);
            }
        }
    }
    // butterfly merge across the 8 cg lanes: snapshot partner's full list
    // FIRST, then insert — both partners mutate during ins4 otherwise.
#pragma unroll
    for (int mask=1; mask<8; mask<<=1){
        float ov[4][4]; int oi[4][4];
#pragma unroll
        for (int i=0;i<4;i++)
#pragma unroll
            for (int s=0;s<4;s++){
                ov[i][s] = __shfl_xor(tv[i][s], mask);
                oi[i][s] = __shfl_xor(ti[i][s], mask);
            }
#pragma unroll
        for (int i=0;i<4;i++)
#pragma unroll
            for (int s=0;s<4;s++)
                ins4(ov[i][s], oi[i][s], tv[i], ti[i]);
    }
    if (cg==0){
#pragma unroll
        for (int i=0;i<4;i++){
            int grow = mb + rg*4 + i;
            if (grow < NNODE){
#pragma unroll
                for (int s=0;s<4;s++){
                    candV[((size_t)grow*8+split)*4+s]=tv[i][s];
                    candI[((size_t)grow*8+split)*4+s]=ti[i][s];
                }
            }
        }
    }
}

__global__ void k_topk_merge(const float* __restrict__ candV, const int* __restrict__ candI,
        int* __restrict__ nbr){
    int r = blockIdx.x*256+threadIdx.x; if (r>=NNODE) return;
    const float* cv = candV + (size_t)r*32;
    const int*   ci = candI + (size_t)r*32;
    int chosen[4];
    for (int s=0;s<4;s++){
        float bv=-INFINITY; int bi=INT_MAX; int bslot=-1;
        for (int i=0;i<32;i++){
            bool used=false;
            for (int q=0;q<s;q++) used = used || (chosen[q]==i);
            if (used) continue;
            float v = cv[i]; int id = ci[i];
            if (v > bv || (v==bv && id < bi)){ bv=v; bi=id; bslot=i; }
        }
        chosen[s]=bslot;
        nbr[r*4+s]=bi;
    }
}

__global__ void k_eattr(const float* __restrict__ xg, const int* __restrict__ nbr, float* __restrict__ ea){
    int j = blockIdx.x; int t = threadIdx.x;
    int n0=nbr[j*4], n1=nbr[j*4+1], n2=nbr[j*4+2], n3=nbr[j*4+3];
    for (int d=t; d<FDIM; d+=256){
        float s = xg[(size_t)n0*FDIM+d]+xg[(size_t)n1*FDIM+d]+xg[(size_t)n2*FDIM+d]+xg[(size_t)n3*FDIM+d];
        ea[(size_t)j*FDIM+d] = 0.25f*s;
    }
}

__global__ void k_count(const int* __restrict__ nbr, int* __restrict__ counts){
    int e = blockIdx.x*256+threadIdx.x; if(e<NEDGE) atomicAdd(&counts[nbr[e]],1);
}

__global__ void k_scan(const int* __restrict__ counts, int* __restrict__ csrOff){
    __shared__ int part[257];
    int t=threadIdx.x;
    int start = t*33; int s=0;
    for (int i=0;i<33;i++){ int idx=start+i; if(idx<NNODE) s += counts[idx]; }
    part[t+1]=s; if(t==0) part[0]=0;
    __syncthreads();
    if (t==0){ for (int i=1;i<=256;i++) part[i]+=part[i-1]; }
    __syncthreads();
    int run = part[t];
    for (int i=0;i<33;i++){ int idx=start+i; if(idx<NNODE){ csrOff[idx]=run; run+=counts[idx]; } }
    if (t==255) csrOff[NNODE]=run;
}

__global__ void k_fill(const int* __restrict__ nbr, const int* __restrict__ csrOff,
        int* __restrict__ fillPos, int* __restrict__ csrE){
    int e = blockIdx.x*256+threadIdx.x; if(e>=NEDGE) return;
    int i = nbr[e];
    int p = atomicAdd(&fillPos[i],1);
    csrE[csrOff[i]+p] = e;
}

__global__ void k_alpha(const int* __restrict__ nbr, const float* __restrict__ ps,
        const float* __restrict__ pe, float* __restrict__ alphan){
    int e = blockIdx.x*256+threadIdx.x; if(e>=NEDGE) return;
    float a = ps[nbr[e]] + pe[e>>2];
    alphan[e] = a>=0.f? a : 0.2f*a;
}

__global__ void k_esm(const int* __restrict__ csrOff, const int* __restrict__ csrE,
        float* __restrict__ alphan){
    int i = blockIdx.x*256+threadIdx.x; if(i>=NNODE) return;
    int s0=csrOff[i], s1=csrOff[i+1];
    if (s1==s0) return;
    float m=-INFINITY;
    for (int s=s0;s<s1;s++) m = fmaxf(m, alphan[csrE[s]]);
    float Z=0.f;
    for (int s=s0;s<s1;s++) Z += __expf(alphan[csrE[s]]-m);
    float inv = 1.f/Z;
    for (int s=s0;s<s1;s++){ int e=csrE[s]; alphan[e] = __expf(alphan[e]-m)*inv; }
}

__global__ void k_oute(const float* __restrict__ xs, const float* __restrict__ alphan,
        const int* __restrict__ nbr, float* __restrict__ out_e){
    int j = blockIdx.x; int t=threadIdx.x;
    __shared__ float a[4]; __shared__ int sidx[4];
    if (t<4){ a[t]=alphan[j*4+t]; sidx[t]=nbr[j*4+t]; }
    __syncthreads();
    for (int d=t; d<FDIM; d+=256){
        float v = a[0]*xs[(size_t)sidx[0]*FDIM+d] + a[1]*xs[(size_t)sidx[1]*FDIM+d]
                + a[2]*xs[(size_t)sidx[2]*FDIM+d] + a[3]*xs[(size_t)sidx[3]*FDIM+d];
        out_e[(size_t)j*FDIM+d] = 0.25f*v;
    }
}

__global__ void k_outn(const float* __restrict__ out_e, const float* __restrict__ alphan,
        const int* __restrict__ csrOff, const int* __restrict__ csrE,
        const float* __restrict__ bias, float* __restrict__ out_n){
    int i = blockIdx.x; int t=threadIdx.x;
    int s0=csrOff[i], s1=csrOff[i+1];
    float Dinv = (s1>s0)? 1.f/(float)(s1-s0) : 0.f;
    for (int d=t; d<FDIM; d+=256){
        float accv=0.f;
        for (int s=s0;s<s1;s++){
            int e=csrE[s];
            accv = fmaf(alphan[e], out_e[(size_t)(e>>2)*FDIM+d], accv);
        }
        out_n[(size_t)i*FDIM+d] = bias[d] + Dinv*accv;
    }
}

__global__ void k_colstat1(const float* __restrict__ Xn, float* __restrict__ p1, float* __restrict__ p2){
    int b = blockIdx.x; int t=threadIdx.x;
    float s0=0,q0=0,s1=0,q1=0;
    for (int r=b; r<NNODE; r+=64){
        float v0 = Xn[(size_t)r*FDIM + t];
        float v1 = Xn[(size_t)r*FDIM + t + 256];
        s0+=v0; q0=fmaf(v0,v0,q0); s1+=v1; q1=fmaf(v1,v1,q1);
    }
    p1[b*FDIM+t]=s0; p1[b*FDIM+t+256]=s1;
    p2[b*FDIM+t]=q0; p2[b*FDIM+t+256]=q1;
}

__global__ void k_colstat2(const float* __restrict__ p1, const float* __restrict__ p2,
        const float* __restrict__ w, const float* __restrict__ sc,
        float* __restrict__ mu, float* __restrict__ g){
    int d = threadIdx.x + blockIdx.x*256; if(d>=FDIM) return;
    float s=0,q=0;
    for (int bb=0;bb<64;bb++){ s+=p1[bb*FDIM+d]; q+=p2[bb*FDIM+d]; }
    float m = s/(float)NNODE;
    float ms = m*sc[d];
    float var = q/(float)NNODE - 2.f*ms*m + ms*ms;
    mu[d]=m;
    g[d] = w[d]*rsqrtf(var+1e-5f);
}

__global__ void k_gnapply(const float* __restrict__ Xin, const float* __restrict__ mu,
        const float* __restrict__ g, const float* __restrict__ sc,
        const float* __restrict__ bb, float* __restrict__ Xout){
    size_t i = (size_t)blockIdx.x*256+threadIdx.x;
    if (i >= (size_t)NNODE*FDIM) return;
    int d = (int)(i & 511);
    float o = Xin[i] - mu[d]*sc[d];
    Xout[i] = lrelu(g[d]*o + bb[d], 0.01f);
}

__global__ void k_final(const float* __restrict__ x1, const float* __restrict__ x2,
        const float* __restrict__ f1W, const float* __restrict__ f1b,
        const float* __restrict__ f2W, const float* __restrict__ f2b,
        const float* __restrict__ clW, const float* __restrict__ clb,
        float* __restrict__ outp){
    int r = blockIdx.x;
    int h = threadIdx.x;
    __shared__ float o8[HIDN];
    float s1=f1b[h], s2=f2b[h];
    for (int k=0;k<FDIM;k++){
        s1 = fmaf(x1[(size_t)r*FDIM+k], f1W[(size_t)k*HIDN+h], s1);
        s2 = fmaf(x2[(size_t)r*FDIM+k], f2W[(size_t)k*HIDN+h], s2);
    }
    o8[h] = lrelu(s1,0.01f)+lrelu(s2,0.01f);
    __syncthreads();
    if (h < 2){
        float s = clb[h];
        for (int k=0;k<HIDN;k++) s = fmaf(o8[k], clW[k*2+h], s);
        outp[16 + r*2 + h] = s;
    }
}

// ---------------------------------------------------------------------------
extern "C" void kernel_launch(void* const* d_in, const int* in_sizes, int n_in,
                              void* d_out, int out_size, void* d_ws, size_t ws_size,
                              hipStream_t stream) {
    (void)in_sizes; (void)n_in; (void)out_size; (void)ws_size;
    const float* x    = (const float*)d_in[0];
    const float* reh  = (const float*)d_in[1];
    const float* aW1  = (const float*)d_in[2];
    const float* ab1  = (const float*)d_in[3];
    const float* aW2  = (const float*)d_in[4];
    const float* cW   = (const float*)d_in[6];
    const float* cb   = (const float*)d_in[7];
    const float* dW1  = (const float*)d_in[8];
    const float* db1  = (const float*)d_in[9];
    const float* dW2  = (const float*)d_in[10];
    const float* db2  = (const float*)d_in[11];
    const float* g1W  = (const float*)d_in[12];
    const float* g1att= (const float*)d_in[13];
    const float* g1b  = (const float*)d_in[14];
    const float* n1w  = (const float*)d_in[15];
    const float* n1b  = (const float*)d_in[16];
    const float* n1s  = (const float*)d_in[17];
    const float* f1W  = (const float*)d_in[18];
    const float* f1b  = (const float*)d_in[19];
    const float* g2W  = (const float*)d_in[20];
    const float* g2att= (const float*)d_in[21];
    const float* g2b  = (const float*)d_in[22];
    const float* n2w  = (const float*)d_in[23];
    const float* n2b  = (const float*)d_in[24];
    const float* n2s  = (const float*)d_in[25];
    const float* f2W  = (const float*)d_in[26];
    const float* f2b  = (const float*)d_in[27];
    const float* clW  = (const float*)d_in[28];
    const float* clb  = (const float*)d_in[29];
    float* out = (float*)d_out;
    char* ws = (char*)d_ws;

    // workspace layout (bytes)
    float* scores = (float*)(ws + 0);              // 524288
    float* Mbuf   = (float*)(ws + 524288);         // 16384
    float* xc     = (float*)(ws + 540672);         // 16793600  (later reused as xs)
    float* xg1    = (float*)(ws + 17334272);       // 8396800
    float* xg     = (float*)(ws + 25731072);       // 16793600  (later reused as x2)
    float* rn     = (float*)(ws + 42524672);       // 32800
    float* candV  = (float*)(ws + 42557696);       // 1049600
    int*   candI  = (int*)  (ws + 43607296);       // 1049600
    int*   nbrp   = (int*)  (ws + 44656896);       // 131200
    float* eattr  = (float*)(ws + 44788224);       // 16793600
    int*   counts = (int*)  (ws + 61581824);       // 32800
    int*   csrOff = (int*)  (ws + 61614848);       // 32804
    int*   fillPos= (int*)  (ws + 61647872);       // 32800
    int*   csrE   = (int*)  (ws + 61680896);       // 131200
    float* w2     = (float*)(ws + 61812096);       // 2048
    float* ps     = (float*)(ws + 61814144);       // 32800
    float* pe     = (float*)(ws + 61847040);       // 32800
    float* alphan = (float*)(ws + 61880064);       // 131200
    float* out_e  = (float*)(ws + 62011264);       // 16793600
    float* out_n  = (float*)(ws + 78804864);       // 16793600
    float* part1  = (float*)(ws + 95598464);       // 131072
    float* part2  = (float*)(ws + 95729536);       // 131072
    float* mu     = (float*)(ws + 95860608);       // 2048
    float* gsc    = (float*)(ws + 95862656);       // 2048
    float* x1buf  = (float*)(ws + 95864704);       // 16793600
    float* scoresP= (float*)(ws + 112658304);      // 2097152
    float* MP     = (float*)(ws + 114755456);      // 524288
    float* xs     = xc;      // alias (xc dead after xg1 GEMM)
    float* x2buf  = xg;      // alias (xg dead after layer-1 xs GEMM)

    hipMemsetAsync(counts, 0, NNODE*sizeof(int), stream);
    hipMemsetAsync(fillPos, 0, NNODE*sizeof(int), stream);

    // ---- attention MIL pooling ----
    k_scores<<<dim3(4,1024),256,0,stream>>>(x, aW1, ab1, aW2, scoresP);
    k_scred<<<512,256,0,stream>>>(scoresP, scores);
    k_softmax<<<NBAGS,256,0,stream>>>(scores);
    k_M<<<dim3(32,NBAGS),256,0,stream>>>(x, scores, MP);
    k_Mred<<<NBAGS,512,0,stream>>>(MP, Mbuf);
    k_logits_mlp<<<1,64,0,stream>>>(Mbuf, cW, cb, out);

    // ---- projector ----
    k_xc<<<(NNODE*FDIM+255)/256,256,0,stream>>>(Mbuf, reh, xc);
    k_gemm<<<dim3(2,(NNODE+63)/64),256,0,stream>>>(xc, dW1, db1, xg1, NNODE, HIDN, FDIM, 0.01f);
    k_gemm<<<dim3(4,(NNODE+63)/64),256,0,stream>>>(xg1, dW2, db2, xg, NNODE, FDIM, HIDN, 0.01f);

    // ---- kNN graph ----
    k_rowdot<<<NNODE,64,0,stream>>>(xg, nullptr, rn, FDIM, 1);
    k_simtopk<<<dim3(8,(NNODE+127)/128),256,0,stream>>>(xg, rn, candV, candI);
    k_topk_merge<<<(NNODE+255)/256,256,0,stream>>>(candV, candI, nbrp);
    k_eattr<<<NNODE,256,0,stream>>>(xg, nbrp, eattr);
    k_count<<<(NEDGE+255)/256,256,0,stream>>>(nbrp, counts);
    k_scan<<<1,256,0,stream>>>(counts, csrOff);
    k_fill<<<(NEDGE+255)/256,256,0,stream>>>(nbrp, csrOff, fillPos, csrE);

    // ---- two hypergraph conv layers ----
    for (int layer=0; layer<2; ++layer){
        const float* Xin  = layer==0 ? xg   : x1buf;
        const float* W    = layer==0 ? g1W  : g2W;
        const float* att  = layer==0 ? g1att: g2att;
        const float* gb   = layer==0 ? g1b  : g2b;
        const float* nw   = layer==0 ? n1w  : n2w;
        const float* nb_  = layer==0 ? n1b  : n2b;
        const float* ns   = layer==0 ? n1s  : n2s;
        float* Xout       = layer==0 ? x1buf: x2buf;

        k_gemm<<<dim3(4,(NNODE+63)/64),256,0,stream>>>(Xin, W, nullptr, xs, NNODE, FDIM, FDIM, 1.0f);
        k_watt<<<FDIM,64,0,stream>>>(W, att+FDIM, w2);
        k_rowdot<<<NNODE,64,0,stream>>>(xs, att, ps, FDIM, 0);
        k_rowdot<<<NNODE,64,0,stream>>>(eattr, w2, pe, FDIM, 0);
        k_alpha<<<(NEDGE+255)/256,256,0,stream>>>(nbrp, ps, pe, alphan);
        k_esm<<<(NNODE+255)/256,256,0,stream>>>(csrOff, csrE, alphan);
        k_oute<<<NNODE,256,0,stream>>>(xs, alphan, nbrp, out_e);
        k_outn<<<NNODE,256,0,stream>>>(out_e, alphan, csrOff, csrE, gb, out_n);
        k_colstat1<<<64,256,0,stream>>>(out_n, part1, part2);
        k_colstat2<<<2,256,0,stream>>>(part1, part2, nw, ns, mu, gsc);
        k_gnapply<<<(NNODE*FDIM+255)/256,256,0,stream>>>(out_n, mu, gsc, ns, nb_, Xout);
    }

    // ---- final heads (only rows 0..7 matter) ----
    k_final<<<NBAGS,HIDN,0,stream>>>(x1buf, x2buf, f1W, f1b, f2W, f2b, clW, clb, out);
}

// Round 5
// 3370.367 us; speedup vs baseline: 1.1033x; 1.0256x over previous
//
#include <hip/hip_runtime.h>
#include <math.h>
#include <limits.h>

#define FDIM 512
#define HIDN 256
#define NBAGS 8
#define NINST 16384
#define NNODE 8200
#define NEDGE 32800
#define NSPLIT 16

__device__ __forceinline__ float lrelu(float v, float s){ return v >= 0.f ? v : v*s; }

// sorted-4 insert with jax.lax.top_k tie semantics (lower index wins ties)
__device__ __forceinline__ void ins4(float v, int id, float* tv, int* ti){
    if ((v > tv[3]) || (v == tv[3] && id < ti[3])){
        tv[3]=v; ti[3]=id;
#pragma unroll
        for (int q=3;q>0;--q){
            bool sw = (tv[q] > tv[q-1]) || (tv[q]==tv[q-1] && ti[q]<ti[q-1]);
            if (sw){ float f=tv[q]; tv[q]=tv[q-1]; tv[q-1]=f; int d=ti[q]; ti[q]=ti[q-1]; ti[q-1]=d; }
        }
    }
}

// ---------------------------------------------------------------------------
// Fused scores GEMM (round-1 verbatim: bit-exact scores feeding the discrete
// top-k downstream). tile 128x128, thread-tile 8x8, col-split partials.
// ---------------------------------------------------------------------------
__global__ __launch_bounds__(256) void k_scores(const float* __restrict__ X,
        const float* __restrict__ W, const float* __restrict__ b1,
        const float* __restrict__ v2, float* __restrict__ scoresP)
{
    __shared__ float As[32][128];
    __shared__ float Ws[32][128];
    __shared__ float red[128][16];
    int t = threadIdx.x; int tx = t & 15, ty = t >> 4;
    size_t mb = (size_t)blockIdx.y * 128; int nb = blockIdx.x * 128;
    float acc[8][8];
#pragma unroll
    for (int i=0;i<8;i++)
#pragma unroll
        for (int j=0;j<8;j++) acc[i][j]=0.f;

    int kq=(t&7)*4, m0=t>>3;
    int n4=(t&31)*4, k0=t>>5;
    for (int kc=0;kc<512;kc+=32){
#pragma unroll
        for (int mm=0;mm<4;mm++){
            int m = m0 + mm*32;
            float4 v = *(const float4*)(X + (mb+m)*512 + kc + kq);
            As[kq+0][m]=v.x; As[kq+1][m]=v.y; As[kq+2][m]=v.z; As[kq+3][m]=v.w;
        }
#pragma unroll
        for (int kk=0;kk<4;kk++){
            float4 v = *(const float4*)(W + (size_t)(kc+k0+kk*8)*512 + nb + n4);
            *(float4*)&Ws[k0+kk*8][n4] = v;
        }
        __syncthreads();
#pragma unroll 4
        for (int k=0;k<32;k++){
            float4 a0 = *(const float4*)&As[k][ty*8];
            float4 a1 = *(const float4*)&As[k][ty*8+4];
            float4 b0 = *(const float4*)&Ws[k][tx*8];
            float4 b1 = *(const float4*)&Ws[k][tx*8+4];
            float av[8]={a0.x,a0.y,a0.z,a0.w,a1.x,a1.y,a1.z,a1.w};
            float bv[8]={b0.x,b0.y,b0.z,b0.w,b1.x,b1.y,b1.z,b1.w};
#pragma unroll
            for (int i=0;i<8;i++)
#pragma unroll
                for (int j=0;j<8;j++)
                    acc[i][j] = fmaf(av[i], bv[j], acc[i][j]);
        }
        __syncthreads();
    }
    // epilogue: relu(h)·v2 partial per row
#pragma unroll
    for (int i=0;i<8;i++){
        float s=0.f;
#pragma unroll
        for (int j=0;j<8;j++){
            int gc = nb + tx*8 + j;
            float h = acc[i][j] + b1[gc];
            h = h > 0.f ? h : 0.f;
            s = fmaf(h, v2[gc], s);
        }
        red[ty*8+i][tx] = s;
    }
    __syncthreads();
    if (t < 128){
        float s=0.f;
#pragma unroll
        for (int q=0;q<16;q++) s += red[t][q];
        scoresP[(size_t)blockIdx.x*(NBAGS*NINST) + mb + t] = s;
    }
}

__global__ void k_scred(const float* __restrict__ sp, float* __restrict__ s){
    int r = blockIdx.x*256+threadIdx.x;
    if (r < NBAGS*NINST)
        s[r] = sp[r] + sp[NBAGS*NINST + r] + sp[2*NBAGS*NINST + r] + sp[3*NBAGS*NINST + r];
}

// softmax over 16384 per bag, in place
__global__ __launch_bounds__(256) void k_softmax(float* __restrict__ s0){
    int b = blockIdx.x; float* s = s0 + (size_t)b*NINST;
    __shared__ float red[256];
    int t = threadIdx.x;
    float m = -INFINITY;
    for (int i=t;i<NINST;i+=256) m = fmaxf(m, s[i]);
    red[t]=m; __syncthreads();
    for (int st=128; st>0; st>>=1){ if(t<st) red[t]=fmaxf(red[t],red[t+st]); __syncthreads(); }
    m = red[0]; __syncthreads();
    float sum=0.f;
    for (int i=t;i<NINST;i+=256) sum += __expf(s[i]-m);
    red[t]=sum; __syncthreads();
    for (int st=128; st>0; st>>=1){ if(t<st) red[t]+=red[t+st]; __syncthreads(); }
    float inv = 1.f/red[0];
    for (int i=t;i<NINST;i+=256) s[i] = __expf(s[i]-m)*inv;
}

// M partials: MP[(chunk*8+b)*512+d]
__global__ __launch_bounds__(256) void k_M(const float* __restrict__ x,
        const float* __restrict__ A, float* __restrict__ MP){
    int b = blockIdx.y; int chunk = blockIdx.x;
    int n0 = chunk*512;
    __shared__ float As[512];
    int t=threadIdx.x;
    As[t]       = A[(size_t)b*NINST+n0+t];
    As[t+256]   = A[(size_t)b*NINST+n0+t+256];
    __syncthreads();
    float a0=0.f, a1=0.f;
    const float* xb = x + ((size_t)b*NINST + n0)*FDIM;
    for (int n=0;n<512;n++){
        float w = As[n];
        a0 = fmaf(w, xb[(size_t)n*FDIM + t],       a0);
        a1 = fmaf(w, xb[(size_t)n*FDIM + t + 256], a1);
    }
    MP[((size_t)chunk*NBAGS + b)*FDIM + t]       = a0;
    MP[((size_t)chunk*NBAGS + b)*FDIM + t + 256] = a1;
}

__global__ void k_Mred(const float* __restrict__ mp, float* __restrict__ M_){
    int b = blockIdx.x; int d = threadIdx.x; // 512 threads
    float s=0.f;
    for (int c=0;c<32;c++) s += mp[((size_t)c*NBAGS+b)*FDIM + d];
    M_[b*FDIM+d]=s;
}

__global__ void k_logits_mlp(const float* __restrict__ M_, const float* __restrict__ cW,
        const float* __restrict__ cb, float* __restrict__ outp){
    int t = threadIdx.x;
    if (t < 16){
        int r=t>>1, c=t&1;
        float s=cb[c];
        for (int k=0;k<FDIM;k++) s = fmaf(M_[r*FDIM+k], cW[k*2+c], s);
        outp[r*2+c] = s;
    }
}

__global__ void k_xc(const float* __restrict__ M_, const float* __restrict__ reh, float* __restrict__ xc){
    size_t i = (size_t)blockIdx.x*256 + threadIdx.x;
    if (i >= (size_t)NNODE*FDIM) return;
    xc[i] = (i < (size_t)NBAGS*FDIM) ? M_[i] : reh[i - (size_t)NBAGS*FDIM];
}

// ---------------------------------------------------------------------------
// generic GEMM: C[M][N] = lrelu(X@W + bias, slope). tile 64x128, thread 4x8.
// ---------------------------------------------------------------------------
__global__ __launch_bounds__(256) void k_gemm(const float* __restrict__ X,
        const float* __restrict__ W, const float* __restrict__ bias,
        float* __restrict__ C, int M, int N, int K, float slope)
{
    __shared__ float As[32][68];
    __shared__ float Ws[32][128];
    int t = threadIdx.x; int tx = t & 15, ty = t >> 4;
    int mb = blockIdx.y * 64, nb = blockIdx.x * 128;
    float acc[4][8];
#pragma unroll
    for (int i=0;i<4;i++)
#pragma unroll
        for (int j=0;j<8;j++) acc[i][j]=0.f;

    int kq=(t&7)*4, m0=t>>3;
    int n4=(t&31)*4, k0=t>>5;
    for (int kc=0;kc<K;kc+=32){
#pragma unroll
        for (int mm=0;mm<2;mm++){
            int m = m0 + mm*32;
            int gr = mb + m; if (gr >= M) gr = M-1;
            float4 v = *(const float4*)(X + (size_t)gr*K + kc + kq);
            As[kq+0][m]=v.x; As[kq+1][m]=v.y; As[kq+2][m]=v.z; As[kq+3][m]=v.w;
        }
#pragma unroll
        for (int kk=0;kk<4;kk++){
            float4 v = *(const float4*)(W + (size_t)(kc+k0+kk*8)*N + nb + n4);
            *(float4*)&Ws[k0+kk*8][n4] = v;
        }
        __syncthreads();
#pragma unroll 4
        for (int k=0;k<32;k++){
            float4 a = *(const float4*)&As[k][ty*4];
            float4 b0 = *(const float4*)&Ws[k][tx*4];
            float4 b1 = *(const float4*)&Ws[k][64+tx*4];
            float av[4]={a.x,a.y,a.z,a.w};
            float bv[8]={b0.x,b0.y,b0.z,b0.w,b1.x,b1.y,b1.z,b1.w};
#pragma unroll
            for (int i=0;i<4;i++)
#pragma unroll
                for (int j=0;j<8;j++)
                    acc[i][j] = fmaf(av[i], bv[j], acc[i][j]);
        }
        __syncthreads();
    }
#pragma unroll
    for (int i=0;i<4;i++){
        int gr = mb + ty*4 + i;
        if (gr >= M) continue;
        float o[8];
#pragma unroll
        for (int j=0;j<8;j++){
            int gc = (j<4) ? (nb + tx*4 + j) : (nb + 64 + tx*4 + (j-4));
            float v = acc[i][j] + (bias ? bias[gc] : 0.f);
            o[j] = lrelu(v, slope);
        }
        float4 o0 = make_float4(o[0],o[1],o[2],o[3]);
        float4 o1 = make_float4(o[4],o[5],o[6],o[7]);
        *(float4*)(C + (size_t)gr*N + nb + tx*4)      = o0;
        *(float4*)(C + (size_t)gr*N + nb + 64 + tx*4) = o1;
    }
}

// row dot: mode 0: out[r] = X[r]·v ; mode 1: out[r] = 1/(sqrt(X[r]·X[r])+1e-12)
__global__ void k_rowdot(const float* __restrict__ X, const float* __restrict__ v,
        float* __restrict__ out, int K, int mode){
    int r = blockIdx.x; int t = threadIdx.x;
    const float* xr = X + (size_t)r*K;
    float s = 0.f;
    if (mode==1){ for (int k=t;k<K;k+=64){ float x_=xr[k]; s=fmaf(x_,x_,s);} }
    else        { for (int k=t;k<K;k+=64) s=fmaf(xr[k],v[k],s); }
    for (int off=32;off;off>>=1) s += __shfl_down(s, off);
    if (t==0) out[r] = (mode==1)? 1.f/(sqrtf(s)+1e-12f) : s;
}

// w2[k] = sum_j W[k][j]*att2[j]
__global__ void k_watt(const float* __restrict__ W, const float* __restrict__ att2, float* __restrict__ w2){
    int k = blockIdx.x; int t=threadIdx.x;
    float s=0.f;
    for (int j=t;j<FDIM;j+=64) s=fmaf(W[(size_t)k*FDIM+j], att2[j], s);
    for (int off=32;off;off>>=1) s += __shfl_down(s, off);
    if (t==0) w2[k]=s;
}

// ---------------------------------------------------------------------------
// sim + fused top-4, all-register selection.
// grid (16 col-splits, 65 row-blocks) = 1040 blocks (~4 blocks/CU).
// tile 128x128, thread tile 4x16. splits 0..14: cols [s*512, s*512+512);
// split 15: [7680, 8200). LDS stride 136: reads conflict-free, transposed
// scalar writes 2-way (was 4-way at stride 132).
// Selection value acc*rnr*rnc — exact round-1 association. Butterfly merge
// snapshots the partner's full 4-slot list before inserting (round-4 fix).
// ---------------------------------------------------------------------------
__global__ __launch_bounds__(256) void k_simtopk(const float* __restrict__ xg,
        const float* __restrict__ rn, float* __restrict__ candV, int* __restrict__ candI)
{
    __shared__ float As[32][136];
    __shared__ float Bs[32][136];
    int t = threadIdx.x;
    int cg = t & 7, rg = t >> 3;
    int split = blockIdx.x; int mb = blockIdx.y * 128;
    int c0 = split * 512;
    int cend = (split == NSPLIT-1) ? NNODE : (c0 + 512);

    float rnri[4];
#pragma unroll
    for (int i=0;i<4;i++){
        int grow = mb + rg*4 + i;
        rnri[i] = (grow < NNODE) ? rn[grow] : 0.f;
    }

    float tv[4][4]; int ti[4][4];
#pragma unroll
    for (int i=0;i<4;i++)
#pragma unroll
        for (int s=0;s<4;s++){ tv[i][s]=-INFINITY; ti[i][s]=INT_MAX; }

    int kq=(t&7)*4, m0=t>>3;
    for (int cc = c0; cc < cend; cc += 128){
        float acc[4][16];
#pragma unroll
        for (int i=0;i<4;i++)
#pragma unroll
            for (int c=0;c<16;c++) acc[i][c]=0.f;

        for (int kc=0;kc<512;kc+=32){
#pragma unroll
            for (int mm=0;mm<4;mm++){
                int m = m0 + mm*32;
                int gr = mb+m; if (gr >= NNODE) gr = NNODE-1;
                float4 v = *(const float4*)(xg + (size_t)gr*512 + kc + kq);
                As[kq+0][m]=v.x; As[kq+1][m]=v.y; As[kq+2][m]=v.z; As[kq+3][m]=v.w;
            }
#pragma unroll
            for (int cci=0;cci<4;cci++){
                int col = m0 + cci*32;
                int gc = cc + col; if (gc >= NNODE) gc = NNODE-1;
                float4 v = *(const float4*)(xg + (size_t)gc*512 + kc + kq);
                Bs[kq+0][col]=v.x; Bs[kq+1][col]=v.y; Bs[kq+2][col]=v.z; Bs[kq+3][col]=v.w;
            }
            __syncthreads();
#pragma unroll 4
            for (int k=0;k<32;k++){
                float4 a  = *(const float4*)&As[k][rg*4];
                float4 b0 = *(const float4*)&Bs[k][cg*4];
                float4 b1 = *(const float4*)&Bs[k][cg*4+32];
                float4 b2 = *(const float4*)&Bs[k][cg*4+64];
                float4 b3 = *(const float4*)&Bs[k][cg*4+96];
                float av[4]={a.x,a.y,a.z,a.w};
                float bv[16]={b0.x,b0.y,b0.z,b0.w,b1.x,b1.y,b1.z,b1.w,
                              b2.x,b2.y,b2.z,b2.w,b3.x,b3.y,b3.z,b3.w};
#pragma unroll
                for (int i=0;i<4;i++)
#pragma unroll
                    for (int c=0;c<16;c++)
                        acc[i][c] = fmaf(av[i], bv[c], acc[i][c]);
            }
            __syncthreads();
        }
        // fold this tile's 16 columns into per-row running top-4 (registers)
#pragma unroll
        for (int c=0;c<16;c++){
            int gcol = cc + cg*4 + ((c>>2)<<5) + (c&3);
            bool valid = gcol < cend;
            float rnc = valid ? rn[gcol] : 0.f;
#pragma unroll
            for (int i=0;i<4;i++){
                float v = valid ? acc[i][c]*rnri[i]*rnc : -INFINITY;
                ins4(v, gcol, tv[i], ti[i]);
            }
        }
    }
    // butterfly merge across the 8 cg lanes: snapshot partner's full list
    // FIRST, then insert — both partners mutate during ins4 otherwise.
#pragma unroll
    for (int mask=1; mask<8; mask<<=1){
        float ov[4][4]; int oi[4][4];
#pragma unroll
        for (int i=0;i<4;i++)
#pragma unroll
            for (int s=0;s<4;s++){
                ov[i][s] = __shfl_xor(tv[i][s], mask);
                oi[i][s] = __shfl_xor(ti[i][s], mask);
            }
#pragma unroll
        for (int i=0;i<4;i++)
#pragma unroll
            for (int s=0;s<4;s++)
                ins4(ov[i][s], oi[i][s], tv[i], ti[i]);
    }
    if (cg==0){
#pragma unroll
        for (int i=0;i<4;i++){
            int grow = mb + rg*4 + i;
            if (grow < NNODE){
#pragma unroll
                for (int s=0;s<4;s++){
                    candV[((size_t)grow*NSPLIT+split)*4+s]=tv[i][s];
                    candI[((size_t)grow*NSPLIT+split)*4+s]=ti[i][s];
                }
            }
        }
    }
}

__global__ void k_topk_merge(const float* __restrict__ candV, const int* __restrict__ candI,
        int* __restrict__ nbr){
    int r = blockIdx.x*256+threadIdx.x; if (r>=NNODE) return;
    const float* cv = candV + (size_t)r*(NSPLIT*4);
    const int*   ci = candI + (size_t)r*(NSPLIT*4);
    int chosen[4];
    for (int s=0;s<4;s++){
        float bv=-INFINITY; int bi=INT_MAX; int bslot=-1;
        for (int i=0;i<NSPLIT*4;i++){
            bool used=false;
            for (int q=0;q<s;q++) used = used || (chosen[q]==i);
            if (used) continue;
            float v = cv[i]; int id = ci[i];
            if (v > bv || (v==bv && id < bi)){ bv=v; bi=id; bslot=i; }
        }
        chosen[s]=bslot;
        nbr[r*4+s]=bi;
    }
}

__global__ void k_eattr(const float* __restrict__ xg, const int* __restrict__ nbr, float* __restrict__ ea){
    int j = blockIdx.x; int t = threadIdx.x;
    int n0=nbr[j*4], n1=nbr[j*4+1], n2=nbr[j*4+2], n3=nbr[j*4+3];
    for (int d=t; d<FDIM; d+=256){
        float s = xg[(size_t)n0*FDIM+d]+xg[(size_t)n1*FDIM+d]+xg[(size_t)n2*FDIM+d]+xg[(size_t)n3*FDIM+d];
        ea[(size_t)j*FDIM+d] = 0.25f*s;
    }
}

__global__ void k_count(const int* __restrict__ nbr, int* __restrict__ counts){
    int e = blockIdx.x*256+threadIdx.x; if(e<NEDGE) atomicAdd(&counts[nbr[e]],1);
}

__global__ void k_scan(const int* __restrict__ counts, int* __restrict__ csrOff){
    __shared__ int part[257];
    int t=threadIdx.x;
    int start = t*33; int s=0;
    for (int i=0;i<33;i++){ int idx=start+i; if(idx<NNODE) s += counts[idx]; }
    part[t+1]=s; if(t==0) part[0]=0;
    __syncthreads();
    if (t==0){ for (int i=1;i<=256;i++) part[i]+=part[i-1]; }
    __syncthreads();
    int run = part[t];
    for (int i=0;i<33;i++){ int idx=start+i; if(idx<NNODE){ csrOff[idx]=run; run+=counts[idx]; } }
    if (t==255) csrOff[NNODE]=run;
}

__global__ void k_fill(const int* __restrict__ nbr, const int* __restrict__ csrOff,
        int* __restrict__ fillPos, int* __restrict__ csrE){
    int e = blockIdx.x*256+threadIdx.x; if(e>=NEDGE) return;
    int i = nbr[e];
    int p = atomicAdd(&fillPos[i],1);
    csrE[csrOff[i]+p] = e;
}

__global__ void k_alpha(const int* __restrict__ nbr, const float* __restrict__ ps,
        const float* __restrict__ pe, float* __restrict__ alphan){
    int e = blockIdx.x*256+threadIdx.x; if(e>=NEDGE) return;
    float a = ps[nbr[e]] + pe[e>>2];
    alphan[e] = a>=0.f? a : 0.2f*a;
}

__global__ void k_esm(const int* __restrict__ csrOff, const int* __restrict__ csrE,
        float* __restrict__ alphan){
    int i = blockIdx.x*256+threadIdx.x; if(i>=NNODE) return;
    int s0=csrOff[i], s1=csrOff[i+1];
    if (s1==s0) return;
    float m=-INFINITY;
    for (int s=s0;s<s1;s++) m = fmaxf(m, alphan[csrE[s]]);
    float Z=0.f;
    for (int s=s0;s<s1;s++) Z += __expf(alphan[csrE[s]]-m);
    float inv = 1.f/Z;
    for (int s=s0;s<s1;s++){ int e=csrE[s]; alphan[e] = __expf(alphan[e]-m)*inv; }
}

__global__ void k_oute(const float* __restrict__ xs, const float* __restrict__ alphan,
        const int* __restrict__ nbr, float* __restrict__ out_e){
    int j = blockIdx.x; int t=threadIdx.x;
    __shared__ float a[4]; __shared__ int sidx[4];
    if (t<4){ a[t]=alphan[j*4+t]; sidx[t]=nbr[j*4+t]; }
    __syncthreads();
    for (int d=t; d<FDIM; d+=256){
        float v = a[0]*xs[(size_t)sidx[0]*FDIM+d] + a[1]*xs[(size_t)sidx[1]*FDIM+d]
                + a[2]*xs[(size_t)sidx[2]*FDIM+d] + a[3]*xs[(size_t)sidx[3]*FDIM+d];
        out_e[(size_t)j*FDIM+d] = 0.25f*v;
    }
}

__global__ void k_outn(const float* __restrict__ out_e, const float* __restrict__ alphan,
        const int* __restrict__ csrOff, const int* __restrict__ csrE,
        const float* __restrict__ bias, float* __restrict__ out_n){
    int i = blockIdx.x; int t=threadIdx.x;
    int s0=csrOff[i], s1=csrOff[i+1];
    float Dinv = (s1>s0)? 1.f/(float)(s1-s0) : 0.f;
    for (int d=t; d<FDIM; d+=256){
        float accv=0.f;
        for (int s=s0;s<s1;s++){
            int e=csrE[s];
            accv = fmaf(alphan[e], out_e[(size_t)(e>>2)*FDIM+d], accv);
        }
        out_n[(size_t)i*FDIM+d] = bias[d] + Dinv*accv;
    }
}

__global__ void k_colstat1(const float* __restrict__ Xn, float* __restrict__ p1, float* __restrict__ p2){
    int b = blockIdx.x; int t=threadIdx.x;
    float s0=0,q0=0,s1=0,q1=0;
    for (int r=b; r<NNODE; r+=64){
        float v0 = Xn[(size_t)r*FDIM + t];
        float v1 = Xn[(size_t)r*FDIM + t + 256];
        s0+=v0; q0=fmaf(v0,v0,q0); s1+=v1; q1=fmaf(v1,v1,q1);
    }
    p1[b*FDIM+t]=s0; p1[b*FDIM+t+256]=s1;
    p2[b*FDIM+t]=q0; p2[b*FDIM+t+256]=q1;
}

__global__ void k_colstat2(const float* __restrict__ p1, const float* __restrict__ p2,
        const float* __restrict__ w, const float* __restrict__ sc,
        float* __restrict__ mu, float* __restrict__ g){
    int d = threadIdx.x + blockIdx.x*256; if(d>=FDIM) return;
    float s=0,q=0;
    for (int bb=0;bb<64;bb++){ s+=p1[bb*FDIM+d]; q+=p2[bb*FDIM+d]; }
    float m = s/(float)NNODE;
    float ms = m*sc[d];
    float var = q/(float)NNODE - 2.f*ms*m + ms*ms;
    mu[d]=m;
    g[d] = w[d]*rsqrtf(var+1e-5f);
}

__global__ void k_gnapply(const float* __restrict__ Xin, const float* __restrict__ mu,
        const float* __restrict__ g, const float* __restrict__ sc,
        const float* __restrict__ bb, float* __restrict__ Xout){
    size_t i = (size_t)blockIdx.x*256+threadIdx.x;
    if (i >= (size_t)NNODE*FDIM) return;
    int d = (int)(i & 511);
    float o = Xin[i] - mu[d]*sc[d];
    Xout[i] = lrelu(g[d]*o + bb[d], 0.01f);
}

__global__ void k_final(const float* __restrict__ x1, const float* __restrict__ x2,
        const float* __restrict__ f1W, const float* __restrict__ f1b,
        const float* __restrict__ f2W, const float* __restrict__ f2b,
        const float* __restrict__ clW, const float* __restrict__ clb,
        float* __restrict__ outp){
    int r = blockIdx.x;
    int h = threadIdx.x;
    __shared__ float o8[HIDN];
    float s1=f1b[h], s2=f2b[h];
    for (int k=0;k<FDIM;k++){
        s1 = fmaf(x1[(size_t)r*FDIM+k], f1W[(size_t)k*HIDN+h], s1);
        s2 = fmaf(x2[(size_t)r*FDIM+k], f2W[(size_t)k*HIDN+h], s2);
    }
    o8[h] = lrelu(s1,0.01f)+lrelu(s2,0.01f);
    __syncthreads();
    if (h < 2){
        float s = clb[h];
        for (int k=0;k<HIDN;k++) s = fmaf(o8[k], clW[k*2+h], s);
        outp[16 + r*2 + h] = s;
    }
}

// ---------------------------------------------------------------------------
extern "C" void kernel_launch(void* const* d_in, const int* in_sizes, int n_in,
                              void* d_out, int out_size, void* d_ws, size_t ws_size,
                              hipStream_t stream) {
    (void)in_sizes; (void)n_in; (void)out_size; (void)ws_size;
    const float* x    = (const float*)d_in[0];
    const float* reh  = (const float*)d_in[1];
    const float* aW1  = (const float*)d_in[2];
    const float* ab1  = (const float*)d_in[3];
    const float* aW2  = (const float*)d_in[4];
    const float* cW   = (const float*)d_in[6];
    const float* cb   = (const float*)d_in[7];
    const float* dW1  = (const float*)d_in[8];
    const float* db1  = (const float*)d_in[9];
    const float* dW2  = (const float*)d_in[10];
    const float* db2  = (const float*)d_in[11];
    const float* g1W  = (const float*)d_in[12];
    const float* g1att= (const float*)d_in[13];
    const float* g1b  = (const float*)d_in[14];
    const float* n1w  = (const float*)d_in[15];
    const float* n1b  = (const float*)d_in[16];
    const float* n1s  = (const float*)d_in[17];
    const float* f1W  = (const float*)d_in[18];
    const float* f1b  = (const float*)d_in[19];
    const float* g2W  = (const float*)d_in[20];
    const float* g2att= (const float*)d_in[21];
    const float* g2b  = (const float*)d_in[22];
    const float* n2w  = (const float*)d_in[23];
    const float* n2b  = (const float*)d_in[24];
    const float* n2s  = (const float*)d_in[25];
    const float* f2W  = (const float*)d_in[26];
    const float* f2b  = (const float*)d_in[27];
    const float* clW  = (const float*)d_in[28];
    const float* clb  = (const float*)d_in[29];
    float* out = (float*)d_out;
    char* ws = (char*)d_ws;

    // workspace layout (bytes)
    float* scores = (float*)(ws + 0);              // 524288
    float* Mbuf   = (float*)(ws + 524288);         // 16384
    float* xc     = (float*)(ws + 540672);         // 16793600  (later reused as xs)
    float* xg1    = (float*)(ws + 17334272);       // 8396800
    float* xg     = (float*)(ws + 25731072);       // 16793600  (later reused as x2)
    float* rn     = (float*)(ws + 42524672);       // 32800
    int*   nbrp   = (int*)  (ws + 44656896);       // 131200
    float* eattr  = (float*)(ws + 44788224);       // 16793600
    int*   counts = (int*)  (ws + 61581824);       // 32800
    int*   csrOff = (int*)  (ws + 61614848);       // 32804
    int*   fillPos= (int*)  (ws + 61647872);       // 32800
    int*   csrE   = (int*)  (ws + 61680896);       // 131200
    float* w2     = (float*)(ws + 61812096);       // 2048
    float* ps     = (float*)(ws + 61814144);       // 32800
    float* pe     = (float*)(ws + 61847040);       // 32800
    float* alphan = (float*)(ws + 61880064);       // 131200
    float* out_e  = (float*)(ws + 62011264);       // 16793600
    float* out_n  = (float*)(ws + 78804864);       // 16793600
    float* part1  = (float*)(ws + 95598464);       // 131072
    float* part2  = (float*)(ws + 95729536);       // 131072
    float* mu     = (float*)(ws + 95860608);       // 2048
    float* gsc    = (float*)(ws + 95862656);       // 2048
    float* x1buf  = (float*)(ws + 95864704);       // 16793600
    float* scoresP= (float*)(ws + 112658304);      // 2097152
    float* MP     = (float*)(ws + 114755456);      // 524288
    float* xs     = xc;      // alias (xc dead after xg1 GEMM)
    float* x2buf  = xg;      // alias (xg dead after layer-1 xs GEMM)
    // cand buffers live in out_n/out_e regions (dead until the layer loop;
    // consumed by k_topk_merge before k_oute/k_outn write them).
    float* candV  = out_n;   // 8200*16*4 floats = 2099200 B  (< 16.8 MB)
    int*   candI  = (int*)out_e;

    hipMemsetAsync(counts, 0, NNODE*sizeof(int), stream);
    hipMemsetAsync(fillPos, 0, NNODE*sizeof(int), stream);

    // ---- attention MIL pooling ----
    k_scores<<<dim3(4,1024),256,0,stream>>>(x, aW1, ab1, aW2, scoresP);
    k_scred<<<512,256,0,stream>>>(scoresP, scores);
    k_softmax<<<NBAGS,256,0,stream>>>(scores);
    k_M<<<dim3(32,NBAGS),256,0,stream>>>(x, scores, MP);
    k_Mred<<<NBAGS,512,0,stream>>>(MP, Mbuf);
    k_logits_mlp<<<1,64,0,stream>>>(Mbuf, cW, cb, out);

    // ---- projector ----
    k_xc<<<(NNODE*FDIM+255)/256,256,0,stream>>>(Mbuf, reh, xc);
    k_gemm<<<dim3(2,(NNODE+63)/64),256,0,stream>>>(xc, dW1, db1, xg1, NNODE, HIDN, FDIM, 0.01f);
    k_gemm<<<dim3(4,(NNODE+63)/64),256,0,stream>>>(xg1, dW2, db2, xg, NNODE, FDIM, HIDN, 0.01f);

    // ---- kNN graph ----
    k_rowdot<<<NNODE,64,0,stream>>>(xg, nullptr, rn, FDIM, 1);
    k_simtopk<<<dim3(NSPLIT,(NNODE+127)/128),256,0,stream>>>(xg, rn, candV, candI);
    k_topk_merge<<<(NNODE+255)/256,256,0,stream>>>(candV, candI, nbrp);
    k_eattr<<<NNODE,256,0,stream>>>(xg, nbrp, eattr);
    k_count<<<(NEDGE+255)/256,256,0,stream>>>(nbrp, counts);
    k_scan<<<1,256,0,stream>>>(counts, csrOff);
    k_fill<<<(NEDGE+255)/256,256,0,stream>>>(nbrp, csrOff, fillPos, csrE);

    // ---- two hypergraph conv layers ----
    for (int layer=0; layer<2; ++layer){
        const float* Xin  = layer==0 ? xg   : x1buf;
        const float* W    = layer==0 ? g1W  : g2W;
        const float* att  = layer==0 ? g1att: g2att;
        const float* gb   = layer==0 ? g1b  : g2b;
        const float* nw   = layer==0 ? n1w  : n2w;
        const float* nb_  = layer==0 ? n1b  : n2b;
        const float* ns   = layer==0 ? n1s  : n2s;
        float* Xout       = layer==0 ? x1buf: x2buf;

        k_gemm<<<dim3(4,(NNODE+63)/64),256,0,stream>>>(Xin, W, nullptr, xs, NNODE, FDIM, FDIM, 1.0f);
        k_watt<<<FDIM,64,0,stream>>>(W, att+FDIM, w2);
        k_rowdot<<<NNODE,64,0,stream>>>(xs, att, ps, FDIM, 0);
        k_rowdot<<<NNODE,64,0,stream>>>(eattr, w2, pe, FDIM, 0);
        k_alpha<<<(NEDGE+255)/256,256,0,stream>>>(nbrp, ps, pe, alphan);
        k_esm<<<(NNODE+255)/256,256,0,stream>>>(csrOff, csrE, alphan);
        k_oute<<<NNODE,256,0,stream>>>(xs, alphan, nbrp, out_e);
        k_outn<<<NNODE,256,0,stream>>>(out_e, alphan, csrOff, csrE, gb, out_n);
        k_colstat1<<<64,256,0,stream>>>(out_n, part1, part2);
        k_colstat2<<<2,256,0,stream>>>(part1, part2, nw, ns, mu, gsc);
        k_gnapply<<<(NNODE*FDIM+255)/256,256,0,stream>>>(out_n, mu, gsc, ns, nb_, Xout);
    }

    // ---- final heads (only rows 0..7 matter) ----
    k_final<<<NBAGS,HIDN,0,stream>>>(x1buf, x2buf, f1W, f1b, f2W, f2b, clW, clb, out);
}

// Round 6
// 3220.950 us; speedup vs baseline: 1.1544x; 1.0464x over previous
//
#include <hip/hip_runtime.h>
#include <math.h>
#include <limits.h>

#define FDIM 512
#define HIDN 256
#define NBAGS 8
#define NINST 16384
#define NNODE 8200
#define NEDGE 32800
#define NSPLIT 16

__device__ __forceinline__ float lrelu(float v, float s){ return v >= 0.f ? v : v*s; }

// sorted-4 insert with jax.lax.top_k tie semantics (lower index wins ties)
__device__ __forceinline__ void ins4(float v, int id, float* tv, int* ti){
    if ((v > tv[3]) || (v == tv[3] && id < ti[3])){
        tv[3]=v; ti[3]=id;
#pragma unroll
        for (int q=3;q>0;--q){
            bool sw = (tv[q] > tv[q-1]) || (tv[q]==tv[q-1] && ti[q]<ti[q-1]);
            if (sw){ float f=tv[q]; tv[q]=tv[q-1]; tv[q-1]=f; int d=ti[q]; ti[q]=ti[q-1]; ti[q-1]=d; }
        }
    }
}

// ---------------------------------------------------------------------------
// Fused scores GEMM (round-1 verbatim: bit-exact scores feeding the discrete
// top-k downstream). tile 128x128, thread-tile 8x8, col-split partials.
// ---------------------------------------------------------------------------
__global__ __launch_bounds__(256) void k_scores(const float* __restrict__ X,
        const float* __restrict__ W, const float* __restrict__ b1,
        const float* __restrict__ v2, float* __restrict__ scoresP)
{
    __shared__ float As[32][128];
    __shared__ float Ws[32][128];
    __shared__ float red[128][16];
    int t = threadIdx.x; int tx = t & 15, ty = t >> 4;
    size_t mb = (size_t)blockIdx.y * 128; int nb = blockIdx.x * 128;
    float acc[8][8];
#pragma unroll
    for (int i=0;i<8;i++)
#pragma unroll
        for (int j=0;j<8;j++) acc[i][j]=0.f;

    int kq=(t&7)*4, m0=t>>3;
    int n4=(t&31)*4, k0=t>>5;
    for (int kc=0;kc<512;kc+=32){
#pragma unroll
        for (int mm=0;mm<4;mm++){
            int m = m0 + mm*32;
            float4 v = *(const float4*)(X + (mb+m)*512 + kc + kq);
            As[kq+0][m]=v.x; As[kq+1][m]=v.y; As[kq+2][m]=v.z; As[kq+3][m]=v.w;
        }
#pragma unroll
        for (int kk=0;kk<4;kk++){
            float4 v = *(const float4*)(W + (size_t)(kc+k0+kk*8)*512 + nb + n4);
            *(float4*)&Ws[k0+kk*8][n4] = v;
        }
        __syncthreads();
#pragma unroll 4
        for (int k=0;k<32;k++){
            float4 a0 = *(const float4*)&As[k][ty*8];
            float4 a1 = *(const float4*)&As[k][ty*8+4];
            float4 b0 = *(const float4*)&Ws[k][tx*8];
            float4 b1 = *(const float4*)&Ws[k][tx*8+4];
            float av[8]={a0.x,a0.y,a0.z,a0.w,a1.x,a1.y,a1.z,a1.w};
            float bv[8]={b0.x,b0.y,b0.z,b0.w,b1.x,b1.y,b1.z,b1.w};
#pragma unroll
            for (int i=0;i<8;i++)
#pragma unroll
                for (int j=0;j<8;j++)
                    acc[i][j] = fmaf(av[i], bv[j], acc[i][j]);
        }
        __syncthreads();
    }
    // epilogue: relu(h)·v2 partial per row
#pragma unroll
    for (int i=0;i<8;i++){
        float s=0.f;
#pragma unroll
        for (int j=0;j<8;j++){
            int gc = nb + tx*8 + j;
            float h = acc[i][j] + b1[gc];
            h = h > 0.f ? h : 0.f;
            s = fmaf(h, v2[gc], s);
        }
        red[ty*8+i][tx] = s;
    }
    __syncthreads();
    if (t < 128){
        float s=0.f;
#pragma unroll
        for (int q=0;q<16;q++) s += red[t][q];
        scoresP[(size_t)blockIdx.x*(NBAGS*NINST) + mb + t] = s;
    }
}

__global__ void k_scred(const float* __restrict__ sp, float* __restrict__ s){
    int r = blockIdx.x*256+threadIdx.x;
    if (r < NBAGS*NINST)
        s[r] = sp[r] + sp[NBAGS*NINST + r] + sp[2*NBAGS*NINST + r] + sp[3*NBAGS*NINST + r];
}

// softmax over 16384 per bag, in place
__global__ __launch_bounds__(256) void k_softmax(float* __restrict__ s0){
    int b = blockIdx.x; float* s = s0 + (size_t)b*NINST;
    __shared__ float red[256];
    int t = threadIdx.x;
    float m = -INFINITY;
    for (int i=t;i<NINST;i+=256) m = fmaxf(m, s[i]);
    red[t]=m; __syncthreads();
    for (int st=128; st>0; st>>=1){ if(t<st) red[t]=fmaxf(red[t],red[t+st]); __syncthreads(); }
    m = red[0]; __syncthreads();
    float sum=0.f;
    for (int i=t;i<NINST;i+=256) sum += __expf(s[i]-m);
    red[t]=sum; __syncthreads();
    for (int st=128; st>0; st>>=1){ if(t<st) red[t]+=red[t+st]; __syncthreads(); }
    float inv = 1.f/red[0];
    for (int i=t;i<NINST;i+=256) s[i] = __expf(s[i]-m)*inv;
}

// M partials: MP[(chunk*8+b)*512+d]
__global__ __launch_bounds__(256) void k_M(const float* __restrict__ x,
        const float* __restrict__ A, float* __restrict__ MP){
    int b = blockIdx.y; int chunk = blockIdx.x;
    int n0 = chunk*512;
    __shared__ float As[512];
    int t=threadIdx.x;
    As[t]       = A[(size_t)b*NINST+n0+t];
    As[t+256]   = A[(size_t)b*NINST+n0+t+256];
    __syncthreads();
    float a0=0.f, a1=0.f;
    const float* xb = x + ((size_t)b*NINST + n0)*FDIM;
    for (int n=0;n<512;n++){
        float w = As[n];
        a0 = fmaf(w, xb[(size_t)n*FDIM + t],       a0);
        a1 = fmaf(w, xb[(size_t)n*FDIM + t + 256], a1);
    }
    MP[((size_t)chunk*NBAGS + b)*FDIM + t]       = a0;
    MP[((size_t)chunk*NBAGS + b)*FDIM + t + 256] = a1;
}

__global__ void k_Mred(const float* __restrict__ mp, float* __restrict__ M_){
    int b = blockIdx.x; int d = threadIdx.x; // 512 threads
    float s=0.f;
    for (int c=0;c<32;c++) s += mp[((size_t)c*NBAGS+b)*FDIM + d];
    M_[b*FDIM+d]=s;
}

__global__ void k_logits_mlp(const float* __restrict__ M_, const float* __restrict__ cW,
        const float* __restrict__ cb, float* __restrict__ outp){
    int t = threadIdx.x;
    if (t < 16){
        int r=t>>1, c=t&1;
        float s=cb[c];
        for (int k=0;k<FDIM;k++) s = fmaf(M_[r*FDIM+k], cW[k*2+c], s);
        outp[r*2+c] = s;
    }
}

__global__ void k_xc(const float* __restrict__ M_, const float* __restrict__ reh, float* __restrict__ xc){
    size_t i = (size_t)blockIdx.x*256 + threadIdx.x;
    if (i >= (size_t)NNODE*FDIM) return;
    xc[i] = (i < (size_t)NBAGS*FDIM) ? M_[i] : reh[i - (size_t)NBAGS*FDIM];
}

// ---------------------------------------------------------------------------
// generic GEMM: C[M][N] = lrelu(X@W + bias, slope). tile 64x128, thread 4x8.
// ---------------------------------------------------------------------------
__global__ __launch_bounds__(256) void k_gemm(const float* __restrict__ X,
        const float* __restrict__ W, const float* __restrict__ bias,
        float* __restrict__ C, int M, int N, int K, float slope)
{
    __shared__ float As[32][68];
    __shared__ float Ws[32][128];
    int t = threadIdx.x; int tx = t & 15, ty = t >> 4;
    int mb = blockIdx.y * 64, nb = blockIdx.x * 128;
    float acc[4][8];
#pragma unroll
    for (int i=0;i<4;i++)
#pragma unroll
        for (int j=0;j<8;j++) acc[i][j]=0.f;

    int kq=(t&7)*4, m0=t>>3;
    int n4=(t&31)*4, k0=t>>5;
    for (int kc=0;kc<K;kc+=32){
#pragma unroll
        for (int mm=0;mm<2;mm++){
            int m = m0 + mm*32;
            int gr = mb + m; if (gr >= M) gr = M-1;
            float4 v = *(const float4*)(X + (size_t)gr*K + kc + kq);
            As[kq+0][m]=v.x; As[kq+1][m]=v.y; As[kq+2][m]=v.z; As[kq+3][m]=v.w;
        }
#pragma unroll
        for (int kk=0;kk<4;kk++){
            float4 v = *(const float4*)(W + (size_t)(kc+k0+kk*8)*N + nb + n4);
            *(float4*)&Ws[k0+kk*8][n4] = v;
        }
        __syncthreads();
#pragma unroll 4
        for (int k=0;k<32;k++){
            float4 a = *(const float4*)&As[k][ty*4];
            float4 b0 = *(const float4*)&Ws[k][tx*4];
            float4 b1 = *(const float4*)&Ws[k][64+tx*4];
            float av[4]={a.x,a.y,a.z,a.w};
            float bv[8]={b0.x,b0.y,b0.z,b0.w,b1.x,b1.y,b1.z,b1.w};
#pragma unroll
            for (int i=0;i<4;i++)
#pragma unroll
                for (int j=0;j<8;j++)
                    acc[i][j] = fmaf(av[i], bv[j], acc[i][j]);
        }
        __syncthreads();
    }
#pragma unroll
    for (int i=0;i<4;i++){
        int gr = mb + ty*4 + i;
        if (gr >= M) continue;
        float o[8];
#pragma unroll
        for (int j=0;j<8;j++){
            int gc = (j<4) ? (nb + tx*4 + j) : (nb + 64 + tx*4 + (j-4));
            float v = acc[i][j] + (bias ? bias[gc] : 0.f);
            o[j] = lrelu(v, slope);
        }
        float4 o0 = make_float4(o[0],o[1],o[2],o[3]);
        float4 o1 = make_float4(o[4],o[5],o[6],o[7]);
        *(float4*)(C + (size_t)gr*N + nb + tx*4)      = o0;
        *(float4*)(C + (size_t)gr*N + nb + 64 + tx*4) = o1;
    }
}

// row dot: mode 0: out[r] = X[r]·v ; mode 1: out[r] = 1/(sqrt(X[r]·X[r])+1e-12)
__global__ void k_rowdot(const float* __restrict__ X, const float* __restrict__ v,
        float* __restrict__ out, int K, int mode){
    int r = blockIdx.x; int t = threadIdx.x;
    const float* xr = X + (size_t)r*K;
    float s = 0.f;
    if (mode==1){ for (int k=t;k<K;k+=64){ float x_=xr[k]; s=fmaf(x_,x_,s);} }
    else        { for (int k=t;k<K;k+=64) s=fmaf(xr[k],v[k],s); }
    for (int off=32;off;off>>=1) s += __shfl_down(s, off);
    if (t==0) out[r] = (mode==1)? 1.f/(sqrtf(s)+1e-12f) : s;
}

// w2[k] = sum_j W[k][j]*att2[j]
__global__ void k_watt(const float* __restrict__ W, const float* __restrict__ att2, float* __restrict__ w2){
    int k = blockIdx.x; int t=threadIdx.x;
    float s=0.f;
    for (int j=t;j<FDIM;j+=64) s=fmaf(W[(size_t)k*FDIM+j], att2[j], s);
    for (int off=32;off;off>>=1) s += __shfl_down(s, off);
    if (t==0) w2[k]=s;
}

// ---------------------------------------------------------------------------
// sim + fused top-4, all-register selection.
// grid (16 col-splits, 65 row-blocks). tile 128x128, thread tile 4x16.
// LDS: transposed [32][132] with XOR column swizzle col' = col ^ s(k),
// s(k) = ((k>>2)&3)<<3  -> writes 2-way (free), b128 reads conflict-free.
// Register prefetch: next K-chunk's 8 float4 loads issued before compute so
// global latency hides under the 32-k FMA loop.
// Numerics bit-identical to the validated round-5 kernel (same fmaf chains,
// same selection value association acc*rnr*rnc, snapshot butterfly merge).
// ---------------------------------------------------------------------------
__global__ __launch_bounds__(256) void k_simtopk(const float* __restrict__ xg,
        const float* __restrict__ rn, float* __restrict__ candV, int* __restrict__ candI)
{
    __shared__ float As[32][132];
    __shared__ float Bs[32][132];
    int t = threadIdx.x;
    int cg = t & 7, rg = t >> 3;
    int split = blockIdx.x; int mb = blockIdx.y * 128;
    int c0 = split * 512;
    int cend = (split == NSPLIT-1) ? NNODE : (c0 + 512);

    float rnri[4];
#pragma unroll
    for (int i=0;i<4;i++){
        int grow = mb + rg*4 + i;
        rnri[i] = (grow < NNODE) ? rn[grow] : 0.f;
    }

    float tv[4][4]; int ti[4][4];
#pragma unroll
    for (int i=0;i<4;i++)
#pragma unroll
        for (int s=0;s<4;s++){ tv[i][s]=-INFINITY; ti[i][s]=INT_MAX; }

    int kq = (t&7)*4, m0 = t>>3;
    int ssw = (t&3) << 3;                 // s(kq+q) for q=0..3 (row>>2 == t&7)
    int colA = (m0 & 31) ^ ssw;           // swizzled base column for stores

    for (int cc = c0; cc < cend; cc += 128){
        float acc[4][16];
#pragma unroll
        for (int i=0;i<4;i++)
#pragma unroll
            for (int c=0;c<16;c++) acc[i][c]=0.f;

        // prologue: load chunk kc=0 into registers
        float4 pa[4], pb[4];
#pragma unroll
        for (int mm=0;mm<4;mm++){
            int gr = mb + m0 + mm*32; if (gr >= NNODE) gr = NNODE-1;
            pa[mm] = *(const float4*)(xg + (size_t)gr*512 + kq);
        }
#pragma unroll
        for (int cci=0;cci<4;cci++){
            int gc = cc + m0 + cci*32; if (gc >= NNODE) gc = NNODE-1;
            pb[cci] = *(const float4*)(xg + (size_t)gc*512 + kq);
        }

        for (int kc=0;kc<512;kc+=32){
            __syncthreads();   // readers of previous chunk done
#pragma unroll
            for (int mm=0;mm<4;mm++){
                int cw = colA + mm*32;
                As[kq+0][cw]=pa[mm].x; As[kq+1][cw]=pa[mm].y;
                As[kq+2][cw]=pa[mm].z; As[kq+3][cw]=pa[mm].w;
            }
#pragma unroll
            for (int cci=0;cci<4;cci++){
                int cw = colA + cci*32;
                Bs[kq+0][cw]=pb[cci].x; Bs[kq+1][cw]=pb[cci].y;
                Bs[kq+2][cw]=pb[cci].z; Bs[kq+3][cw]=pb[cci].w;
            }
            __syncthreads();   // chunk visible
            if (kc + 32 < 512){
                int kn = kc + 32;
#pragma unroll
                for (int mm=0;mm<4;mm++){
                    int gr = mb + m0 + mm*32; if (gr >= NNODE) gr = NNODE-1;
                    pa[mm] = *(const float4*)(xg + (size_t)gr*512 + kn + kq);
                }
#pragma unroll
                for (int cci=0;cci<4;cci++){
                    int gc = cc + m0 + cci*32; if (gc >= NNODE) gc = NNODE-1;
                    pb[cci] = *(const float4*)(xg + (size_t)gc*512 + kn + kq);
                }
            }
#pragma unroll 4
            for (int k=0;k<32;k++){
                int sk = ((k>>2)&3)<<3;
                float4 a  = *(const float4*)&As[k][(rg*4) ^ sk];
                int cb0 = (cg*4) ^ sk;
                float4 b0 = *(const float4*)&Bs[k][cb0];
                float4 b1 = *(const float4*)&Bs[k][cb0+32];
                float4 b2 = *(const float4*)&Bs[k][cb0+64];
                float4 b3 = *(const float4*)&Bs[k][cb0+96];
                float av[4]={a.x,a.y,a.z,a.w};
                float bv[16]={b0.x,b0.y,b0.z,b0.w,b1.x,b1.y,b1.z,b1.w,
                              b2.x,b2.y,b2.z,b2.w,b3.x,b3.y,b3.z,b3.w};
#pragma unroll
                for (int i=0;i<4;i++)
#pragma unroll
                    for (int c=0;c<16;c++)
                        acc[i][c] = fmaf(av[i], bv[c], acc[i][c]);
            }
        }
        // fold this tile's 16 columns into per-row running top-4 (registers)
#pragma unroll
        for (int c=0;c<16;c++){
            int gcol = cc + cg*4 + ((c>>2)<<5) + (c&3);
            bool valid = gcol < cend;
            float rnc = valid ? rn[gcol] : 0.f;
#pragma unroll
            for (int i=0;i<4;i++){
                float v = valid ? acc[i][c]*rnri[i]*rnc : -INFINITY;
                ins4(v, gcol, tv[i], ti[i]);
            }
        }
    }
    // butterfly merge across the 8 cg lanes: snapshot partner's full list
    // FIRST, then insert.
#pragma unroll
    for (int mask=1; mask<8; mask<<=1){
        float ov[4][4]; int oi[4][4];
#pragma unroll
        for (int i=0;i<4;i++)
#pragma unroll
            for (int s=0;s<4;s++){
                ov[i][s] = __shfl_xor(tv[i][s], mask);
                oi[i][s] = __shfl_xor(ti[i][s], mask);
            }
#pragma unroll
        for (int i=0;i<4;i++)
#pragma unroll
            for (int s=0;s<4;s++)
                ins4(ov[i][s], oi[i][s], tv[i], ti[i]);
    }
    if (cg==0){
#pragma unroll
        for (int i=0;i<4;i++){
            int grow = mb + rg*4 + i;
            if (grow < NNODE){
#pragma unroll
                for (int s=0;s<4;s++){
                    candV[((size_t)grow*NSPLIT+split)*4+s]=tv[i][s];
                    candI[((size_t)grow*NSPLIT+split)*4+s]=ti[i][s];
                }
            }
        }
    }
}

__global__ void k_topk_merge(const float* __restrict__ candV, const int* __restrict__ candI,
        int* __restrict__ nbr){
    int r = blockIdx.x*256+threadIdx.x; if (r>=NNODE) return;
    const float* cv = candV + (size_t)r*(NSPLIT*4);
    const int*   ci = candI + (size_t)r*(NSPLIT*4);
    int chosen[4];
    for (int s=0;s<4;s++){
        float bv=-INFINITY; int bi=INT_MAX; int bslot=-1;
        for (int i=0;i<NSPLIT*4;i++){
            bool used=false;
            for (int q=0;q<s;q++) used = used || (chosen[q]==i);
            if (used) continue;
            float v = cv[i]; int id = ci[i];
            if (v > bv || (v==bv && id < bi)){ bv=v; bi=id; bslot=i; }
        }
        chosen[s]=bslot;
        nbr[r*4+s]=bi;
    }
}

__global__ void k_eattr(const float* __restrict__ xg, const int* __restrict__ nbr, float* __restrict__ ea){
    int j = blockIdx.x; int t = threadIdx.x;
    int n0=nbr[j*4], n1=nbr[j*4+1], n2=nbr[j*4+2], n3=nbr[j*4+3];
    for (int d=t; d<FDIM; d+=256){
        float s = xg[(size_t)n0*FDIM+d]+xg[(size_t)n1*FDIM+d]+xg[(size_t)n2*FDIM+d]+xg[(size_t)n3*FDIM+d];
        ea[(size_t)j*FDIM+d] = 0.25f*s;
    }
}

__global__ void k_count(const int* __restrict__ nbr, int* __restrict__ counts){
    int e = blockIdx.x*256+threadIdx.x; if(e<NEDGE) atomicAdd(&counts[nbr[e]],1);
}

__global__ void k_scan(const int* __restrict__ counts, int* __restrict__ csrOff){
    __shared__ int part[257];
    int t=threadIdx.x;
    int start = t*33; int s=0;
    for (int i=0;i<33;i++){ int idx=start+i; if(idx<NNODE) s += counts[idx]; }
    part[t+1]=s; if(t==0) part[0]=0;
    __syncthreads();
    if (t==0){ for (int i=1;i<=256;i++) part[i]+=part[i-1]; }
    __syncthreads();
    int run = part[t];
    for (int i=0;i<33;i++){ int idx=start+i; if(idx<NNODE){ csrOff[idx]=run; run+=counts[idx]; } }
    if (t==255) csrOff[NNODE]=run;
}

__global__ void k_fill(const int* __restrict__ nbr, const int* __restrict__ csrOff,
        int* __restrict__ fillPos, int* __restrict__ csrE){
    int e = blockIdx.x*256+threadIdx.x; if(e>=NEDGE) return;
    int i = nbr[e];
    int p = atomicAdd(&fillPos[i],1);
    csrE[csrOff[i]+p] = e;
}

__global__ void k_alpha(const int* __restrict__ nbr, const float* __restrict__ ps,
        const float* __restrict__ pe, float* __restrict__ alphan){
    int e = blockIdx.x*256+threadIdx.x; if(e>=NEDGE) return;
    float a = ps[nbr[e]] + pe[e>>2];
    alphan[e] = a>=0.f? a : 0.2f*a;
}

__global__ void k_esm(const int* __restrict__ csrOff, const int* __restrict__ csrE,
        float* __restrict__ alphan){
    int i = blockIdx.x*256+threadIdx.x; if(i>=NNODE) return;
    int s0=csrOff[i], s1=csrOff[i+1];
    if (s1==s0) return;
    float m=-INFINITY;
    for (int s=s0;s<s1;s++) m = fmaxf(m, alphan[csrE[s]]);
    float Z=0.f;
    for (int s=s0;s<s1;s++) Z += __expf(alphan[csrE[s]]-m);
    float inv = 1.f/Z;
    for (int s=s0;s<s1;s++){ int e=csrE[s]; alphan[e] = __expf(alphan[e]-m)*inv; }
}

__global__ void k_oute(const float* __restrict__ xs, const float* __restrict__ alphan,
        const int* __restrict__ nbr, float* __restrict__ out_e){
    int j = blockIdx.x; int t=threadIdx.x;
    __shared__ float a[4]; __shared__ int sidx[4];
    if (t<4){ a[t]=alphan[j*4+t]; sidx[t]=nbr[j*4+t]; }
    __syncthreads();
    for (int d=t; d<FDIM; d+=256){
        float v = a[0]*xs[(size_t)sidx[0]*FDIM+d] + a[1]*xs[(size_t)sidx[1]*FDIM+d]
                + a[2]*xs[(size_t)sidx[2]*FDIM+d] + a[3]*xs[(size_t)sidx[3]*FDIM+d];
        out_e[(size_t)j*FDIM+d] = 0.25f*v;
    }
}

__global__ void k_outn(const float* __restrict__ out_e, const float* __restrict__ alphan,
        const int* __restrict__ csrOff, const int* __restrict__ csrE,
        const float* __restrict__ bias, float* __restrict__ out_n){
    int i = blockIdx.x; int t=threadIdx.x;
    int s0=csrOff[i], s1=csrOff[i+1];
    float Dinv = (s1>s0)? 1.f/(float)(s1-s0) : 0.f;
    for (int d=t; d<FDIM; d+=256){
        float accv=0.f;
        for (int s=s0;s<s1;s++){
            int e=csrE[s];
            accv = fmaf(alphan[e], out_e[(size_t)(e>>2)*FDIM+d], accv);
        }
        out_n[(size_t)i*FDIM+d] = bias[d] + Dinv*accv;
    }
}

__global__ void k_colstat1(const float* __restrict__ Xn, float* __restrict__ p1, float* __restrict__ p2){
    int b = blockIdx.x; int t=threadIdx.x;
    float s0=0,q0=0,s1=0,q1=0;
    for (int r=b; r<NNODE; r+=64){
        float v0 = Xn[(size_t)r*FDIM + t];
        float v1 = Xn[(size_t)r*FDIM + t + 256];
        s0+=v0; q0=fmaf(v0,v0,q0); s1+=v1; q1=fmaf(v1,v1,q1);
    }
    p1[b*FDIM+t]=s0; p1[b*FDIM+t+256]=s1;
    p2[b*FDIM+t]=q0; p2[b*FDIM+t+256]=q1;
}

__global__ void k_colstat2(const float* __restrict__ p1, const float* __restrict__ p2,
        const float* __restrict__ w, const float* __restrict__ sc,
        float* __restrict__ mu, float* __restrict__ g){
    int d = threadIdx.x + blockIdx.x*256; if(d>=FDIM) return;
    float s=0,q=0;
    for (int bb=0;bb<64;bb++){ s+=p1[bb*FDIM+d]; q+=p2[bb*FDIM+d]; }
    float m = s/(float)NNODE;
    float ms = m*sc[d];
    float var = q/(float)NNODE - 2.f*ms*m + ms*ms;
    mu[d]=m;
    g[d] = w[d]*rsqrtf(var+1e-5f);
}

__global__ void k_gnapply(const float* __restrict__ Xin, const float* __restrict__ mu,
        const float* __restrict__ g, const float* __restrict__ sc,
        const float* __restrict__ bb, float* __restrict__ Xout){
    size_t i = (size_t)blockIdx.x*256+threadIdx.x;
    if (i >= (size_t)NNODE*FDIM) return;
    int d = (int)(i & 511);
    float o = Xin[i] - mu[d]*sc[d];
    Xout[i] = lrelu(g[d]*o + bb[d], 0.01f);
}

__global__ void k_final(const float* __restrict__ x1, const float* __restrict__ x2,
        const float* __restrict__ f1W, const float* __restrict__ f1b,
        const float* __restrict__ f2W, const float* __restrict__ f2b,
        const float* __restrict__ clW, const float* __restrict__ clb,
        float* __restrict__ outp){
    int r = blockIdx.x;
    int h = threadIdx.x;
    __shared__ float o8[HIDN];
    float s1=f1b[h], s2=f2b[h];
    for (int k=0;k<FDIM;k++){
        s1 = fmaf(x1[(size_t)r*FDIM+k], f1W[(size_t)k*HIDN+h], s1);
        s2 = fmaf(x2[(size_t)r*FDIM+k], f2W[(size_t)k*HIDN+h], s2);
    }
    o8[h] = lrelu(s1,0.01f)+lrelu(s2,0.01f);
    __syncthreads();
    if (h < 2){
        float s = clb[h];
        for (int k=0;k<HIDN;k++) s = fmaf(o8[k], clW[k*2+h], s);
        outp[16 + r*2 + h] = s;
    }
}

// ---------------------------------------------------------------------------
extern "C" void kernel_launch(void* const* d_in, const int* in_sizes, int n_in,
                              void* d_out, int out_size, void* d_ws, size_t ws_size,
                              hipStream_t stream) {
    (void)in_sizes; (void)n_in; (void)out_size; (void)ws_size;
    const float* x    = (const float*)d_in[0];
    const float* reh  = (const float*)d_in[1];
    const float* aW1  = (const float*)d_in[2];
    const float* ab1  = (const float*)d_in[3];
    const float* aW2  = (const float*)d_in[4];
    const float* cW   = (const float*)d_in[6];
    const float* cb   = (const float*)d_in[7];
    const float* dW1  = (const float*)d_in[8];
    const float* db1  = (const float*)d_in[9];
    const float* dW2  = (const float*)d_in[10];
    const float* db2  = (const float*)d_in[11];
    const float* g1W  = (const float*)d_in[12];
    const float* g1att= (const float*)d_in[13];
    const float* g1b  = (const float*)d_in[14];
    const float* n1w  = (const float*)d_in[15];
    const float* n1b  = (const float*)d_in[16];
    const float* n1s  = (const float*)d_in[17];
    const float* f1W  = (const float*)d_in[18];
    const float* f1b  = (const float*)d_in[19];
    const float* g2W  = (const float*)d_in[20];
    const float* g2att= (const float*)d_in[21];
    const float* g2b  = (const float*)d_in[22];
    const float* n2w  = (const float*)d_in[23];
    const float* n2b  = (const float*)d_in[24];
    const float* n2s  = (const float*)d_in[25];
    const float* f2W  = (const float*)d_in[26];
    const float* f2b  = (const float*)d_in[27];
    const float* clW  = (const float*)d_in[28];
    const float* clb  = (const float*)d_in[29];
    float* out = (float*)d_out;
    char* ws = (char*)d_ws;

    // workspace layout (bytes)
    float* scores = (float*)(ws + 0);              // 524288
    float* Mbuf   = (float*)(ws + 524288);         // 16384
    float* xc     = (float*)(ws + 540672);         // 16793600  (later reused as xs)
    float* xg1    = (float*)(ws + 17334272);       // 8396800
    float* xg     = (float*)(ws + 25731072);       // 16793600  (later reused as x2)
    float* rn     = (float*)(ws + 42524672);       // 32800
    int*   nbrp   = (int*)  (ws + 44656896);       // 131200
    float* eattr  = (float*)(ws + 44788224);       // 16793600
    int*   counts = (int*)  (ws + 61581824);       // 32800
    int*   csrOff = (int*)  (ws + 61614848);       // 32804
    int*   fillPos= (int*)  (ws + 61647872);       // 32800
    int*   csrE   = (int*)  (ws + 61680896);       // 131200
    float* w2     = (float*)(ws + 61812096);       // 2048
    float* ps     = (float*)(ws + 61814144);       // 32800
    float* pe     = (float*)(ws + 61847040);       // 32800
    float* alphan = (float*)(ws + 61880064);       // 131200
    float* out_e  = (float*)(ws + 62011264);       // 16793600
    float* out_n  = (float*)(ws + 78804864);       // 16793600
    float* part1  = (float*)(ws + 95598464);       // 131072
    float* part2  = (float*)(ws + 95729536);       // 131072
    float* mu     = (float*)(ws + 95860608);       // 2048
    float* gsc    = (float*)(ws + 95862656);       // 2048
    float* x1buf  = (float*)(ws + 95864704);       // 16793600
    float* scoresP= (float*)(ws + 112658304);      // 2097152
    float* MP     = (float*)(ws + 114755456);      // 524288
    float* xs     = xc;      // alias (xc dead after xg1 GEMM)
    float* x2buf  = xg;      // alias (xg dead after layer-1 xs GEMM)
    // cand buffers live in out_n/out_e regions (dead until the layer loop;
    // consumed by k_topk_merge before k_oute/k_outn write them).
    float* candV  = out_n;   // 8200*16*4 floats = 2099200 B
    int*   candI  = (int*)out_e;

    hipMemsetAsync(counts, 0, NNODE*sizeof(int), stream);
    hipMemsetAsync(fillPos, 0, NNODE*sizeof(int), stream);

    // ---- attention MIL pooling ----
    k_scores<<<dim3(4,1024),256,0,stream>>>(x, aW1, ab1, aW2, scoresP);
    k_scred<<<512,256,0,stream>>>(scoresP, scores);
    k_softmax<<<NBAGS,256,0,stream>>>(scores);
    k_M<<<dim3(32,NBAGS),256,0,stream>>>(x, scores, MP);
    k_Mred<<<NBAGS,512,0,stream>>>(MP, Mbuf);
    k_logits_mlp<<<1,64,0,stream>>>(Mbuf, cW, cb, out);

    // ---- projector ----
    k_xc<<<(NNODE*FDIM+255)/256,256,0,stream>>>(Mbuf, reh, xc);
    k_gemm<<<dim3(2,(NNODE+63)/64),256,0,stream>>>(xc, dW1, db1, xg1, NNODE, HIDN, FDIM, 0.01f);
    k_gemm<<<dim3(4,(NNODE+63)/64),256,0,stream>>>(xg1, dW2, db2, xg, NNODE, FDIM, HIDN, 0.01f);

    // ---- kNN graph ----
    k_rowdot<<<NNODE,64,0,stream>>>(xg, nullptr, rn, FDIM, 1);
    k_simtopk<<<dim3(NSPLIT,(NNODE+127)/128),256,0,stream>>>(xg, rn, candV, candI);
    k_topk_merge<<<(NNODE+255)/256,256,0,stream>>>(candV, candI, nbrp);
    k_eattr<<<NNODE,256,0,stream>>>(xg, nbrp, eattr);
    k_count<<<(NEDGE+255)/256,256,0,stream>>>(nbrp, counts);
    k_scan<<<1,256,0,stream>>>(counts, csrOff);
    k_fill<<<(NEDGE+255)/256,256,0,stream>>>(nbrp, csrOff, fillPos, csrE);

    // ---- two hypergraph conv layers ----
    for (int layer=0; layer<2; ++layer){
        const float* Xin  = layer==0 ? xg   : x1buf;
        const float* W    = layer==0 ? g1W  : g2W;
        const float* att  = layer==0 ? g1att: g2att;
        const float* gb   = layer==0 ? g1b  : g2b;
        const float* nw   = layer==0 ? n1w  : n2w;
        const float* nb_  = layer==0 ? n1b  : n2b;
        const float* ns   = layer==0 ? n1s  : n2s;
        float* Xout       = layer==0 ? x1buf: x2buf;

        k_gemm<<<dim3(4,(NNODE+63)/64),256,0,stream>>>(Xin, W, nullptr, xs, NNODE, FDIM, FDIM, 1.0f);
        k_watt<<<FDIM,64,0,stream>>>(W, att+FDIM, w2);
        k_rowdot<<<NNODE,64,0,stream>>>(xs, att, ps, FDIM, 0);
        k_rowdot<<<NNODE,64,0,stream>>>(eattr, w2, pe, FDIM, 0);
        k_alpha<<<(NEDGE+255)/256,256,0,stream>>>(nbrp, ps, pe, alphan);
        k_esm<<<(NNODE+255)/256,256,0,stream>>>(csrOff, csrE, alphan);
        k_oute<<<NNODE,256,0,stream>>>(xs, alphan, nbrp, out_e);
        k_outn<<<NNODE,256,0,stream>>>(out_e, alphan, csrOff, csrE, gb, out_n);
        k_colstat1<<<64,256,0,stream>>>(out_n, part1, part2);
        k_colstat2<<<2,256,0,stream>>>(part1, part2, nw, ns, mu, gsc);
        k_gnapply<<<(NNODE*FDIM+255)/256,256,0,stream>>>(out_n, mu, gsc, ns, nb_, Xout);
    }

    // ---- final heads (only rows 0..7 matter) ----
    k_final<<<NBAGS,HIDN,0,stream>>>(x1buf, x2buf, f1W, f1b, f2W, f2b, clW, clb, out);
}

// Round 7
// 2471.136 us; speedup vs baseline: 1.5047x; 1.3034x over previous
//
#include <hip/hip_runtime.h>
#include <math.h>
#include <limits.h>

#define FDIM 512
#define HIDN 256
#define NBAGS 8
#define NINST 16384
#define NNODE 8200
#define NEDGE 32800
#define BFSPLIT 8

typedef __attribute__((ext_vector_type(8))) short short8v;   // 8 bf16 (4 VGPR)
typedef __attribute__((ext_vector_type(4))) float f32x4v;    // MFMA C/D frag

__device__ __forceinline__ float lrelu(float v, float s){ return v >= 0.f ? v : v*s; }

// sorted-4 insert with jax.lax.top_k tie semantics (lower index wins ties)
__device__ __forceinline__ void ins4(float v, int id, float* tv, int* ti){
    if ((v > tv[3]) || (v == tv[3] && id < ti[3])){
        tv[3]=v; ti[3]=id;
#pragma unroll
        for (int q=3;q>0;--q){
            bool sw = (tv[q] > tv[q-1]) || (tv[q]==tv[q-1] && ti[q]<ti[q-1]);
            if (sw){ float f=tv[q]; tv[q]=tv[q-1]; tv[q-1]=f; int d=ti[q]; ti[q]=ti[q-1]; ti[q-1]=d; }
        }
    }
}

__device__ __forceinline__ void ins8(float v, int id, float* tv, int* ti){
    if ((v > tv[7]) || (v == tv[7] && id < ti[7])){
        tv[7]=v; ti[7]=id;
#pragma unroll
        for (int q=7;q>0;--q){
            bool sw = (tv[q] > tv[q-1]) || (tv[q]==tv[q-1] && ti[q]<ti[q-1]);
            if (sw){ float f=tv[q]; tv[q]=tv[q-1]; tv[q-1]=f; int d=ti[q]; ti[q]=ti[q-1]; ti[q-1]=d; }
        }
    }
}

__device__ __forceinline__ unsigned short f2bf(float f){
    unsigned u = __float_as_uint(f);
    unsigned r = u + 0x7FFFu + ((u >> 16) & 1u);   // round-to-nearest-even
    return (unsigned short)(r >> 16);
}

// ---------------------------------------------------------------------------
// Fused scores GEMM (round-1 verbatim: bit-exact scores feeding the discrete
// top-k downstream). tile 128x128, thread-tile 8x8, col-split partials.
// ---------------------------------------------------------------------------
__global__ __launch_bounds__(256) void k_scores(const float* __restrict__ X,
        const float* __restrict__ W, const float* __restrict__ b1,
        const float* __restrict__ v2, float* __restrict__ scoresP)
{
    __shared__ float As[32][128];
    __shared__ float Ws[32][128];
    __shared__ float red[128][16];
    int t = threadIdx.x; int tx = t & 15, ty = t >> 4;
    size_t mb = (size_t)blockIdx.y * 128; int nb = blockIdx.x * 128;
    float acc[8][8];
#pragma unroll
    for (int i=0;i<8;i++)
#pragma unroll
        for (int j=0;j<8;j++) acc[i][j]=0.f;

    int kq=(t&7)*4, m0=t>>3;
    int n4=(t&31)*4, k0=t>>5;
    for (int kc=0;kc<512;kc+=32){
#pragma unroll
        for (int mm=0;mm<4;mm++){
            int m = m0 + mm*32;
            float4 v = *(const float4*)(X + (mb+m)*512 + kc + kq);
            As[kq+0][m]=v.x; As[kq+1][m]=v.y; As[kq+2][m]=v.z; As[kq+3][m]=v.w;
        }
#pragma unroll
        for (int kk=0;kk<4;kk++){
            float4 v = *(const float4*)(W + (size_t)(kc+k0+kk*8)*512 + nb + n4);
            *(float4*)&Ws[k0+kk*8][n4] = v;
        }
        __syncthreads();
#pragma unroll 4
        for (int k=0;k<32;k++){
            float4 a0 = *(const float4*)&As[k][ty*8];
            float4 a1 = *(const float4*)&As[k][ty*8+4];
            float4 b0 = *(const float4*)&Ws[k][tx*8];
            float4 b1 = *(const float4*)&Ws[k][tx*8+4];
            float av[8]={a0.x,a0.y,a0.z,a0.w,a1.x,a1.y,a1.z,a1.w};
            float bv[8]={b0.x,b0.y,b0.z,b0.w,b1.x,b1.y,b1.z,b1.w};
#pragma unroll
            for (int i=0;i<8;i++)
#pragma unroll
                for (int j=0;j<8;j++)
                    acc[i][j] = fmaf(av[i], bv[j], acc[i][j]);
        }
        __syncthreads();
    }
    // epilogue: relu(h)·v2 partial per row
#pragma unroll
    for (int i=0;i<8;i++){
        float s=0.f;
#pragma unroll
        for (int j=0;j<8;j++){
            int gc = nb + tx*8 + j;
            float h = acc[i][j] + b1[gc];
            h = h > 0.f ? h : 0.f;
            s = fmaf(h, v2[gc], s);
        }
        red[ty*8+i][tx] = s;
    }
    __syncthreads();
    if (t < 128){
        float s=0.f;
#pragma unroll
        for (int q=0;q<16;q++) s += red[t][q];
        scoresP[(size_t)blockIdx.x*(NBAGS*NINST) + mb + t] = s;
    }
}

__global__ void k_scred(const float* __restrict__ sp, float* __restrict__ s){
    int r = blockIdx.x*256+threadIdx.x;
    if (r < NBAGS*NINST)
        s[r] = sp[r] + sp[NBAGS*NINST + r] + sp[2*NBAGS*NINST + r] + sp[3*NBAGS*NINST + r];
}

// softmax over 16384 per bag, in place
__global__ __launch_bounds__(256) void k_softmax(float* __restrict__ s0){
    int b = blockIdx.x; float* s = s0 + (size_t)b*NINST;
    __shared__ float red[256];
    int t = threadIdx.x;
    float m = -INFINITY;
    for (int i=t;i<NINST;i+=256) m = fmaxf(m, s[i]);
    red[t]=m; __syncthreads();
    for (int st=128; st>0; st>>=1){ if(t<st) red[t]=fmaxf(red[t],red[t+st]); __syncthreads(); }
    m = red[0]; __syncthreads();
    float sum=0.f;
    for (int i=t;i<NINST;i+=256) sum += __expf(s[i]-m);
    red[t]=sum; __syncthreads();
    for (int st=128; st>0; st>>=1){ if(t<st) red[t]+=red[t+st]; __syncthreads(); }
    float inv = 1.f/red[0];
    for (int i=t;i<NINST;i+=256) s[i] = __expf(s[i]-m)*inv;
}

// M partials: MP[(chunk*8+b)*512+d]
__global__ __launch_bounds__(256) void k_M(const float* __restrict__ x,
        const float* __restrict__ A, float* __restrict__ MP){
    int b = blockIdx.y; int chunk = blockIdx.x;
    int n0 = chunk*512;
    __shared__ float As[512];
    int t=threadIdx.x;
    As[t]       = A[(size_t)b*NINST+n0+t];
    As[t+256]   = A[(size_t)b*NINST+n0+t+256];
    __syncthreads();
    float a0=0.f, a1=0.f;
    const float* xb = x + ((size_t)b*NINST + n0)*FDIM;
    for (int n=0;n<512;n++){
        float w = As[n];
        a0 = fmaf(w, xb[(size_t)n*FDIM + t],       a0);
        a1 = fmaf(w, xb[(size_t)n*FDIM + t + 256], a1);
    }
    MP[((size_t)chunk*NBAGS + b)*FDIM + t]       = a0;
    MP[((size_t)chunk*NBAGS + b)*FDIM + t + 256] = a1;
}

__global__ void k_Mred(const float* __restrict__ mp, float* __restrict__ M_){
    int b = blockIdx.x; int d = threadIdx.x; // 512 threads
    float s=0.f;
    for (int c=0;c<32;c++) s += mp[((size_t)c*NBAGS+b)*FDIM + d];
    M_[b*FDIM+d]=s;
}

__global__ void k_logits_mlp(const float* __restrict__ M_, const float* __restrict__ cW,
        const float* __restrict__ cb, float* __restrict__ outp){
    int t = threadIdx.x;
    if (t < 16){
        int r=t>>1, c=t&1;
        float s=cb[c];
        for (int k=0;k<FDIM;k++) s = fmaf(M_[r*FDIM+k], cW[k*2+c], s);
        outp[r*2+c] = s;
    }
}

__global__ void k_xc(const float* __restrict__ M_, const float* __restrict__ reh, float* __restrict__ xc){
    size_t i = (size_t)blockIdx.x*256 + threadIdx.x;
    if (i >= (size_t)NNODE*FDIM) return;
    xc[i] = (i < (size_t)NBAGS*FDIM) ? M_[i] : reh[i - (size_t)NBAGS*FDIM];
}

// ---------------------------------------------------------------------------
// generic GEMM: C[M][N] = lrelu(X@W + bias, slope). tile 64x128, thread 4x8.
// ---------------------------------------------------------------------------
__global__ __launch_bounds__(256) void k_gemm(const float* __restrict__ X,
        const float* __restrict__ W, const float* __restrict__ bias,
        float* __restrict__ C, int M, int N, int K, float slope)
{
    __shared__ float As[32][68];
    __shared__ float Ws[32][128];
    int t = threadIdx.x; int tx = t & 15, ty = t >> 4;
    int mb = blockIdx.y * 64, nb = blockIdx.x * 128;
    float acc[4][8];
#pragma unroll
    for (int i=0;i<4;i++)
#pragma unroll
        for (int j=0;j<8;j++) acc[i][j]=0.f;

    int kq=(t&7)*4, m0=t>>3;
    int n4=(t&31)*4, k0=t>>5;
    for (int kc=0;kc<K;kc+=32){
#pragma unroll
        for (int mm=0;mm<2;mm++){
            int m = m0 + mm*32;
            int gr = mb + m; if (gr >= M) gr = M-1;
            float4 v = *(const float4*)(X + (size_t)gr*K + kc + kq);
            As[kq+0][m]=v.x; As[kq+1][m]=v.y; As[kq+2][m]=v.z; As[kq+3][m]=v.w;
        }
#pragma unroll
        for (int kk=0;kk<4;kk++){
            float4 v = *(const float4*)(W + (size_t)(kc+k0+kk*8)*N + nb + n4);
            *(float4*)&Ws[k0+kk*8][n4] = v;
        }
        __syncthreads();
#pragma unroll 4
        for (int k=0;k<32;k++){
            float4 a = *(const float4*)&As[k][ty*4];
            float4 b0 = *(const float4*)&Ws[k][tx*4];
            float4 b1 = *(const float4*)&Ws[k][64+tx*4];
            float av[4]={a.x,a.y,a.z,a.w};
            float bv[8]={b0.x,b0.y,b0.z,b0.w,b1.x,b1.y,b1.z,b1.w};
#pragma unroll
            for (int i=0;i<4;i++)
#pragma unroll
                for (int j=0;j<8;j++)
                    acc[i][j] = fmaf(av[i], bv[j], acc[i][j]);
        }
        __syncthreads();
    }
#pragma unroll
    for (int i=0;i<4;i++){
        int gr = mb + ty*4 + i;
        if (gr >= M) continue;
        float o[8];
#pragma unroll
        for (int j=0;j<8;j++){
            int gc = (j<4) ? (nb + tx*4 + j) : (nb + 64 + tx*4 + (j-4));
            float v = acc[i][j] + (bias ? bias[gc] : 0.f);
            o[j] = lrelu(v, slope);
        }
        float4 o0 = make_float4(o[0],o[1],o[2],o[3]);
        float4 o1 = make_float4(o[4],o[5],o[6],o[7]);
        *(float4*)(C + (size_t)gr*N + nb + tx*4)      = o0;
        *(float4*)(C + (size_t)gr*N + nb + 64 + tx*4) = o1;
    }
}

// row dot: mode 0: out[r] = X[r]·v ; mode 1: out[r] = 1/(sqrt(X[r]·X[r])+1e-12)
__global__ void k_rowdot(const float* __restrict__ X, const float* __restrict__ v,
        float* __restrict__ out, int K, int mode){
    int r = blockIdx.x; int t = threadIdx.x;
    const float* xr = X + (size_t)r*K;
    float s = 0.f;
    if (mode==1){ for (int k=t;k<K;k+=64){ float x_=xr[k]; s=fmaf(x_,x_,s);} }
    else        { for (int k=t;k<K;k+=64) s=fmaf(xr[k],v[k],s); }
    for (int off=32;off;off>>=1) s += __shfl_down(s, off);
    if (t==0) out[r] = (mode==1)? 1.f/(sqrtf(s)+1e-12f) : s;
}

// w2[k] = sum_j W[k][j]*att2[j]
__global__ void k_watt(const float* __restrict__ W, const float* __restrict__ att2, float* __restrict__ w2){
    int k = blockIdx.x; int t=threadIdx.x;
    float s=0.f;
    for (int j=t;j<FDIM;j+=64) s=fmaf(W[(size_t)k*FDIM+j], att2[j], s);
    for (int off=32;off;off>>=1) s += __shfl_down(s, off);
    if (t==0) w2[k]=s;
}

// ---------------------------------------------------------------------------
// bf16 conversion of xg (prefilter input only; exact values never used for
// final comparisons)
// ---------------------------------------------------------------------------
__global__ void k_tobf16(const float* __restrict__ x, unsigned short* __restrict__ o){
    size_t i = ((size_t)blockIdx.x*256 + threadIdx.x)*4;
    if (i >= (size_t)NNODE*FDIM) return;
    float4 v = *(const float4*)(x + i);
    ushort4 r;
    r.x = f2bf(v.x); r.y = f2bf(v.y); r.z = f2bf(v.z); r.w = f2bf(v.w);
    *(ushort4*)(o + i) = r;
}

// ---------------------------------------------------------------------------
// bf16 MFMA prefilter: per row, top-8 bf16-cosine candidates per 1025-col
// split (8 splits -> 64 candidates/row). mfma_f32_16x16x32_bf16;
// C layout col=lane&15, row=(lane>>4)*4+reg (m89-verified).
// Per-lane running top-4 provably contains every row-global top-4 element in
// that lane's column class; lane-merge keeps top-8 per split for bf16-noise
// margin. grid (8 splits, 129 row-blocks of 64 rows), 4 waves/block.
// ---------------------------------------------------------------------------
__global__ __launch_bounds__(256) void k_simbf(const unsigned short* __restrict__ xgh,
        const float* __restrict__ rn, float* __restrict__ candV, int* __restrict__ candI)
{
    __shared__ unsigned short Bs[16][520];   // 16 cols x 512 k, padded (bank-spread)
    int t = threadIdx.x;
    int wv = t >> 6, lane = t & 63;
    int lcol = lane & 15, lk = lane >> 4;
    int split = blockIdx.x;
    int r0 = blockIdx.y * 64 + wv * 16;      // wave's 16-row strip

    // preload this wave's A fragments for all 16 K-steps (rows reused across
    // the whole column sweep): lane holds row=lane&15, k=(lane>>4)*8+j
    short8v aF[16];
    {
        int arow = r0 + lcol; if (arow >= NNODE) arow = NNODE - 1;
        const unsigned short* ap = xgh + (size_t)arow * FDIM + lk * 8;
#pragma unroll
        for (int s = 0; s < 16; s++)
            aF[s] = *(const short8v*)(ap + s * 32);
    }

    int c0 = split * 1025;
    int cend = c0 + 1025;                    // 8*1025 == 8200 == NNODE

    float tv[4][4]; int ti[4][4];
#pragma unroll
    for (int i=0;i<4;i++)
#pragma unroll
        for (int q=0;q<4;q++){ tv[i][q]=-INFINITY; ti[i][q]=INT_MAX; }

    int rho = t >> 4, seg = t & 15;          // staging coords

    for (int cc = c0; cc < cend; cc += 16){
        __syncthreads();                     // previous tile's readers done
        {
            int gc = cc + rho; if (gc >= cend) gc = cend - 1;
            const unsigned short* bp = xgh + (size_t)gc * FDIM;
#pragma unroll
            for (int p = 0; p < 4; p++)
                *(short8v*)&Bs[rho][seg*8 + p*128] = *(const short8v*)(bp + seg*8 + p*128);
        }
        __syncthreads();

        f32x4v acc = {0.f, 0.f, 0.f, 0.f};
#pragma unroll
        for (int s = 0; s < 16; s++){
            short8v bF = *(const short8v*)&Bs[lcol][lk*8 + s*32];
            acc = __builtin_amdgcn_mfma_f32_16x16x32_bf16(aF[s], bF, acc, 0, 0, 0);
        }
        int gcol = cc + lcol;
        bool valid = gcol < cend;
        float rnc = valid ? rn[gcol] : 0.f;
#pragma unroll
        for (int i = 0; i < 4; i++){
            float v = valid ? acc[i] * rnc : -INFINITY;
            ins4(v, gcol, tv[i], ti[i]);
        }
    }

    // merge the 16 col-class lanes (same 4 rows) to per-row top-8,
    // snapshot-then-insert butterfly (round-4 lesson)
    float mv[4][8]; int mi[4][8];
#pragma unroll
    for (int i=0;i<4;i++){
#pragma unroll
        for (int q=0;q<4;q++){ mv[i][q]=tv[i][q]; mi[i][q]=ti[i][q]; }
#pragma unroll
        for (int q=4;q<8;q++){ mv[i][q]=-INFINITY; mi[i][q]=INT_MAX; }
    }
#pragma unroll
    for (int mask=1; mask<16; mask<<=1){
        float ov[4][8]; int oi[4][8];
#pragma unroll
        for (int i=0;i<4;i++)
#pragma unroll
            for (int q=0;q<8;q++){
                ov[i][q] = __shfl_xor(mv[i][q], mask);
                oi[i][q] = __shfl_xor(mi[i][q], mask);
            }
#pragma unroll
        for (int i=0;i<4;i++)
#pragma unroll
            for (int q=0;q<8;q++)
                ins8(ov[i][q], oi[i][q], mv[i], mi[i]);
    }
    if (lcol == 0){
#pragma unroll
        for (int i=0;i<4;i++){
            int grow = r0 + lk*4 + i;
            if (grow < NNODE){
#pragma unroll
                for (int q=0;q<8;q++){
                    candV[((size_t)grow*BFSPLIT + split)*8 + q] = mv[i][q];
                    candI[((size_t)grow*BFSPLIT + split)*8 + q] = mi[i][q];
                }
            }
        }
    }
}

// ---------------------------------------------------------------------------
// exact rescore: per row, 64 unique candidates; recompute dot with the exact
// validated fmaf chain (k ascending, (dot*rnr)*rnc association) and take
// top-4 with lower-index tie-break -> bit-identical nbr to the fp32 kernel.
// 4 rows per block (one wave each).
// ---------------------------------------------------------------------------
__global__ __launch_bounds__(256) void k_rescore(const float* __restrict__ xg,
        const float* __restrict__ rn, const float* __restrict__ candV,
        const int* __restrict__ candI, int* __restrict__ nbr)
{
    int r = blockIdx.x*4 + (threadIdx.x >> 6);
    int lane = threadIdx.x & 63;
    if (r >= NNODE) return;
    int cid = candI[(size_t)r*64 + lane];
    float pv = candV[(size_t)r*64 + lane];
    bool ok = (pv != -INFINITY) && (cid >= 0) && (cid < NNODE);
    int c = ok ? cid : 0;
    const float* xr = xg + (size_t)r*FDIM;
    const float* xc = xg + (size_t)c*FDIM;
    float dot = 0.f;
    for (int k=0;k<FDIM;k++) dot = fmaf(xr[k], xc[k], dot);
    float v = ok ? (dot * rn[r]) * rn[c] : -INFINITY;
    int id = ok ? cid : INT_MAX;
    float tvv[4]={-INFINITY,-INFINITY,-INFINITY,-INFINITY};
    int tii[4]={INT_MAX,INT_MAX,INT_MAX,INT_MAX};
    ins4(v, id, tvv, tii);
#pragma unroll
    for (int mask=1; mask<64; mask<<=1){
        float ov[4]; int oi[4];
#pragma unroll
        for (int s=0;s<4;s++){ ov[s]=__shfl_xor(tvv[s],mask); oi[s]=__shfl_xor(tii[s],mask); }
#pragma unroll
        for (int s=0;s<4;s++) ins4(ov[s], oi[s], tvv, tii);
    }
    if (lane == 0){
#pragma unroll
        for (int s=0;s<4;s++) nbr[r*4+s] = tii[s];
    }
}

__global__ void k_eattr(const float* __restrict__ xg, const int* __restrict__ nbr, float* __restrict__ ea){
    int j = blockIdx.x; int t = threadIdx.x;
    int n0=nbr[j*4], n1=nbr[j*4+1], n2=nbr[j*4+2], n3=nbr[j*4+3];
    for (int d=t; d<FDIM; d+=256){
        float s = xg[(size_t)n0*FDIM+d]+xg[(size_t)n1*FDIM+d]+xg[(size_t)n2*FDIM+d]+xg[(size_t)n3*FDIM+d];
        ea[(size_t)j*FDIM+d] = 0.25f*s;
    }
}

__global__ void k_count(const int* __restrict__ nbr, int* __restrict__ counts){
    int e = blockIdx.x*256+threadIdx.x; if(e<NEDGE) atomicAdd(&counts[nbr[e]],1);
}

__global__ void k_scan(const int* __restrict__ counts, int* __restrict__ csrOff){
    __shared__ int part[257];
    int t=threadIdx.x;
    int start = t*33; int s=0;
    for (int i=0;i<33;i++){ int idx=start+i; if(idx<NNODE) s += counts[idx]; }
    part[t+1]=s; if(t==0) part[0]=0;
    __syncthreads();
    if (t==0){ for (int i=1;i<=256;i++) part[i]+=part[i-1]; }
    __syncthreads();
    int run = part[t];
    for (int i=0;i<33;i++){ int idx=start+i; if(idx<NNODE){ csrOff[idx]=run; run+=counts[idx]; } }
    if (t==255) csrOff[NNODE]=run;
}

__global__ void k_fill(const int* __restrict__ nbr, const int* __restrict__ csrOff,
        int* __restrict__ fillPos, int* __restrict__ csrE){
    int e = blockIdx.x*256+threadIdx.x; if(e>=NEDGE) return;
    int i = nbr[e];
    int p = atomicAdd(&fillPos[i],1);
    csrE[csrOff[i]+p] = e;
}

__global__ void k_alpha(const int* __restrict__ nbr, const float* __restrict__ ps,
        const float* __restrict__ pe, float* __restrict__ alphan){
    int e = blockIdx.x*256+threadIdx.x; if(e>=NEDGE) return;
    float a = ps[nbr[e]] + pe[e>>2];
    alphan[e] = a>=0.f? a : 0.2f*a;
}

__global__ void k_esm(const int* __restrict__ csrOff, const int* __restrict__ csrE,
        float* __restrict__ alphan){
    int i = blockIdx.x*256+threadIdx.x; if(i>=NNODE) return;
    int s0=csrOff[i], s1=csrOff[i+1];
    if (s1==s0) return;
    float m=-INFINITY;
    for (int s=s0;s<s1;s++) m = fmaxf(m, alphan[csrE[s]]);
    float Z=0.f;
    for (int s=s0;s<s1;s++) Z += __expf(alphan[csrE[s]]-m);
    float inv = 1.f/Z;
    for (int s=s0;s<s1;s++){ int e=csrE[s]; alphan[e] = __expf(alphan[e]-m)*inv; }
}

__global__ void k_oute(const float* __restrict__ xs, const float* __restrict__ alphan,
        const int* __restrict__ nbr, float* __restrict__ out_e){
    int j = blockIdx.x; int t=threadIdx.x;
    __shared__ float a[4]; __shared__ int sidx[4];
    if (t<4){ a[t]=alphan[j*4+t]; sidx[t]=nbr[j*4+t]; }
    __syncthreads();
    for (int d=t; d<FDIM; d+=256){
        float v = a[0]*xs[(size_t)sidx[0]*FDIM+d] + a[1]*xs[(size_t)sidx[1]*FDIM+d]
                + a[2]*xs[(size_t)sidx[2]*FDIM+d] + a[3]*xs[(size_t)sidx[3]*FDIM+d];
        out_e[(size_t)j*FDIM+d] = 0.25f*v;
    }
}

__global__ void k_outn(const float* __restrict__ out_e, const float* __restrict__ alphan,
        const int* __restrict__ csrOff, const int* __restrict__ csrE,
        const float* __restrict__ bias, float* __restrict__ out_n){
    int i = blockIdx.x; int t=threadIdx.x;
    int s0=csrOff[i], s1=csrOff[i+1];
    float Dinv = (s1>s0)? 1.f/(float)(s1-s0) : 0.f;
    for (int d=t; d<FDIM; d+=256){
        float accv=0.f;
        for (int s=s0;s<s1;s++){
            int e=csrE[s];
            accv = fmaf(alphan[e], out_e[(size_t)(e>>2)*FDIM+d], accv);
        }
        out_n[(size_t)i*FDIM+d] = bias[d] + Dinv*accv;
    }
}

__global__ void k_colstat1(const float* __restrict__ Xn, float* __restrict__ p1, float* __restrict__ p2){
    int b = blockIdx.x; int t=threadIdx.x;
    float s0=0,q0=0,s1=0,q1=0;
    for (int r=b; r<NNODE; r+=64){
        float v0 = Xn[(size_t)r*FDIM + t];
        float v1 = Xn[(size_t)r*FDIM + t + 256];
        s0+=v0; q0=fmaf(v0,v0,q0); s1+=v1; q1=fmaf(v1,v1,q1);
    }
    p1[b*FDIM+t]=s0; p1[b*FDIM+t+256]=s1;
    p2[b*FDIM+t]=q0; p2[b*FDIM+t+256]=q1;
}

__global__ void k_colstat2(const float* __restrict__ p1, const float* __restrict__ p2,
        const float* __restrict__ w, const float* __restrict__ sc,
        float* __restrict__ mu, float* __restrict__ g){
    int d = threadIdx.x + blockIdx.x*256; if(d>=FDIM) return;
    float s=0,q=0;
    for (int bb=0;bb<64;bb++){ s+=p1[bb*FDIM+d]; q+=p2[bb*FDIM+d]; }
    float m = s/(float)NNODE;
    float ms = m*sc[d];
    float var = q/(float)NNODE - 2.f*ms*m + ms*ms;
    mu[d]=m;
    g[d] = w[d]*rsqrtf(var+1e-5f);
}

__global__ void k_gnapply(const float* __restrict__ Xin, const float* __restrict__ mu,
        const float* __restrict__ g, const float* __restrict__ sc,
        const float* __restrict__ bb, float* __restrict__ Xout){
    size_t i = (size_t)blockIdx.x*256+threadIdx.x;
    if (i >= (size_t)NNODE*FDIM) return;
    int d = (int)(i & 511);
    float o = Xin[i] - mu[d]*sc[d];
    Xout[i] = lrelu(g[d]*o + bb[d], 0.01f);
}

__global__ void k_final(const float* __restrict__ x1, const float* __restrict__ x2,
        const float* __restrict__ f1W, const float* __restrict__ f1b,
        const float* __restrict__ f2W, const float* __restrict__ f2b,
        const float* __restrict__ clW, const float* __restrict__ clb,
        float* __restrict__ outp){
    int r = blockIdx.x;
    int h = threadIdx.x;
    __shared__ float o8[HIDN];
    float s1=f1b[h], s2=f2b[h];
    for (int k=0;k<FDIM;k++){
        s1 = fmaf(x1[(size_t)r*FDIM+k], f1W[(size_t)k*HIDN+h], s1);
        s2 = fmaf(x2[(size_t)r*FDIM+k], f2W[(size_t)k*HIDN+h], s2);
    }
    o8[h] = lrelu(s1,0.01f)+lrelu(s2,0.01f);
    __syncthreads();
    if (h < 2){
        float s = clb[h];
        for (int k=0;k<HIDN;k++) s = fmaf(o8[k], clW[k*2+h], s);
        outp[16 + r*2 + h] = s;
    }
}

// ---------------------------------------------------------------------------
extern "C" void kernel_launch(void* const* d_in, const int* in_sizes, int n_in,
                              void* d_out, int out_size, void* d_ws, size_t ws_size,
                              hipStream_t stream) {
    (void)in_sizes; (void)n_in; (void)out_size; (void)ws_size;
    const float* x    = (const float*)d_in[0];
    const float* reh  = (const float*)d_in[1];
    const float* aW1  = (const float*)d_in[2];
    const float* ab1  = (const float*)d_in[3];
    const float* aW2  = (const float*)d_in[4];
    const float* cW   = (const float*)d_in[6];
    const float* cb   = (const float*)d_in[7];
    const float* dW1  = (const float*)d_in[8];
    const float* db1  = (const float*)d_in[9];
    const float* dW2  = (const float*)d_in[10];
    const float* db2  = (const float*)d_in[11];
    const float* g1W  = (const float*)d_in[12];
    const float* g1att= (const float*)d_in[13];
    const float* g1b  = (const float*)d_in[14];
    const float* n1w  = (const float*)d_in[15];
    const float* n1b  = (const float*)d_in[16];
    const float* n1s  = (const float*)d_in[17];
    const float* f1W  = (const float*)d_in[18];
    const float* f1b  = (const float*)d_in[19];
    const float* g2W  = (const float*)d_in[20];
    const float* g2att= (const float*)d_in[21];
    const float* g2b  = (const float*)d_in[22];
    const float* n2w  = (const float*)d_in[23];
    const float* n2b  = (const float*)d_in[24];
    const float* n2s  = (const float*)d_in[25];
    const float* f2W  = (const float*)d_in[26];
    const float* f2b  = (const float*)d_in[27];
    const float* clW  = (const float*)d_in[28];
    const float* clb  = (const float*)d_in[29];
    float* out = (float*)d_out;
    char* ws = (char*)d_ws;

    // workspace layout (bytes)
    float* scores = (float*)(ws + 0);              // 524288
    float* Mbuf   = (float*)(ws + 524288);         // 16384
    float* xc     = (float*)(ws + 540672);         // 16793600  (later reused as xs)
    float* xg1    = (float*)(ws + 17334272);       // 8396800
    float* xg     = (float*)(ws + 25731072);       // 16793600  (later reused as x2)
    float* rn     = (float*)(ws + 42524672);       // 32800
    int*   nbrp   = (int*)  (ws + 44656896);       // 131200
    float* eattr  = (float*)(ws + 44788224);       // 16793600
    int*   counts = (int*)  (ws + 61581824);       // 32800
    int*   csrOff = (int*)  (ws + 61614848);       // 32804
    int*   fillPos= (int*)  (ws + 61647872);       // 32800
    int*   csrE   = (int*)  (ws + 61680896);       // 131200
    float* w2     = (float*)(ws + 61812096);       // 2048
    float* ps     = (float*)(ws + 61814144);       // 32800
    float* pe     = (float*)(ws + 61847040);       // 32800
    float* alphan = (float*)(ws + 61880064);       // 131200
    float* out_e  = (float*)(ws + 62011264);       // 16793600
    float* out_n  = (float*)(ws + 78804864);       // 16793600
    float* part1  = (float*)(ws + 95598464);       // 131072
    float* part2  = (float*)(ws + 95729536);       // 131072
    float* mu     = (float*)(ws + 95860608);       // 2048
    float* gsc    = (float*)(ws + 95862656);       // 2048
    float* x1buf  = (float*)(ws + 95864704);       // 16793600
    float* scoresP= (float*)(ws + 112658304);      // 2097152
    float* MP     = (float*)(ws + 114755456);      // 524288
    float* xs     = xc;      // alias (xc dead after xg1 GEMM)
    float* x2buf  = xg;      // alias (xg dead after layer-1 xs GEMM)
    // kNN scratch lives in the out_e/out_n regions (dead until the conv
    // layer loop; consumed by k_rescore before k_oute/k_outn write them)
    unsigned short* xgh = (unsigned short*)out_e;          // 8396800 B
    int*   candI  = (int*)((char*)out_e + 8396800);        // 2099200 B
    float* candV  = out_n;                                 // 2099200 B

    hipMemsetAsync(counts, 0, NNODE*sizeof(int), stream);
    hipMemsetAsync(fillPos, 0, NNODE*sizeof(int), stream);

    // ---- attention MIL pooling ----
    k_scores<<<dim3(4,1024),256,0,stream>>>(x, aW1, ab1, aW2, scoresP);
    k_scred<<<512,256,0,stream>>>(scoresP, scores);
    k_softmax<<<NBAGS,256,0,stream>>>(scores);
    k_M<<<dim3(32,NBAGS),256,0,stream>>>(x, scores, MP);
    k_Mred<<<NBAGS,512,0,stream>>>(MP, Mbuf);
    k_logits_mlp<<<1,64,0,stream>>>(Mbuf, cW, cb, out);

    // ---- projector ----
    k_xc<<<(NNODE*FDIM+255)/256,256,0,stream>>>(Mbuf, reh, xc);
    k_gemm<<<dim3(2,(NNODE+63)/64),256,0,stream>>>(xc, dW1, db1, xg1, NNODE, HIDN, FDIM, 0.01f);
    k_gemm<<<dim3(4,(NNODE+63)/64),256,0,stream>>>(xg1, dW2, db2, xg, NNODE, FDIM, HIDN, 0.01f);

    // ---- kNN graph: bf16 MFMA prefilter + exact fp32 rescore ----
    k_rowdot<<<NNODE,64,0,stream>>>(xg, nullptr, rn, FDIM, 1);
    k_tobf16<<<(NNODE*FDIM/4+255)/256,256,0,stream>>>(xg, xgh);
    k_simbf<<<dim3(BFSPLIT,(NNODE+63)/64),256,0,stream>>>(xgh, rn, candV, candI);
    k_rescore<<<(NNODE+3)/4,256,0,stream>>>(xg, rn, candV, candI, nbrp);
    k_eattr<<<NNODE,256,0,stream>>>(xg, nbrp, eattr);
    k_count<<<(NEDGE+255)/256,256,0,stream>>>(nbrp, counts);
    k_scan<<<1,256,0,stream>>>(counts, csrOff);
    k_fill<<<(NEDGE+255)/256,256,0,stream>>>(nbrp, csrOff, fillPos, csrE);

    // ---- two hypergraph conv layers ----
    for (int layer=0; layer<2; ++layer){
        const float* Xin  = layer==0 ? xg   : x1buf;
        const float* W    = layer==0 ? g1W  : g2W;
        const float* att  = layer==0 ? g1att: g2att;
        const float* gb   = layer==0 ? g1b  : g2b;
        const float* nw   = layer==0 ? n1w  : n2w;
        const float* nb_  = layer==0 ? n1b  : n2b;
        const float* ns   = layer==0 ? n1s  : n2s;
        float* Xout       = layer==0 ? x1buf: x2buf;

        k_gemm<<<dim3(4,(NNODE+63)/64),256,0,stream>>>(Xin, W, nullptr, xs, NNODE, FDIM, FDIM, 1.0f);
        k_watt<<<FDIM,64,0,stream>>>(W, att+FDIM, w2);
        k_rowdot<<<NNODE,64,0,stream>>>(xs, att, ps, FDIM, 0);
        k_rowdot<<<NNODE,64,0,stream>>>(eattr, w2, pe, FDIM, 0);
        k_alpha<<<(NEDGE+255)/256,256,0,stream>>>(nbrp, ps, pe, alphan);
        k_esm<<<(NNODE+255)/256,256,0,stream>>>(csrOff, csrE, alphan);
        k_oute<<<NNODE,256,0,stream>>>(xs, alphan, nbrp, out_e);
        k_outn<<<NNODE,256,0,stream>>>(out_e, alphan, csrOff, csrE, gb, out_n);
        k_colstat1<<<64,256,0,stream>>>(out_n, part1, part2);
        k_colstat2<<<2,256,0,stream>>>(part1, part2, nw, ns, mu, gsc);
        k_gnapply<<<(NNODE*FDIM+255)/256,256,0,stream>>>(out_n, mu, gsc, ns, nb_, Xout);
    }

    // ---- final heads (only rows 0..7 matter) ----
    k_final<<<NBAGS,HIDN,0,stream>>>(x1buf, x2buf, f1W, f1b, f2W, f2b, clW, clb, out);
}

// Round 8
// 2349.878 us; speedup vs baseline: 1.5824x; 1.0516x over previous
//
#include <hip/hip_runtime.h>
#include <math.h>
#include <limits.h>

#define FDIM 512
#define HIDN 256
#define NBAGS 8
#define NINST 16384
#define NNODE 8200
#define NEDGE 32800
#define BFSPLIT 8

typedef __attribute__((ext_vector_type(8))) short short8v;   // 8 bf16 (4 VGPR)
typedef __attribute__((ext_vector_type(4))) float f32x4v;    // MFMA C/D frag

__device__ __forceinline__ float lrelu(float v, float s){ return v >= 0.f ? v : v*s; }

// sorted-4 insert with jax.lax.top_k tie semantics (lower index wins ties)
__device__ __forceinline__ void ins4(float v, int id, float* tv, int* ti){
    if ((v > tv[3]) || (v == tv[3] && id < ti[3])){
        tv[3]=v; ti[3]=id;
#pragma unroll
        for (int q=3;q>0;--q){
            bool sw = (tv[q] > tv[q-1]) || (tv[q]==tv[q-1] && ti[q]<ti[q-1]);
            if (sw){ float f=tv[q]; tv[q]=tv[q-1]; tv[q-1]=f; int d=ti[q]; ti[q]=ti[q-1]; ti[q-1]=d; }
        }
    }
}

__device__ __forceinline__ void ins8(float v, int id, float* tv, int* ti){
    if ((v > tv[7]) || (v == tv[7] && id < ti[7])){
        tv[7]=v; ti[7]=id;
#pragma unroll
        for (int q=7;q>0;--q){
            bool sw = (tv[q] > tv[q-1]) || (tv[q]==tv[q-1] && ti[q]<ti[q-1]);
            if (sw){ float f=tv[q]; tv[q]=tv[q-1]; tv[q-1]=f; int d=ti[q]; ti[q]=ti[q-1]; ti[q-1]=d; }
        }
    }
}

__device__ __forceinline__ unsigned short f2bf(float f){
    unsigned u = __float_as_uint(f);
    unsigned r = u + 0x7FFFu + ((u >> 16) & 1u);   // round-to-nearest-even
    return (unsigned short)(r >> 16);
}

// ---------------------------------------------------------------------------
// Fused scores GEMM. Arithmetic (fmaf chains + epilogue order) is verbatim
// round-1 -> bit-exact scores. Changes are layout-only:
//  - A tile transposed [32][128] with XOR swizzle col^=((row>>2)&3)<<3:
//    scalar stores 2-way (was 8-way), reads broadcast/conflict-free.
//  - epilogue red[][] overlays the As region: LDS 40960 -> 32768 B
//    (5 blocks/CU instead of 4).
// ---------------------------------------------------------------------------
__global__ __launch_bounds__(256) void k_scores(const float* __restrict__ X,
        const float* __restrict__ W, const float* __restrict__ b1,
        const float* __restrict__ v2, float* __restrict__ scoresP)
{
    __shared__ __align__(16) float smem[8192];          // 32 KB exactly
    float (*As)[128] = (float(*)[128])smem;             // transposed X tile (swizzled)
    float (*Ws)[128] = (float(*)[128])(smem + 4096);    // dense W rows (round-1 layout)
    float (*red)[16] = (float(*)[16])smem;              // epilogue overlay on As
    int t = threadIdx.x; int tx = t & 15, ty = t >> 4;
    size_t mb = (size_t)blockIdx.y * 128; int nb = blockIdx.x * 128;
    float acc[8][8];
#pragma unroll
    for (int i=0;i<8;i++)
#pragma unroll
        for (int j=0;j<8;j++) acc[i][j]=0.f;

    int kq=(t&7)*4, m0=t>>3;
    int ssw=(t&3)<<3; int colA = m0 ^ ssw;     // s(kq+q) = (t&3)<<3 for q=0..3
    int n4=(t&31)*4, k0=t>>5;
    for (int kc=0;kc<512;kc+=32){
        __syncthreads();                       // prev chunk's readers done
#pragma unroll
        for (int mm=0;mm<4;mm++){
            int m = m0 + mm*32;
            float4 v = *(const float4*)(X + (mb+m)*512 + kc + kq);
            int cw = colA + mm*32;
            As[kq+0][cw]=v.x; As[kq+1][cw]=v.y; As[kq+2][cw]=v.z; As[kq+3][cw]=v.w;
        }
#pragma unroll
        for (int kk=0;kk<4;kk++){
            float4 v = *(const float4*)(W + (size_t)(kc+k0+kk*8)*512 + nb + n4);
            *(float4*)&Ws[k0+kk*8][n4] = v;
        }
        __syncthreads();
#pragma unroll 4
        for (int k=0;k<32;k++){
            int sk = ((k>>2)&3)<<3;
            int ca = (ty*8) ^ sk;
            float4 a0 = *(const float4*)&As[k][ca];
            float4 a1 = *(const float4*)&As[k][ca+4];
            float4 b0 = *(const float4*)&Ws[k][tx*8];
            float4 b1 = *(const float4*)&Ws[k][tx*8+4];
            float av[8]={a0.x,a0.y,a0.z,a0.w,a1.x,a1.y,a1.z,a1.w};
            float bv[8]={b0.x,b0.y,b0.z,b0.w,b1.x,b1.y,b1.z,b1.w};
#pragma unroll
            for (int i=0;i<8;i++)
#pragma unroll
                for (int j=0;j<8;j++)
                    acc[i][j] = fmaf(av[i], bv[j], acc[i][j]);
        }
    }
    __syncthreads();    // all compute done before red overlays As
    // epilogue: relu(h)·v2 partial per row (identical order to round 1)
#pragma unroll
    for (int i=0;i<8;i++){
        float s=0.f;
#pragma unroll
        for (int j=0;j<8;j++){
            int gc = nb + tx*8 + j;
            float h = acc[i][j] + b1[gc];
            h = h > 0.f ? h : 0.f;
            s = fmaf(h, v2[gc], s);
        }
        red[ty*8+i][tx] = s;
    }
    __syncthreads();
    if (t < 128){
        float s=0.f;
#pragma unroll
        for (int q=0;q<16;q++) s += red[t][q];
        scoresP[(size_t)blockIdx.x*(NBAGS*NINST) + mb + t] = s;
    }
}

__global__ void k_scred(const float* __restrict__ sp, float* __restrict__ s){
    int r = blockIdx.x*256+threadIdx.x;
    if (r < NBAGS*NINST)
        s[r] = sp[r] + sp[NBAGS*NINST + r] + sp[2*NBAGS*NINST + r] + sp[3*NBAGS*NINST + r];
}

// softmax over 16384 per bag, in place
__global__ __launch_bounds__(256) void k_softmax(float* __restrict__ s0){
    int b = blockIdx.x; float* s = s0 + (size_t)b*NINST;
    __shared__ float red[256];
    int t = threadIdx.x;
    float m = -INFINITY;
    for (int i=t;i<NINST;i+=256) m = fmaxf(m, s[i]);
    red[t]=m; __syncthreads();
    for (int st=128; st>0; st>>=1){ if(t<st) red[t]=fmaxf(red[t],red[t+st]); __syncthreads(); }
    m = red[0]; __syncthreads();
    float sum=0.f;
    for (int i=t;i<NINST;i+=256) sum += __expf(s[i]-m);
    red[t]=sum; __syncthreads();
    for (int st=128; st>0; st>>=1){ if(t<st) red[t]+=red[t+st]; __syncthreads(); }
    float inv = 1.f/red[0];
    for (int i=t;i<NINST;i+=256) s[i] = __expf(s[i]-m)*inv;
}

// M partials: MP[(chunk*8+b)*512+d]
__global__ __launch_bounds__(256) void k_M(const float* __restrict__ x,
        const float* __restrict__ A, float* __restrict__ MP){
    int b = blockIdx.y; int chunk = blockIdx.x;
    int n0 = chunk*512;
    __shared__ float As[512];
    int t=threadIdx.x;
    As[t]       = A[(size_t)b*NINST+n0+t];
    As[t+256]   = A[(size_t)b*NINST+n0+t+256];
    __syncthreads();
    float a0=0.f, a1=0.f;
    const float* xb = x + ((size_t)b*NINST + n0)*FDIM;
    for (int n=0;n<512;n++){
        float w = As[n];
        a0 = fmaf(w, xb[(size_t)n*FDIM + t],       a0);
        a1 = fmaf(w, xb[(size_t)n*FDIM + t + 256], a1);
    }
    MP[((size_t)chunk*NBAGS + b)*FDIM + t]       = a0;
    MP[((size_t)chunk*NBAGS + b)*FDIM + t + 256] = a1;
}

__global__ void k_Mred(const float* __restrict__ mp, float* __restrict__ M_){
    int b = blockIdx.x; int d = threadIdx.x; // 512 threads
    float s=0.f;
    for (int c=0;c<32;c++) s += mp[((size_t)c*NBAGS+b)*FDIM + d];
    M_[b*FDIM+d]=s;
}

__global__ void k_logits_mlp(const float* __restrict__ M_, const float* __restrict__ cW,
        const float* __restrict__ cb, float* __restrict__ outp){
    int t = threadIdx.x;
    if (t < 16){
        int r=t>>1, c=t&1;
        float s=cb[c];
        for (int k=0;k<FDIM;k++) s = fmaf(M_[r*FDIM+k], cW[k*2+c], s);
        outp[r*2+c] = s;
    }
}

__global__ void k_xc(const float* __restrict__ M_, const float* __restrict__ reh, float* __restrict__ xc){
    size_t i = (size_t)blockIdx.x*256 + threadIdx.x;
    if (i >= (size_t)NNODE*FDIM) return;
    xc[i] = (i < (size_t)NBAGS*FDIM) ? M_[i] : reh[i - (size_t)NBAGS*FDIM];
}

// ---------------------------------------------------------------------------
// generic GEMM: C[M][N] = lrelu(X@W + bias, slope). tile 64x128, thread 4x8.
// ---------------------------------------------------------------------------
__global__ __launch_bounds__(256) void k_gemm(const float* __restrict__ X,
        const float* __restrict__ W, const float* __restrict__ bias,
        float* __restrict__ C, int M, int N, int K, float slope)
{
    __shared__ float As[32][68];
    __shared__ float Ws[32][128];
    int t = threadIdx.x; int tx = t & 15, ty = t >> 4;
    int mb = blockIdx.y * 64, nb = blockIdx.x * 128;
    float acc[4][8];
#pragma unroll
    for (int i=0;i<4;i++)
#pragma unroll
        for (int j=0;j<8;j++) acc[i][j]=0.f;

    int kq=(t&7)*4, m0=t>>3;
    int n4=(t&31)*4, k0=t>>5;
    for (int kc=0;kc<K;kc+=32){
#pragma unroll
        for (int mm=0;mm<2;mm++){
            int m = m0 + mm*32;
            int gr = mb + m; if (gr >= M) gr = M-1;
            float4 v = *(const float4*)(X + (size_t)gr*K + kc + kq);
            As[kq+0][m]=v.x; As[kq+1][m]=v.y; As[kq+2][m]=v.z; As[kq+3][m]=v.w;
        }
#pragma unroll
        for (int kk=0;kk<4;kk++){
            float4 v = *(const float4*)(W + (size_t)(kc+k0+kk*8)*N + nb + n4);
            *(float4*)&Ws[k0+kk*8][n4] = v;
        }
        __syncthreads();
#pragma unroll 4
        for (int k=0;k<32;k++){
            float4 a = *(const float4*)&As[k][ty*4];
            float4 b0 = *(const float4*)&Ws[k][tx*4];
            float4 b1 = *(const float4*)&Ws[k][64+tx*4];
            float av[4]={a.x,a.y,a.z,a.w};
            float bv[8]={b0.x,b0.y,b0.z,b0.w,b1.x,b1.y,b1.z,b1.w};
#pragma unroll
            for (int i=0;i<4;i++)
#pragma unroll
                for (int j=0;j<8;j++)
                    acc[i][j] = fmaf(av[i], bv[j], acc[i][j]);
        }
        __syncthreads();
    }
#pragma unroll
    for (int i=0;i<4;i++){
        int gr = mb + ty*4 + i;
        if (gr >= M) continue;
        float o[8];
#pragma unroll
        for (int j=0;j<8;j++){
            int gc = (j<4) ? (nb + tx*4 + j) : (nb + 64 + tx*4 + (j-4));
            float v = acc[i][j] + (bias ? bias[gc] : 0.f);
            o[j] = lrelu(v, slope);
        }
        float4 o0 = make_float4(o[0],o[1],o[2],o[3]);
        float4 o1 = make_float4(o[4],o[5],o[6],o[7]);
        *(float4*)(C + (size_t)gr*N + nb + tx*4)      = o0;
        *(float4*)(C + (size_t)gr*N + nb + 64 + tx*4) = o1;
    }
}

// row dot: mode 0: out[r] = X[r]·v ; mode 1: out[r] = 1/(sqrt(X[r]·X[r])+1e-12)
__global__ void k_rowdot(const float* __restrict__ X, const float* __restrict__ v,
        float* __restrict__ out, int K, int mode){
    int r = blockIdx.x; int t = threadIdx.x;
    const float* xr = X + (size_t)r*K;
    float s = 0.f;
    if (mode==1){ for (int k=t;k<K;k+=64){ float x_=xr[k]; s=fmaf(x_,x_,s);} }
    else        { for (int k=t;k<K;k+=64) s=fmaf(xr[k],v[k],s); }
    for (int off=32;off;off>>=1) s += __shfl_down(s, off);
    if (t==0) out[r] = (mode==1)? 1.f/(sqrtf(s)+1e-12f) : s;
}

// w2[k] = sum_j W[k][j]*att2[j]
__global__ void k_watt(const float* __restrict__ W, const float* __restrict__ att2, float* __restrict__ w2){
    int k = blockIdx.x; int t=threadIdx.x;
    float s=0.f;
    for (int j=t;j<FDIM;j+=64) s=fmaf(W[(size_t)k*FDIM+j], att2[j], s);
    for (int off=32;off;off>>=1) s += __shfl_down(s, off);
    if (t==0) w2[k]=s;
}

// ---------------------------------------------------------------------------
// bf16 conversion of xg (prefilter input only)
// ---------------------------------------------------------------------------
__global__ void k_tobf16(const float* __restrict__ x, unsigned short* __restrict__ o){
    size_t i = ((size_t)blockIdx.x*256 + threadIdx.x)*4;
    if (i >= (size_t)NNODE*FDIM) return;
    float4 v = *(const float4*)(x + i);
    ushort4 r;
    r.x = f2bf(v.x); r.y = f2bf(v.y); r.z = f2bf(v.z); r.w = f2bf(v.w);
    *(ushort4*)(o + i) = r;
}

// ---------------------------------------------------------------------------
// bf16 MFMA prefilter: per row, top-8 bf16-cosine candidates per 1025-col
// split (8 splits -> 64 candidates/row).
// ---------------------------------------------------------------------------
__global__ __launch_bounds__(256) void k_simbf(const unsigned short* __restrict__ xgh,
        const float* __restrict__ rn, float* __restrict__ candV, int* __restrict__ candI)
{
    __shared__ unsigned short Bs[16][520];
    int t = threadIdx.x;
    int wv = t >> 6, lane = t & 63;
    int lcol = lane & 15, lk = lane >> 4;
    int split = blockIdx.x;
    int r0 = blockIdx.y * 64 + wv * 16;

    short8v aF[16];
    {
        int arow = r0 + lcol; if (arow >= NNODE) arow = NNODE - 1;
        const unsigned short* ap = xgh + (size_t)arow * FDIM + lk * 8;
#pragma unroll
        for (int s = 0; s < 16; s++)
            aF[s] = *(const short8v*)(ap + s * 32);
    }

    int c0 = split * 1025;
    int cend = c0 + 1025;

    float tv[4][4]; int ti[4][4];
#pragma unroll
    for (int i=0;i<4;i++)
#pragma unroll
        for (int q=0;q<4;q++){ tv[i][q]=-INFINITY; ti[i][q]=INT_MAX; }

    int rho = t >> 4, seg = t & 15;

    for (int cc = c0; cc < cend; cc += 16){
        __syncthreads();
        {
            int gc = cc + rho; if (gc >= cend) gc = cend - 1;
            const unsigned short* bp = xgh + (size_t)gc * FDIM;
#pragma unroll
            for (int p = 0; p < 4; p++)
                *(short8v*)&Bs[rho][seg*8 + p*128] = *(const short8v*)(bp + seg*8 + p*128);
        }
        __syncthreads();

        f32x4v acc = {0.f, 0.f, 0.f, 0.f};
#pragma unroll
        for (int s = 0; s < 16; s++){
            short8v bF = *(const short8v*)&Bs[lcol][lk*8 + s*32];
            acc = __builtin_amdgcn_mfma_f32_16x16x32_bf16(aF[s], bF, acc, 0, 0, 0);
        }
        int gcol = cc + lcol;
        bool valid = gcol < cend;
        float rnc = valid ? rn[gcol] : 0.f;
#pragma unroll
        for (int i = 0; i < 4; i++){
            float v = valid ? acc[i] * rnc : -INFINITY;
            ins4(v, gcol, tv[i], ti[i]);
        }
    }

    float mv[4][8]; int mi[4][8];
#pragma unroll
    for (int i=0;i<4;i++){
#pragma unroll
        for (int q=0;q<4;q++){ mv[i][q]=tv[i][q]; mi[i][q]=ti[i][q]; }
#pragma unroll
        for (int q=4;q<8;q++){ mv[i][q]=-INFINITY; mi[i][q]=INT_MAX; }
    }
#pragma unroll
    for (int mask=1; mask<16; mask<<=1){
        float ov[4][8]; int oi[4][8];
#pragma unroll
        for (int i=0;i<4;i++)
#pragma unroll
            for (int q=0;q<8;q++){
                ov[i][q] = __shfl_xor(mv[i][q], mask);
                oi[i][q] = __shfl_xor(mi[i][q], mask);
            }
#pragma unroll
        for (int i=0;i<4;i++)
#pragma unroll
            for (int q=0;q<8;q++)
                ins8(ov[i][q], oi[i][q], mv[i], mi[i]);
    }
    if (lcol == 0){
#pragma unroll
        for (int i=0;i<4;i++){
            int grow = r0 + lk*4 + i;
            if (grow < NNODE){
#pragma unroll
                for (int q=0;q<8;q++){
                    candV[((size_t)grow*BFSPLIT + split)*8 + q] = mv[i][q];
                    candI[((size_t)grow*BFSPLIT + split)*8 + q] = mi[i][q];
                }
            }
        }
    }
}

// ---------------------------------------------------------------------------
// exact rescore v2: identical per-lane k-ascending fmaf chain (bit-exact nbr),
// but candidate rows staged through LDS with coalesced global loads.
// Block = 4 rows (1 wave each); 16-wide k chunks; Cs stride 17 -> 2-way max.
// ---------------------------------------------------------------------------
__global__ __launch_bounds__(256) void k_rescore(const float* __restrict__ xg,
        const float* __restrict__ rn, const float* __restrict__ candV,
        const int* __restrict__ candI, int* __restrict__ nbr)
{
    __shared__ float Xr[4][512];        // 8 KB
    __shared__ float Cs[256][17];       // 17408 B
    __shared__ int   CrowS[256];        // 1 KB
    int t = threadIdx.x;
    int wv = t >> 6, lane = t & 63;
    int r0 = blockIdx.x * 4;
    int r  = r0 + wv;                    // grid 2050*4 = 8200 exact
    int cid = candI[(size_t)r*64 + lane];
    float pv = candV[(size_t)r*64 + lane];
    bool ok = (pv != -INFINITY) && (cid >= 0) && (cid < NNODE);
    int crow = ok ? cid : 0;
    CrowS[t] = crow;
    {
        int rr = t >> 6; int c = t & 63;
        const float* xp = xg + (size_t)(r0+rr)*FDIM;
        *(float4*)&Xr[rr][c*4]       = *(const float4*)(xp + c*4);
        *(float4*)&Xr[rr][256 + c*4] = *(const float4*)(xp + 256 + c*4);
    }
    float dot = 0.f;
    for (int kc = 0; kc < 512; kc += 16){
        __syncthreads();                 // prev chunk consumed (also covers init)
#pragma unroll
        for (int p = 0; p < 4; p++){
            int slot = p*64 + (t >> 2);
            int f = t & 3;
            float4 v = *(const float4*)(xg + (size_t)CrowS[slot]*FDIM + kc + f*4);
            float* dst = &Cs[slot][f*4];
            dst[0]=v.x; dst[1]=v.y; dst[2]=v.z; dst[3]=v.w;
        }
        __syncthreads();
#pragma unroll
        for (int k2 = 0; k2 < 16; k2++)
            dot = fmaf(Xr[wv][kc + k2], Cs[t][k2], dot);
    }
    float v = ok ? (dot * rn[r]) * rn[crow] : -INFINITY;
    int id = ok ? cid : INT_MAX;
    float tvv[4]={-INFINITY,-INFINITY,-INFINITY,-INFINITY};
    int tii[4]={INT_MAX,INT_MAX,INT_MAX,INT_MAX};
    ins4(v, id, tvv, tii);
#pragma unroll
    for (int mask=1; mask<64; mask<<=1){
        float ov[4]; int oi[4];
#pragma unroll
        for (int s=0;s<4;s++){ ov[s]=__shfl_xor(tvv[s],mask); oi[s]=__shfl_xor(tii[s],mask); }
#pragma unroll
        for (int s=0;s<4;s++) ins4(ov[s], oi[s], tvv, tii);
    }
    if (lane == 0){
#pragma unroll
        for (int s=0;s<4;s++) nbr[r*4+s] = tii[s];
    }
}

__global__ void k_eattr(const float* __restrict__ xg, const int* __restrict__ nbr, float* __restrict__ ea){
    int j = blockIdx.x; int t = threadIdx.x;
    int n0=nbr[j*4], n1=nbr[j*4+1], n2=nbr[j*4+2], n3=nbr[j*4+3];
    for (int d=t; d<FDIM; d+=256){
        float s = xg[(size_t)n0*FDIM+d]+xg[(size_t)n1*FDIM+d]+xg[(size_t)n2*FDIM+d]+xg[(size_t)n3*FDIM+d];
        ea[(size_t)j*FDIM+d] = 0.25f*s;
    }
}

__global__ void k_count(const int* __restrict__ nbr, int* __restrict__ counts){
    int e = blockIdx.x*256+threadIdx.x; if(e<NEDGE) atomicAdd(&counts[nbr[e]],1);
}

__global__ void k_scan(const int* __restrict__ counts, int* __restrict__ csrOff){
    __shared__ int part[257];
    int t=threadIdx.x;
    int start = t*33; int s=0;
    for (int i=0;i<33;i++){ int idx=start+i; if(idx<NNODE) s += counts[idx]; }
    part[t+1]=s; if(t==0) part[0]=0;
    __syncthreads();
    if (t==0){ for (int i=1;i<=256;i++) part[i]+=part[i-1]; }
    __syncthreads();
    int run = part[t];
    for (int i=0;i<33;i++){ int idx=start+i; if(idx<NNODE){ csrOff[idx]=run; run+=counts[idx]; } }
    if (t==255) csrOff[NNODE]=run;
}

__global__ void k_fill(const int* __restrict__ nbr, const int* __restrict__ csrOff,
        int* __restrict__ fillPos, int* __restrict__ csrE){
    int e = blockIdx.x*256+threadIdx.x; if(e>=NEDGE) return;
    int i = nbr[e];
    int p = atomicAdd(&fillPos[i],1);
    csrE[csrOff[i]+p] = e;
}

__global__ void k_alpha(const int* __restrict__ nbr, const float* __restrict__ ps,
        const float* __restrict__ pe, float* __restrict__ alphan){
    int e = blockIdx.x*256+threadIdx.x; if(e>=NEDGE) return;
    float a = ps[nbr[e]] + pe[e>>2];
    alphan[e] = a>=0.f? a : 0.2f*a;
}

__global__ void k_esm(const int* __restrict__ csrOff, const int* __restrict__ csrE,
        float* __restrict__ alphan){
    int i = blockIdx.x*256+threadIdx.x; if(i>=NNODE) return;
    int s0=csrOff[i], s1=csrOff[i+1];
    if (s1==s0) return;
    float m=-INFINITY;
    for (int s=s0;s<s1;s++) m = fmaxf(m, alphan[csrE[s]]);
    float Z=0.f;
    for (int s=s0;s<s1;s++) Z += __expf(alphan[csrE[s]]-m);
    float inv = 1.f/Z;
    for (int s=s0;s<s1;s++){ int e=csrE[s]; alphan[e] = __expf(alphan[e]-m)*inv; }
}

__global__ void k_oute(const float* __restrict__ xs, const float* __restrict__ alphan,
        const int* __restrict__ nbr, float* __restrict__ out_e){
    int j = blockIdx.x; int t=threadIdx.x;
    __shared__ float a[4]; __shared__ int sidx[4];
    if (t<4){ a[t]=alphan[j*4+t]; sidx[t]=nbr[j*4+t]; }
    __syncthreads();
    for (int d=t; d<FDIM; d+=256){
        float v = a[0]*xs[(size_t)sidx[0]*FDIM+d] + a[1]*xs[(size_t)sidx[1]*FDIM+d]
                + a[2]*xs[(size_t)sidx[2]*FDIM+d] + a[3]*xs[(size_t)sidx[3]*FDIM+d];
        out_e[(size_t)j*FDIM+d] = 0.25f*v;
    }
}

__global__ void k_outn(const float* __restrict__ out_e, const float* __restrict__ alphan,
        const int* __restrict__ csrOff, const int* __restrict__ csrE,
        const float* __restrict__ bias, float* __restrict__ out_n){
    int i = blockIdx.x; int t=threadIdx.x;
    int s0=csrOff[i], s1=csrOff[i+1];
    float Dinv = (s1>s0)? 1.f/(float)(s1-s0) : 0.f;
    for (int d=t; d<FDIM; d+=256){
        float accv=0.f;
        for (int s=s0;s<s1;s++){
            int e=csrE[s];
            accv = fmaf(alphan[e], out_e[(size_t)(e>>2)*FDIM+d], accv);
        }
        out_n[(size_t)i*FDIM+d] = bias[d] + Dinv*accv;
    }
}

__global__ void k_colstat1(const float* __restrict__ Xn, float* __restrict__ p1, float* __restrict__ p2){
    int b = blockIdx.x; int t=threadIdx.x;
    float s0=0,q0=0,s1=0,q1=0;
    for (int r=b; r<NNODE; r+=64){
        float v0 = Xn[(size_t)r*FDIM + t];
        float v1 = Xn[(size_t)r*FDIM + t + 256];
        s0+=v0; q0=fmaf(v0,v0,q0); s1+=v1; q1=fmaf(v1,v1,q1);
    }
    p1[b*FDIM+t]=s0; p1[b*FDIM+t+256]=s1;
    p2[b*FDIM+t]=q0; p2[b*FDIM+t+256]=q1;
}

__global__ void k_colstat2(const float* __restrict__ p1, const float* __restrict__ p2,
        const float* __restrict__ w, const float* __restrict__ sc,
        float* __restrict__ mu, float* __restrict__ g){
    int d = threadIdx.x + blockIdx.x*256; if(d>=FDIM) return;
    float s=0,q=0;
    for (int bb=0;bb<64;bb++){ s+=p1[bb*FDIM+d]; q+=p2[bb*FDIM+d]; }
    float m = s/(float)NNODE;
    float ms = m*sc[d];
    float var = q/(float)NNODE - 2.f*ms*m + ms*ms;
    mu[d]=m;
    g[d] = w[d]*rsqrtf(var+1e-5f);
}

__global__ void k_gnapply(const float* __restrict__ Xin, const float* __restrict__ mu,
        const float* __restrict__ g, const float* __restrict__ sc,
        const float* __restrict__ bb, float* __restrict__ Xout){
    size_t i = (size_t)blockIdx.x*256+threadIdx.x;
    if (i >= (size_t)NNODE*FDIM) return;
    int d = (int)(i & 511);
    float o = Xin[i] - mu[d]*sc[d];
    Xout[i] = lrelu(g[d]*o + bb[d], 0.01f);
}

__global__ void k_final(const float* __restrict__ x1, const float* __restrict__ x2,
        const float* __restrict__ f1W, const float* __restrict__ f1b,
        const float* __restrict__ f2W, const float* __restrict__ f2b,
        const float* __restrict__ clW, const float* __restrict__ clb,
        float* __restrict__ outp){
    int r = blockIdx.x;
    int h = threadIdx.x;
    __shared__ float o8[HIDN];
    float s1=f1b[h], s2=f2b[h];
    for (int k=0;k<FDIM;k++){
        s1 = fmaf(x1[(size_t)r*FDIM+k], f1W[(size_t)k*HIDN+h], s1);
        s2 = fmaf(x2[(size_t)r*FDIM+k], f2W[(size_t)k*HIDN+h], s2);
    }
    o8[h] = lrelu(s1,0.01f)+lrelu(s2,0.01f);
    __syncthreads();
    if (h < 2){
        float s = clb[h];
        for (int k=0;k<HIDN;k++) s = fmaf(o8[k], clW[k*2+h], s);
        outp[16 + r*2 + h] = s;
    }
}

// ---------------------------------------------------------------------------
extern "C" void kernel_launch(void* const* d_in, const int* in_sizes, int n_in,
                              void* d_out, int out_size, void* d_ws, size_t ws_size,
                              hipStream_t stream) {
    (void)in_sizes; (void)n_in; (void)out_size; (void)ws_size;
    const float* x    = (const float*)d_in[0];
    const float* reh  = (const float*)d_in[1];
    const float* aW1  = (const float*)d_in[2];
    const float* ab1  = (const float*)d_in[3];
    const float* aW2  = (const float*)d_in[4];
    const float* cW   = (const float*)d_in[6];
    const float* cb   = (const float*)d_in[7];
    const float* dW1  = (const float*)d_in[8];
    const float* db1  = (const float*)d_in[9];
    const float* dW2  = (const float*)d_in[10];
    const float* db2  = (const float*)d_in[11];
    const float* g1W  = (const float*)d_in[12];
    const float* g1att= (const float*)d_in[13];
    const float* g1b  = (const float*)d_in[14];
    const float* n1w  = (const float*)d_in[15];
    const float* n1b  = (const float*)d_in[16];
    const float* n1s  = (const float*)d_in[17];
    const float* f1W  = (const float*)d_in[18];
    const float* f1b  = (const float*)d_in[19];
    const float* g2W  = (const float*)d_in[20];
    const float* g2att= (const float*)d_in[21];
    const float* g2b  = (const float*)d_in[22];
    const float* n2w  = (const float*)d_in[23];
    const float* n2b  = (const float*)d_in[24];
    const float* n2s  = (const float*)d_in[25];
    const float* f2W  = (const float*)d_in[26];
    const float* f2b  = (const float*)d_in[27];
    const float* clW  = (const float*)d_in[28];
    const float* clb  = (const float*)d_in[29];
    float* out = (float*)d_out;
    char* ws = (char*)d_ws;

    // workspace layout (bytes)
    float* scores = (float*)(ws + 0);              // 524288
    float* Mbuf   = (float*)(ws + 524288);         // 16384
    float* xc     = (float*)(ws + 540672);         // 16793600  (later reused as xs)
    float* xg1    = (float*)(ws + 17334272);       // 8396800
    float* xg     = (float*)(ws + 25731072);       // 16793600  (later reused as x2)
    float* rn     = (float*)(ws + 42524672);       // 32800
    int*   nbrp   = (int*)  (ws + 44656896);       // 131200
    float* eattr  = (float*)(ws + 44788224);       // 16793600
    int*   counts = (int*)  (ws + 61581824);       // 32800
    int*   csrOff = (int*)  (ws + 61614848);       // 32804
    int*   fillPos= (int*)  (ws + 61647872);       // 32800
    int*   csrE   = (int*)  (ws + 61680896);       // 131200
    float* w2     = (float*)(ws + 61812096);       // 2048
    float* ps     = (float*)(ws + 61814144);       // 32800
    float* pe     = (float*)(ws + 61847040);       // 32800
    float* alphan = (float*)(ws + 61880064);       // 131200
    float* out_e  = (float*)(ws + 62011264);       // 16793600
    float* out_n  = (float*)(ws + 78804864);       // 16793600
    float* part1  = (float*)(ws + 95598464);       // 131072
    float* part2  = (float*)(ws + 95729536);       // 131072
    float* mu     = (float*)(ws + 95860608);       // 2048
    float* gsc    = (float*)(ws + 95862656);       // 2048
    float* x1buf  = (float*)(ws + 95864704);       // 16793600
    float* scoresP= (float*)(ws + 112658304);      // 2097152
    float* MP     = (float*)(ws + 114755456);      // 524288
    float* xs     = xc;      // alias (xc dead after xg1 GEMM)
    float* x2buf  = xg;      // alias (xg dead after layer-1 xs GEMM)
    // kNN scratch lives in the out_e/out_n regions (dead until the conv
    // layer loop; consumed by k_rescore before k_oute/k_outn write them)
    unsigned short* xgh = (unsigned short*)out_e;          // 8396800 B
    int*   candI  = (int*)((char*)out_e + 8396800);        // 2099200 B
    float* candV  = out_n;                                 // 2099200 B

    hipMemsetAsync(counts, 0, NNODE*sizeof(int), stream);
    hipMemsetAsync(fillPos, 0, NNODE*sizeof(int), stream);

    // ---- attention MIL pooling ----
    k_scores<<<dim3(4,1024),256,0,stream>>>(x, aW1, ab1, aW2, scoresP);
    k_scred<<<512,256,0,stream>>>(scoresP, scores);
    k_softmax<<<NBAGS,256,0,stream>>>(scores);
    k_M<<<dim3(32,NBAGS),256,0,stream>>>(x, scores, MP);
    k_Mred<<<NBAGS,512,0,stream>>>(MP, Mbuf);
    k_logits_mlp<<<1,64,0,stream>>>(Mbuf, cW, cb, out);

    // ---- projector ----
    k_xc<<<(NNODE*FDIM+255)/256,256,0,stream>>>(Mbuf, reh, xc);
    k_gemm<<<dim3(2,(NNODE+63)/64),256,0,stream>>>(xc, dW1, db1, xg1, NNODE, HIDN, FDIM, 0.01f);
    k_gemm<<<dim3(4,(NNODE+63)/64),256,0,stream>>>(xg1, dW2, db2, xg, NNODE, FDIM, HIDN, 0.01f);

    // ---- kNN graph: bf16 MFMA prefilter + exact fp32 rescore ----
    k_rowdot<<<NNODE,64,0,stream>>>(xg, nullptr, rn, FDIM, 1);
    k_tobf16<<<(NNODE*FDIM/4+255)/256,256,0,stream>>>(xg, xgh);
    k_simbf<<<dim3(BFSPLIT,(NNODE+63)/64),256,0,stream>>>(xgh, rn, candV, candI);
    k_rescore<<<NNODE/4,256,0,stream>>>(xg, rn, candV, candI, nbrp);
    k_eattr<<<NNODE,256,0,stream>>>(xg, nbrp, eattr);
    k_count<<<(NEDGE+255)/256,256,0,stream>>>(nbrp, counts);
    k_scan<<<1,256,0,stream>>>(counts, csrOff);
    k_fill<<<(NEDGE+255)/256,256,0,stream>>>(nbrp, csrOff, fillPos, csrE);

    // ---- two hypergraph conv layers ----
    for (int layer=0; layer<2; ++layer){
        const float* Xin  = layer==0 ? xg   : x1buf;
        const float* W    = layer==0 ? g1W  : g2W;
        const float* att  = layer==0 ? g1att: g2att;
        const float* gb   = layer==0 ? g1b  : g2b;
        const float* nw   = layer==0 ? n1w  : n2w;
        const float* nb_  = layer==0 ? n1b  : n2b;
        const float* ns   = layer==0 ? n1s  : n2s;
        float* Xout       = layer==0 ? x1buf: x2buf;

        k_gemm<<<dim3(4,(NNODE+63)/64),256,0,stream>>>(Xin, W, nullptr, xs, NNODE, FDIM, FDIM, 1.0f);
        k_watt<<<FDIM,64,0,stream>>>(W, att+FDIM, w2);
        k_rowdot<<<NNODE,64,0,stream>>>(xs, att, ps, FDIM, 0);
        k_rowdot<<<NNODE,64,0,stream>>>(eattr, w2, pe, FDIM, 0);
        k_alpha<<<(NEDGE+255)/256,256,0,stream>>>(nbrp, ps, pe, alphan);
        k_esm<<<(NNODE+255)/256,256,0,stream>>>(csrOff, csrE, alphan);
        k_oute<<<NNODE,256,0,stream>>>(xs, alphan, nbrp, out_e);
        k_outn<<<NNODE,256,0,stream>>>(out_e, alphan, csrOff, csrE, gb, out_n);
        k_colstat1<<<64,256,0,stream>>>(out_n, part1, part2);
        k_colstat2<<<2,256,0,stream>>>(part1, part2, nw, ns, mu, gsc);
        k_gnapply<<<(NNODE*FDIM+255)/256,256,0,stream>>>(out_n, mu, gsc, ns, nb_, Xout);
    }

    // ---- final heads (only rows 0..7 matter) ----
    k_final<<<NBAGS,HIDN,0,stream>>>(x1buf, x2buf, f1W, f1b, f2W, f2b, clW, clb, out);
}